// Round 1
// baseline (3061.733 us; speedup 1.0000x reference)
//
#include <hip/hip_runtime.h>

#define Bc 512
#define Lc 128
#define Kc 6
#define AFc 39
#define BFc 10
#define FPc 200
#define Rc 3
#define Tc 2
constexpr int BL = Bc * Lc;          // 65536
constexpr float SLOPE = 0.01f;
constexpr float NEGC = -9e8f;

__device__ __forceinline__ float leaky(float x) { return x >= 0.f ? x : SLOPE * x; }
__device__ __forceinline__ float sigm(float x) { return 1.f / (1.f + __expf(-x)); }
__device__ __forceinline__ float eluf(float x) { return x > 0.f ? x : expm1f(x); }
__device__ __forceinline__ float wave_sum(float v) {
  #pragma unroll
  for (int m = 32; m >= 1; m >>= 1) v += __shfl_xor(v, m);
  return v;
}

// -------------------- weight transpose: out[c*R + r] = in[r*C + c] --------------------
__global__ void transpose_k(const float* __restrict__ in, float* __restrict__ out, int R, int C) {
  int n = R * C;
  for (int i = blockIdx.x * blockDim.x + threadIdx.x; i < n; i += gridDim.x * blockDim.x) {
    int r = i / C, c = i - r * C;
    out[c * R + r] = in[i];
  }
}

// -------------------- generic GEMM: Y[rows][200] = epi(X[rows][KD] @ WT[KD][200]) ----
// 8 rows per block, thread f computes 8 outputs. EPI: 0=raw(no bias), 1=atomlin(raw->Y, leaky->Y2), 2=elu(acc+sumw*bias)
template<int KD, int EPI>
__global__ __launch_bounds__(256) void gemm8x1(
    const float* __restrict__ X, const float* __restrict__ WT,
    const float* __restrict__ bias, const float* __restrict__ sumw,
    float* __restrict__ Y, float* __restrict__ Y2) {
  constexpr int TR = 8, LDP = 12;
  __shared__ float xT[KD * LDP];
  const int row0 = blockIdx.x * TR;
  const int tid = threadIdx.x;
  for (int e = tid; e < TR * KD; e += 256) {
    int r = e / KD, g = e - r * KD;
    xT[g * LDP + r] = X[(size_t)row0 * KD + e];
  }
  __syncthreads();
  const int f = tid;
  if (f < FPc) {
    float acc[TR];
    #pragma unroll
    for (int r = 0; r < TR; ++r) acc[r] = 0.f;
    #pragma unroll 4
    for (int g = 0; g < KD; ++g) {
      float w = WT[(size_t)g * FPc + f];
      float4 x0 = *reinterpret_cast<const float4*>(&xT[g * LDP]);
      float4 x1 = *reinterpret_cast<const float4*>(&xT[g * LDP + 4]);
      acc[0] = fmaf(x0.x, w, acc[0]); acc[1] = fmaf(x0.y, w, acc[1]);
      acc[2] = fmaf(x0.z, w, acc[2]); acc[3] = fmaf(x0.w, w, acc[3]);
      acc[4] = fmaf(x1.x, w, acc[4]); acc[5] = fmaf(x1.y, w, acc[5]);
      acc[6] = fmaf(x1.z, w, acc[6]); acc[7] = fmaf(x1.w, w, acc[7]);
    }
    #pragma unroll
    for (int r = 0; r < TR; ++r) {
      size_t idx = (size_t)(row0 + r) * FPc + f;
      if (EPI == 0) {
        Y[idx] = acc[r];
      } else if (EPI == 1) {
        float v = acc[r] + bias[f];
        Y[idx] = v;           // raw atom_lin
        Y2[idx] = leaky(v);   // atom_feature / h init
      } else { // EPI == 2
        float v = fmaf(sumw[row0 + r], bias[f], acc[r]);
        Y[idx] = eluf(v);
      }
    }
  }
}

// -------------------- fused GRU: h' and act for 8 rows per block ---------------------
__global__ __launch_bounds__(256) void gru8(
    const float* __restrict__ XC,            // ctx rows [rows][200]
    float* __restrict__ H,                   // in-place hidden [rows][200]
    const float* __restrict__ WihT, const float* __restrict__ WhhT,  // [200][600]
    const float* __restrict__ bih, const float* __restrict__ bhh,    // [600]
    float* __restrict__ actOut, float* __restrict__ unbOut, float* __restrict__ vizOut) {
  constexpr int TR = 8, LDP = 12;
  __shared__ float xc[FPc * LDP];
  __shared__ float xh[FPc * LDP];
  const int row0 = blockIdx.x * TR;
  const int tid = threadIdx.x;
  for (int e = tid; e < TR * FPc; e += 256) {
    int r = e / FPc, g = e - r * FPc;
    xc[g * LDP + r] = XC[(size_t)row0 * FPc + e];
    xh[g * LDP + r] = H[(size_t)row0 * FPc + e];
  }
  __syncthreads();
  const int f = tid;
  if (f < FPc) {
    float air[8], aiz[8], ain[8], ahr[8], ahz[8], ahn[8];
    const float bir = bih[f], biz = bih[f + 200], bin_ = bih[f + 400];
    const float bhr = bhh[f], bhz = bhh[f + 200], bhn = bhh[f + 400];
    #pragma unroll
    for (int r = 0; r < 8; ++r) {
      air[r] = bir; aiz[r] = biz; ain[r] = bin_;
      ahr[r] = bhr; ahz[r] = bhz; ahn[r] = bhn;
    }
    #pragma unroll 2
    for (int g = 0; g < FPc; ++g) {
      const float* wi = &WihT[(size_t)g * 600 + f];
      const float* wh = &WhhT[(size_t)g * 600 + f];
      float wir = wi[0], wiz = wi[200], win = wi[400];
      float whr = wh[0], whz = wh[200], whn = wh[400];
      float4 c0 = *reinterpret_cast<const float4*>(&xc[g * LDP]);
      float4 c1 = *reinterpret_cast<const float4*>(&xc[g * LDP + 4]);
      float4 h0 = *reinterpret_cast<const float4*>(&xh[g * LDP]);
      float4 h1 = *reinterpret_cast<const float4*>(&xh[g * LDP + 4]);
      float cx[8] = {c0.x, c0.y, c0.z, c0.w, c1.x, c1.y, c1.z, c1.w};
      float hx[8] = {h0.x, h0.y, h0.z, h0.w, h1.x, h1.y, h1.z, h1.w};
      #pragma unroll
      for (int r = 0; r < 8; ++r) {
        air[r] = fmaf(cx[r], wir, air[r]);
        aiz[r] = fmaf(cx[r], wiz, aiz[r]);
        ain[r] = fmaf(cx[r], win, ain[r]);
        ahr[r] = fmaf(hx[r], whr, ahr[r]);
        ahz[r] = fmaf(hx[r], whz, ahz[r]);
        ahn[r] = fmaf(hx[r], whn, ahn[r]);
      }
    }
    #pragma unroll
    for (int r = 0; r < 8; ++r) {
      float rg = sigm(air[r] + ahr[r]);
      float zg = sigm(aiz[r] + ahz[r]);
      float ng = tanhf(fmaf(rg, ahn[r], ain[r]));
      float hv = xh[f * LDP + r];
      float hp = (1.f - zg) * ng + zg * hv;
      size_t idx = (size_t)(row0 + r) * FPc + f;
      H[idx] = hp;
      float a = fmaxf(hp, 0.f);
      if (actOut) actOut[idx] = a;
      if (unbOut) unbOut[idx] = hp;
      if (vizOut) vizOut[idx] = a;
    }
  }
}

// -------------------- per-(b,l) neighbor attention round -----------------------------
// one wave per row; neighbor rows staged in LDS
__global__ __launch_bounds__(256) void attn_round(
    int r,
    const float* __restrict__ cur,   // [BL][200]
    const float* __restrict__ act,   // neigh source for r>=1
    const float* __restrict__ P, const float* __restrict__ Q, const float* __restrict__ nbb,
    const int* __restrict__ adl, const int* __restrict__ bdl,
    const float* __restrict__ alW,   // align_W + r*400
    const float* __restrict__ alb,   // align_b (len R)
    float* __restrict__ attnOut,     // attn_viz + r*BL*K
    float* __restrict__ WN, float* __restrict__ sumwOut) {
  __shared__ float nb[4][Kc][FPc];
  const int wv = threadIdx.x >> 6, lane = threadIdx.x & 63;
  const int row = blockIdx.x * 4 + wv;
  const int b = row >> 7;
  int ai[Kc];
  #pragma unroll
  for (int k = 0; k < Kc; ++k) ai[k] = adl[(size_t)row * Kc + k];
  if (r == 0) {
    int bi[Kc];
    #pragma unroll
    for (int k = 0; k < Kc; ++k) bi[k] = bdl[(size_t)row * Kc + k];
    #pragma unroll
    for (int k = 0; k < Kc; ++k)
      for (int f = lane; f < FPc; f += 64) {
        float v = P[((size_t)(b * Lc + ai[k])) * FPc + f]
                + Q[((size_t)(b * Lc + bi[k])) * FPc + f] + nbb[f];
        nb[wv][k][f] = leaky(v);
      }
  } else {
    #pragma unroll
    for (int k = 0; k < Kc; ++k)
      for (int f = lane; f < FPc; f += 64)
        nb[wv][k][f] = act[((size_t)(b * Lc + ai[k])) * FPc + f];
  }
  __syncthreads();
  // sa = cur . alW[0:200]
  float part = 0.f;
  for (int f = lane; f < FPc; f += 64) part = fmaf(cur[(size_t)row * FPc + f], alW[f], part);
  float sa = wave_sum(part);
  float s[Kc];
  #pragma unroll
  for (int k = 0; k < Kc; ++k) {
    float p = 0.f;
    for (int f = lane; f < FPc; f += 64) p = fmaf(nb[wv][k][f], alW[FPc + f], p);
    s[k] = wave_sum(p);
  }
  const float ab = alb[r];
  bool pad[Kc];
  float mx = -3.0e38f;
  #pragma unroll
  for (int k = 0; k < Kc; ++k) {
    pad[k] = (ai[k] == Lc - 1);
    s[k] = leaky(sa + s[k] + ab) + (pad[k] ? NEGC : 0.f);
    mx = fmaxf(mx, s[k]);
  }
  float e[Kc], sum = 0.f;
  #pragma unroll
  for (int k = 0; k < Kc; ++k) { e[k] = __expf(s[k] - mx); sum += e[k]; }
  float inv = 1.f / sum;
  float w[Kc], sw = 0.f;
  #pragma unroll
  for (int k = 0; k < Kc; ++k) { w[k] = pad[k] ? 0.f : e[k] * inv; sw += w[k]; }
  if (lane < Kc) attnOut[(size_t)row * Kc + lane] = w[lane];
  if (lane == 0) sumwOut[row] = sw;
  for (int f = lane; f < FPc; f += 64) {
    float a = 0.f;
    #pragma unroll
    for (int k = 0; k < Kc; ++k) a = fmaf(w[k], nb[wv][k][f], a);
    WN[(size_t)row * FPc + f] = a;
  }
}

// -------------------- mol-level sum over atoms ---------------------------------------
__global__ __launch_bounds__(256) void mol_sum_k(
    const float* __restrict__ H, const float* __restrict__ ACT, const float* __restrict__ mask,
    float* __restrict__ unb0, float* __restrict__ viz0,
    float* __restrict__ molfeat, float* __restrict__ actmol) {
  const int b = blockIdx.x;
  __shared__ float mk[Lc];
  for (int l = threadIdx.x; l < Lc; l += 256) mk[l] = mask[b * Lc + l];
  __syncthreads();
  const int f = threadIdx.x;
  if (f < FPc) {
    float s1 = 0.f, s2 = 0.f;
    for (int l = 0; l < Lc; ++l) {
      float m = mk[l];
      size_t idx = ((size_t)b * Lc + l) * FPc + f;
      s1 = fmaf(H[idx], m, s1);
      s2 = fmaf(ACT[idx], m, s2);
    }
    unb0[b * FPc + f] = s1;
    viz0[b * FPc + f] = s2;
    molfeat[b * FPc + f] = s2;
    actmol[b * FPc + f] = fmaxf(s2, 0.f);
  }
}

// -------------------- mol-level attention over L atoms -------------------------------
__global__ __launch_bounds__(256) void mol_attn_k(
    const float* __restrict__ act, const float* __restrict__ actmol,
    const float* __restrict__ malW, const float* __restrict__ malb,
    const float* __restrict__ mask,
    float* __restrict__ attnOut, float* __restrict__ wact, float* __restrict__ msumw) {
  const int b = blockIdx.x;
  __shared__ float sa_s;
  __shared__ float sn[Lc];
  __shared__ float wl[Lc];
  __shared__ float redmx[2], redsum[2], redsw[2];
  const int wv = threadIdx.x >> 6, lane = threadIdx.x & 63;
  if (wv == 0) {
    float p = 0.f;
    for (int f = lane; f < FPc; f += 64) p = fmaf(actmol[b * FPc + f], malW[f], p);
    float s = wave_sum(p);
    if (lane == 0) sa_s = s;
  }
  for (int l = wv; l < Lc; l += 4) {
    float p = 0.f;
    for (int f = lane; f < FPc; f += 64)
      p = fmaf(act[((size_t)b * Lc + l) * FPc + f], malW[FPc + f], p);
    float s = wave_sum(p);
    if (lane == 0) sn[l] = s;
  }
  __syncthreads();
  const int l = threadIdx.x;
  float sc = -3.0e38f, mval = 0.f;
  if (l < Lc) {
    mval = mask[b * Lc + l];
    sc = leaky(sa_s + sn[l] + malb[0]) + (mval == 0.f ? NEGC : 0.f);
  }
  float m = sc;
  #pragma unroll
  for (int o = 32; o >= 1; o >>= 1) m = fmaxf(m, __shfl_xor(m, o));
  if (lane == 0 && wv < 2) redmx[wv] = m;
  __syncthreads();
  float mx = fmaxf(redmx[0], redmx[1]);
  float e = (l < Lc) ? __expf(sc - mx) : 0.f;
  float s = e;
  #pragma unroll
  for (int o = 32; o >= 1; o >>= 1) s += __shfl_xor(s, o);
  if (lane == 0 && wv < 2) redsum[wv] = s;
  __syncthreads();
  float tot = redsum[0] + redsum[1];
  float w = 0.f;
  if (l < Lc) {
    w = e / tot * mval;
    wl[l] = w;
    attnOut[(size_t)b * Lc + l] = w;
  }
  float swp = w;
  #pragma unroll
  for (int o = 32; o >= 1; o >>= 1) swp += __shfl_xor(swp, o);
  if (lane == 0 && wv < 2) redsw[wv] = swp;
  __syncthreads();
  if (threadIdx.x == 0) msumw[b] = redsw[0] + redsw[1];
  const int f = threadIdx.x;
  if (f < FPc) {
    float a = 0.f;
    for (int l2 = 0; l2 < Lc; ++l2)
      a = fmaf(wl[l2], act[((size_t)b * Lc + l2) * FPc + f], a);
    wact[b * FPc + f] = a;
  }
}

// -------------------- final prediction -----------------------------------------------
__global__ __launch_bounds__(256) void pred_k(
    const float* __restrict__ molfeat, const float* __restrict__ outW,
    const float* __restrict__ outb, float* __restrict__ pred) {
  const int wv = threadIdx.x >> 6, lane = threadIdx.x & 63;
  const int b = blockIdx.x * 4 + wv;
  if (b < Bc) {
    float p = 0.f;
    for (int f = lane; f < FPc; f += 64) p = fmaf(molfeat[b * FPc + f], outW[f], p);
    float s = wave_sum(p);
    if (lane == 0) pred[b] = s + outb[0];
  }
}

extern "C" void kernel_launch(void* const* d_in, const int* in_sizes, int n_in,
                              void* d_out, int out_size, void* d_ws, size_t ws_size,
                              hipStream_t stream) {
  const float* atom_list = (const float*)d_in[0];
  const float* bond_list = (const float*)d_in[1];
  const int*   adl       = (const int*)d_in[2];
  const int*   bdl       = (const int*)d_in[3];
  const float* mask      = (const float*)d_in[4];
  const float* atom_fc_W = (const float*)d_in[5];
  const float* atom_fc_b = (const float*)d_in[6];
  const float* nb_W      = (const float*)d_in[7];
  const float* nb_b      = (const float*)d_in[8];
  const float* align_W   = (const float*)d_in[9];
  const float* align_b   = (const float*)d_in[10];
  const float* attend_W  = (const float*)d_in[11];
  const float* attend_b  = (const float*)d_in[12];
  const float* gru_Wih   = (const float*)d_in[13];
  const float* gru_Whh   = (const float*)d_in[14];
  const float* gru_bih   = (const float*)d_in[15];
  const float* gru_bhh   = (const float*)d_in[16];
  const float* mal_W     = (const float*)d_in[17];
  const float* mal_b     = (const float*)d_in[18];
  const float* matt_W    = (const float*)d_in[19];
  const float* matt_b    = (const float*)d_in[20];
  const float* mWih      = (const float*)d_in[21];
  const float* mWhh      = (const float*)d_in[22];
  const float* mbih      = (const float*)d_in[23];
  const float* mbhh      = (const float*)d_in[24];
  const float* out_W     = (const float*)d_in[25];
  const float* out_b     = (const float*)d_in[26];

  float* out  = (float*)d_out;
  float* AV   = out;                                  // (4,B,L,FP)
  float* ATTN = AV + (size_t)4 * BL * FPc;            // (3,B,L,K)
  float* MV   = ATTN + (size_t)Rc * BL * Kc;          // (3,B,FP)
  float* MU   = MV + (size_t)3 * Bc * FPc;            // (3,B,FP)
  float* MA   = MU + (size_t)3 * Bc * FPc;            // (2,B,L)
  float* PRED = MA + (size_t)Tc * Bc * Lc;            // (B,1)

  float* ws   = (float*)d_ws;
  float* H    = ws;
  float* Pb   = H  + (size_t)BL * FPc;
  float* Qb   = Pb + (size_t)BL * FPc;
  float* WN   = Qb + (size_t)BL * FPc;
  float* SW   = WN + (size_t)BL * FPc;   // [BL]
  float* MOLF = SW + BL;
  float* ACTM = MOLF + Bc * FPc;
  float* WACT = ACTM + Bc * FPc;
  float* MSW  = WACT + Bc * FPc;
  float* MCTX = MSW + Bc;
  float* WT0  = MCTX + Bc * FPc;
  float* atomfcT = WT0;                               // [39][200]
  float* naT     = atomfcT + AFc * FPc;               // [49][200]
  float* attT    = naT + (AFc + BFc) * FPc;           // 3*[200][200]
  float* WihT    = attT + 3 * FPc * FPc;              // 3*[200][600]
  float* WhhT    = WihT + 3 * FPc * 600;
  float* mattT   = WhhT + 3 * FPc * 600;              // [200][200]
  float* mWihT   = mattT + FPc * FPc;                 // [200][600]
  float* mWhhT   = mWihT + FPc * 600;

  transpose_k<<<64, 256, 0, stream>>>(atom_fc_W, atomfcT, FPc, AFc);
  transpose_k<<<64, 256, 0, stream>>>(nb_W, naT, FPc, AFc + BFc);
  for (int r = 0; r < Rc; ++r) {
    transpose_k<<<64, 256, 0, stream>>>(attend_W + (size_t)r * FPc * FPc, attT + (size_t)r * FPc * FPc, FPc, FPc);
    transpose_k<<<64, 256, 0, stream>>>(gru_Wih + (size_t)r * 600 * FPc, WihT + (size_t)r * FPc * 600, 600, FPc);
    transpose_k<<<64, 256, 0, stream>>>(gru_Whh + (size_t)r * 600 * FPc, WhhT + (size_t)r * FPc * 600, 600, FPc);
  }
  transpose_k<<<64, 256, 0, stream>>>(matt_W, mattT, FPc, FPc);
  transpose_k<<<64, 256, 0, stream>>>(mWih, mWihT, 600, FPc);
  transpose_k<<<64, 256, 0, stream>>>(mWhh, mWhhT, 600, FPc);

  // atom_lin (raw -> AV[0]) + atom_feature (leaky -> H)
  gemm8x1<AFc, 1><<<BL / 8, 256, 0, stream>>>(atom_list, atomfcT, atom_fc_b, nullptr, AV, H);
  // P = atom_list @ Wa.T ; Q = bond_list @ Wb.T  (neighbor_fc split, bias folded later)
  gemm8x1<AFc, 0><<<BL / 8, 256, 0, stream>>>(atom_list, naT, nullptr, nullptr, Pb, nullptr);
  gemm8x1<BFc, 0><<<BL / 8, 256, 0, stream>>>(bond_list, naT + AFc * FPc, nullptr, nullptr, Qb, nullptr);

  for (int r = 0; r < Rc; ++r) {
    const float* curp = (r == 0) ? H : AV + (size_t)r * BL * FPc;
    attn_round<<<BL / 4, 256, 0, stream>>>(r, curp, AV + (size_t)r * BL * FPc,
        Pb, Qb, nb_b, adl, bdl, align_W + (size_t)r * 2 * FPc, align_b,
        ATTN + (size_t)r * BL * Kc, WN, SW);
    // ctx = elu(WN @ attT + sumw*attend_b), in-place in WN
    gemm8x1<FPc, 2><<<BL / 8, 256, 0, stream>>>(WN, attT + (size_t)r * FPc * FPc,
        attend_b + (size_t)r * FPc, SW, WN, nullptr);
    gru8<<<BL / 8, 256, 0, stream>>>(WN, H, WihT + (size_t)r * FPc * 600, WhhT + (size_t)r * FPc * 600,
        gru_bih + (size_t)r * 600, gru_bhh + (size_t)r * 600,
        AV + (size_t)(r + 1) * BL * FPc, nullptr, nullptr);
  }

  mol_sum_k<<<Bc, 256, 0, stream>>>(H, AV + (size_t)3 * BL * FPc, mask, MU, MV, MOLF, ACTM);
  for (int t = 0; t < Tc; ++t) {
    mol_attn_k<<<Bc, 256, 0, stream>>>(AV + (size_t)3 * BL * FPc, ACTM, mal_W, mal_b, mask,
        MA + (size_t)t * Bc * Lc, WACT, MSW);
    gemm8x1<FPc, 2><<<Bc / 8, 256, 0, stream>>>(WACT, mattT, matt_b, MSW, MCTX, nullptr);
    gru8<<<Bc / 8, 256, 0, stream>>>(MCTX, MOLF, mWihT, mWhhT, mbih, mbhh,
        ACTM, MU + (size_t)(t + 1) * Bc * FPc, MV + (size_t)(t + 1) * Bc * FPc);
  }
  pred_k<<<Bc / 4, 256, 0, stream>>>(MOLF, out_W, out_b, PRED);
}

// Round 2
// 1938.807 us; speedup vs baseline: 1.5792x; 1.5792x over previous
//
#include <hip/hip_runtime.h>
#include <stdint.h>

#define Bc 512
#define Lc 128
#define Kc 6
#define AFc 39
#define BFc 10
#define FPc 200
#define Rc 3
#define Tc 2
constexpr int BL = Bc * Lc;          // 65536
constexpr int KP = 224;              // padded K / F for MFMA
constexpr float SLOPE = 0.01f;
constexpr float NEGC = -9e8f;

typedef __attribute__((ext_vector_type(8))) __bf16 bf16x8;
typedef __attribute__((ext_vector_type(16))) float f32x16;

__device__ __forceinline__ float leaky(float x) { return x >= 0.f ? x : SLOPE * x; }
__device__ __forceinline__ float sigm(float x) { return 1.f / (1.f + __expf(-x)); }
__device__ __forceinline__ float eluf(float x) { return x > 0.f ? x : expm1f(x); }
__device__ __forceinline__ float wave_sum(float v) {
  #pragma unroll
  for (int m = 32; m >= 1; m >>= 1) v += __shfl_xor(v, m);
  return v;
}
__device__ __forceinline__ void glds16(const void* g, void* l) {
  __builtin_amdgcn_global_load_lds((const __attribute__((address_space(1))) uint32_t*)g,
      (__attribute__((address_space(3))) uint32_t*)l, 16, 0, 0);
}
__device__ __forceinline__ f32x16 zero16() {
  f32x16 z;
  #pragma unroll
  for (int i = 0; i < 16; ++i) z[i] = 0.f;
  return z;
}

// -------------------- weight transpose: out[c*R + r] = in[r*C + c] --------------------
__global__ void transpose_k(const float* __restrict__ in, float* __restrict__ out, int R, int C) {
  int n = R * C;
  for (int i = blockIdx.x * blockDim.x + threadIdx.x; i < n; i += gridDim.x * blockDim.x) {
    int r = i / C, c = i - r * C;
    out[c * R + r] = in[i];
  }
}

// -------------------- pack GRU weights: Wpk[r][g][f(224)][k(224)] bf16 ----------------
__global__ void pack_gru_k(const float* __restrict__ Wih, const float* __restrict__ Whh,
                           __bf16* __restrict__ Wpk) {
  int i = blockIdx.x * 256 + threadIdx.x;
  if (i >= Rc * 6 * KP * KP) return;
  int k = i % KP; int t = i / KP; int f = t % KP; t /= KP; int g = t % 6; int r = t / 6;
  float v = 0.f;
  if (f < FPc && k < FPc) {
    if (g < 3) v = Wih[((size_t)r * 3 * FPc + g * FPc + f) * FPc + k];
    else       v = Whh[((size_t)r * 3 * FPc + (g - 3) * FPc + f) * FPc + k];
  }
  Wpk[i] = (__bf16)v;
}

// -------------------- pack attend weights: Apk[r][f(224)][k(224)] bf16 ----------------
__global__ void pack_att_k(const float* __restrict__ W, __bf16* __restrict__ Apk) {
  int i = blockIdx.x * 256 + threadIdx.x;
  if (i >= Rc * KP * KP) return;
  int k = i % KP; int t = i / KP; int f = t % KP; int r = t / KP;
  float v = (f < FPc && k < FPc) ? W[((size_t)r * FPc + f) * FPc + k] : 0.f;
  Apk[i] = (__bf16)v;
}

// -------------------- generic small GEMM (f32): Y[rows][200] ------------------------
// EPI: 0 = write bf16 raw (stride 200), 1 = raw->Y(f32) + leaky->Yb(bf16, stride KP, pads),
//      2 = elu(acc + sumw*bias) -> Y(f32)
template<int KD, int EPI>
__global__ __launch_bounds__(256) void gemm8x1(
    const float* __restrict__ X, const float* __restrict__ WT,
    const float* __restrict__ bias, const float* __restrict__ sumw,
    float* __restrict__ Y, __bf16* __restrict__ Yb) {
  constexpr int TR = 8, LDP = 12;
  __shared__ float xT[KD * LDP];
  const int row0 = blockIdx.x * TR;
  const int tid = threadIdx.x;
  for (int e = tid; e < TR * KD; e += 256) {
    int r = e / KD, g = e - r * KD;
    xT[g * LDP + r] = X[(size_t)row0 * KD + e];
  }
  __syncthreads();
  const int f = tid;
  if (f < FPc) {
    float acc[TR];
    #pragma unroll
    for (int r = 0; r < TR; ++r) acc[r] = 0.f;
    #pragma unroll 4
    for (int g = 0; g < KD; ++g) {
      float w = WT[(size_t)g * FPc + f];
      float4 x0 = *reinterpret_cast<const float4*>(&xT[g * LDP]);
      float4 x1 = *reinterpret_cast<const float4*>(&xT[g * LDP + 4]);
      acc[0] = fmaf(x0.x, w, acc[0]); acc[1] = fmaf(x0.y, w, acc[1]);
      acc[2] = fmaf(x0.z, w, acc[2]); acc[3] = fmaf(x0.w, w, acc[3]);
      acc[4] = fmaf(x1.x, w, acc[4]); acc[5] = fmaf(x1.y, w, acc[5]);
      acc[6] = fmaf(x1.z, w, acc[6]); acc[7] = fmaf(x1.w, w, acc[7]);
    }
    #pragma unroll
    for (int r = 0; r < TR; ++r) {
      if (EPI == 0) {
        Yb[(size_t)(row0 + r) * FPc + f] = (__bf16)acc[r];
      } else if (EPI == 1) {
        float v = acc[r] + bias[f];
        Y[(size_t)(row0 + r) * FPc + f] = v;              // raw atom_lin (viz)
        Yb[(size_t)(row0 + r) * KP + f] = (__bf16)leaky(v); // h0
      } else {
        float v = fmaf(sumw[row0 + r], bias[f], acc[r]);
        Y[(size_t)(row0 + r) * FPc + f] = eluf(v);
      }
    }
  } else if (EPI == 1 && f < KP) {
    #pragma unroll
    for (int r = 0; r < TR; ++r) Yb[(size_t)(row0 + r) * KP + f] = (__bf16)0.f;
  }
}

// -------------------- MFMA GRU: 128 rows/block, 6 gates fused ------------------------
__global__ __launch_bounds__(256) void gru_mfma(
    const __bf16* __restrict__ XCb, const __bf16* __restrict__ Hin,
    __bf16* __restrict__ Hout, const __bf16* __restrict__ Wpk,
    const float* __restrict__ bih, const float* __restrict__ bhh,
    float* __restrict__ actOut) {
  __shared__ __bf16 As[2][2][128][32];   // [buf][xc/h][row][k] 32 KB
  __shared__ __bf16 Bs[2][6][32][32];    // [buf][gate][f][k]   24 KB
  const int tid = threadIdx.x, wv = tid >> 6, lane = tid & 63;
  const size_t row0 = (size_t)blockIdx.x * 128;

  auto stage = [&](int it, int buf) {
    int ft = it / 7, kt = it % 7;
    int k0 = kt * 32, f0 = ft * 32;
    #pragma unroll
    for (int j = 0; j < 2; ++j) {
      int rr = wv * 32 + j * 16 + (lane >> 2);
      size_t so = (row0 + rr) * KP + k0 + (lane & 3) * 8;
      glds16(XCb + so, &As[buf][0][wv * 32 + j * 16][0] + (size_t)lane * 8);
      glds16(Hin + so, &As[buf][1][wv * 32 + j * 16][0] + (size_t)lane * 8);
    }
    #pragma unroll
    for (int j = 0; j < 3; ++j) {
      int m = wv + 4 * j;            // 0..11
      int g = m >> 1, hf = m & 1;
      int fr = f0 + hf * 16 + (lane >> 2);
      size_t so = ((size_t)g * KP + fr) * KP + k0 + (lane & 3) * 8;
      glds16(Wpk + so, &Bs[buf][g][hf * 16][0] + (size_t)lane * 8);
    }
  };

  f32x16 acc[6];
  #pragma unroll
  for (int g = 0; g < 6; ++g) acc[g] = zero16();

  stage(0, 0);
  __syncthreads();
  for (int it = 0; it < 49; ++it) {
    int buf = it & 1;
    int kt = it % 7, ft = it / 7;
    if (it + 1 < 49) stage(it + 1, buf ^ 1);
    #pragma unroll
    for (int h = 0; h < 2; ++h) {
      const int ko = h * 16 + (lane >> 5) * 8;
      bf16x8 axc = *(const bf16x8*)&As[buf][0][wv * 32 + (lane & 31)][ko];
      bf16x8 ah  = *(const bf16x8*)&As[buf][1][wv * 32 + (lane & 31)][ko];
      bf16x8 b0 = *(const bf16x8*)&Bs[buf][0][lane & 31][ko];
      bf16x8 b1 = *(const bf16x8*)&Bs[buf][1][lane & 31][ko];
      bf16x8 b2 = *(const bf16x8*)&Bs[buf][2][lane & 31][ko];
      bf16x8 b3 = *(const bf16x8*)&Bs[buf][3][lane & 31][ko];
      bf16x8 b4 = *(const bf16x8*)&Bs[buf][4][lane & 31][ko];
      bf16x8 b5 = *(const bf16x8*)&Bs[buf][5][lane & 31][ko];
      acc[0] = __builtin_amdgcn_mfma_f32_32x32x16_bf16(axc, b0, acc[0], 0, 0, 0);
      acc[1] = __builtin_amdgcn_mfma_f32_32x32x16_bf16(axc, b1, acc[1], 0, 0, 0);
      acc[2] = __builtin_amdgcn_mfma_f32_32x32x16_bf16(axc, b2, acc[2], 0, 0, 0);
      acc[3] = __builtin_amdgcn_mfma_f32_32x32x16_bf16(ah,  b3, acc[3], 0, 0, 0);
      acc[4] = __builtin_amdgcn_mfma_f32_32x32x16_bf16(ah,  b4, acc[4], 0, 0, 0);
      acc[5] = __builtin_amdgcn_mfma_f32_32x32x16_bf16(ah,  b5, acc[5], 0, 0, 0);
    }
    if (kt == 6) {
      int f = ft * 32 + (lane & 31);
      float bir = 0, biz = 0, bin_ = 0, bhr = 0, bhz = 0, bhn = 0;
      if (f < FPc) {
        bir = bih[f]; biz = bih[FPc + f]; bin_ = bih[2 * FPc + f];
        bhr = bhh[f]; bhz = bhh[FPc + f]; bhn = bhh[2 * FPc + f];
      }
      #pragma unroll
      for (int reg = 0; reg < 16; ++reg) {
        int rl = (reg & 3) + 8 * (reg >> 2) + 4 * (lane >> 5);
        size_t row = row0 + wv * 32 + rl;
        if (f < FPc) {
          float rg = sigm(acc[0][reg] + bir + acc[3][reg] + bhr);
          float zg = sigm(acc[1][reg] + biz + acc[4][reg] + bhz);
          float ng = tanhf(acc[2][reg] + bin_ + rg * (acc[5][reg] + bhn));
          float ho = (float)Hin[row * KP + f];
          float hp = (1.f - zg) * ng + zg * ho;
          Hout[row * KP + f] = (__bf16)hp;
          actOut[row * FPc + f] = fmaxf(hp, 0.f);
        } else {
          Hout[row * KP + f] = (__bf16)0.f;
        }
      }
      #pragma unroll
      for (int g = 0; g < 6; ++g) acc[g] = zero16();
    }
    __syncthreads();
  }
}

// -------------------- MFMA attend: ctx = elu(WN @ attW.T + sumw*b) -------------------
__global__ __launch_bounds__(256) void attend_mfma(
    const __bf16* __restrict__ WNb, const __bf16* __restrict__ Apk,
    const float* __restrict__ bias, const float* __restrict__ SW,
    __bf16* __restrict__ XCb) {
  __shared__ __bf16 As[2][128][32];  // 16 KB
  __shared__ __bf16 Bs[2][32][32];   // 4 KB
  const int tid = threadIdx.x, wv = tid >> 6, lane = tid & 63;
  const size_t row0 = (size_t)blockIdx.x * 128;

  auto stage = [&](int it, int buf) {
    int ft = it / 7, kt = it % 7;
    int k0 = kt * 32, f0 = ft * 32;
    #pragma unroll
    for (int j = 0; j < 2; ++j) {
      int rr = wv * 32 + j * 16 + (lane >> 2);
      size_t so = (row0 + rr) * KP + k0 + (lane & 3) * 8;
      glds16(WNb + so, &As[buf][wv * 32 + j * 16][0] + (size_t)lane * 8);
    }
    if (wv < 2) {
      int fr = f0 + wv * 16 + (lane >> 2);
      size_t so = (size_t)fr * KP + k0 + (lane & 3) * 8;
      glds16(Apk + so, &Bs[buf][wv * 16][0] + (size_t)lane * 8);
    }
  };

  f32x16 acc = zero16();
  stage(0, 0);
  __syncthreads();
  for (int it = 0; it < 49; ++it) {
    int buf = it & 1;
    int kt = it % 7, ft = it / 7;
    if (it + 1 < 49) stage(it + 1, buf ^ 1);
    #pragma unroll
    for (int h = 0; h < 2; ++h) {
      const int ko = h * 16 + (lane >> 5) * 8;
      bf16x8 a = *(const bf16x8*)&As[buf][wv * 32 + (lane & 31)][ko];
      bf16x8 b = *(const bf16x8*)&Bs[buf][lane & 31][ko];
      acc = __builtin_amdgcn_mfma_f32_32x32x16_bf16(a, b, acc, 0, 0, 0);
    }
    if (kt == 6) {
      int f = ft * 32 + (lane & 31);
      float bf = (f < FPc) ? bias[f] : 0.f;
      #pragma unroll
      for (int reg = 0; reg < 16; ++reg) {
        int rl = (reg & 3) + 8 * (reg >> 2) + 4 * (lane >> 5);
        size_t row = row0 + wv * 32 + rl;
        if (f < FPc) {
          float v = acc[reg] + SW[row] * bf;
          XCb[row * KP + f] = (__bf16)eluf(v);
        } else {
          XCb[row * KP + f] = (__bf16)0.f;
        }
      }
      acc = zero16();
    }
    __syncthreads();
  }
}

// -------------------- per-(b,l) neighbor attention round -----------------------------
__global__ __launch_bounds__(256) void attn_round(
    int r,
    const float* __restrict__ cur,   // r==0: raw atom_lin (leaky applied on the fly)
    const float* __restrict__ act,   // neigh source for r>=1 (f32)
    const __bf16* __restrict__ P, const __bf16* __restrict__ Q, const float* __restrict__ nbb,
    const int* __restrict__ adl, const int* __restrict__ bdl,
    const float* __restrict__ alW, const float* __restrict__ alb,
    float* __restrict__ attnOut,
    __bf16* __restrict__ WNb, float* __restrict__ sumwOut) {
  __shared__ float nb[4][Kc][FPc];
  const int wv = threadIdx.x >> 6, lane = threadIdx.x & 63;
  const int row = blockIdx.x * 4 + wv;
  const int b = row >> 7;
  int ai[Kc];
  #pragma unroll
  for (int k = 0; k < Kc; ++k) ai[k] = adl[(size_t)row * Kc + k];
  if (r == 0) {
    int bi[Kc];
    #pragma unroll
    for (int k = 0; k < Kc; ++k) bi[k] = bdl[(size_t)row * Kc + k];
    #pragma unroll
    for (int k = 0; k < Kc; ++k)
      for (int f = lane; f < FPc; f += 64) {
        float v = (float)P[((size_t)(b * Lc + ai[k])) * FPc + f]
                + (float)Q[((size_t)(b * Lc + bi[k])) * FPc + f] + nbb[f];
        nb[wv][k][f] = leaky(v);
      }
  } else {
    #pragma unroll
    for (int k = 0; k < Kc; ++k)
      for (int f = lane; f < FPc; f += 64)
        nb[wv][k][f] = act[((size_t)(b * Lc + ai[k])) * FPc + f];
  }
  __syncthreads();
  float part = 0.f;
  for (int f = lane; f < FPc; f += 64) {
    float cv = cur[(size_t)row * FPc + f];
    if (r == 0) cv = leaky(cv);
    part = fmaf(cv, alW[f], part);
  }
  float sa = wave_sum(part);
  float s[Kc];
  #pragma unroll
  for (int k = 0; k < Kc; ++k) {
    float p = 0.f;
    for (int f = lane; f < FPc; f += 64) p = fmaf(nb[wv][k][f], alW[FPc + f], p);
    s[k] = wave_sum(p);
  }
  const float ab = alb[r];
  bool pad[Kc];
  float mx = -3.0e38f;
  #pragma unroll
  for (int k = 0; k < Kc; ++k) {
    pad[k] = (ai[k] == Lc - 1);
    s[k] = leaky(sa + s[k] + ab) + (pad[k] ? NEGC : 0.f);
    mx = fmaxf(mx, s[k]);
  }
  float e[Kc], sum = 0.f;
  #pragma unroll
  for (int k = 0; k < Kc; ++k) { e[k] = __expf(s[k] - mx); sum += e[k]; }
  float inv = 1.f / sum;
  float w[Kc], sw = 0.f;
  #pragma unroll
  for (int k = 0; k < Kc; ++k) { w[k] = pad[k] ? 0.f : e[k] * inv; sw += w[k]; }
  if (lane < Kc) attnOut[(size_t)row * Kc + lane] = w[lane];
  if (lane == 0) sumwOut[row] = sw;
  for (int f = lane; f < KP; f += 64) {
    float a = 0.f;
    if (f < FPc) {
      #pragma unroll
      for (int k = 0; k < Kc; ++k) a = fmaf(w[k], nb[wv][k][f], a);
    }
    WNb[(size_t)row * KP + f] = (__bf16)a;
  }
}

// -------------------- fused GRU f32 (mol path, 512 rows) -----------------------------
__global__ __launch_bounds__(256) void gru8(
    const float* __restrict__ XC, float* __restrict__ H,
    const float* __restrict__ WihT, const float* __restrict__ WhhT,
    const float* __restrict__ bih, const float* __restrict__ bhh,
    float* __restrict__ actOut, float* __restrict__ unbOut, float* __restrict__ vizOut) {
  constexpr int TR = 8, LDP = 12;
  __shared__ float xc[FPc * LDP];
  __shared__ float xh[FPc * LDP];
  const int row0 = blockIdx.x * TR;
  const int tid = threadIdx.x;
  for (int e = tid; e < TR * FPc; e += 256) {
    int r = e / FPc, g = e - r * FPc;
    xc[g * LDP + r] = XC[(size_t)row0 * FPc + e];
    xh[g * LDP + r] = H[(size_t)row0 * FPc + e];
  }
  __syncthreads();
  const int f = tid;
  if (f < FPc) {
    float air[8], aiz[8], ain[8], ahr[8], ahz[8], ahn[8];
    const float bir = bih[f], biz = bih[f + 200], bin_ = bih[f + 400];
    const float bhr = bhh[f], bhz = bhh[f + 200], bhn = bhh[f + 400];
    #pragma unroll
    for (int r = 0; r < 8; ++r) {
      air[r] = bir; aiz[r] = biz; ain[r] = bin_;
      ahr[r] = bhr; ahz[r] = bhz; ahn[r] = bhn;
    }
    #pragma unroll 2
    for (int g = 0; g < FPc; ++g) {
      const float* wi = &WihT[(size_t)g * 600 + f];
      const float* wh = &WhhT[(size_t)g * 600 + f];
      float wir = wi[0], wiz = wi[200], win = wi[400];
      float whr = wh[0], whz = wh[200], whn = wh[400];
      float4 c0 = *reinterpret_cast<const float4*>(&xc[g * LDP]);
      float4 c1 = *reinterpret_cast<const float4*>(&xc[g * LDP + 4]);
      float4 h0 = *reinterpret_cast<const float4*>(&xh[g * LDP]);
      float4 h1 = *reinterpret_cast<const float4*>(&xh[g * LDP + 4]);
      float cx[8] = {c0.x, c0.y, c0.z, c0.w, c1.x, c1.y, c1.z, c1.w};
      float hx[8] = {h0.x, h0.y, h0.z, h0.w, h1.x, h1.y, h1.z, h1.w};
      #pragma unroll
      for (int r = 0; r < 8; ++r) {
        air[r] = fmaf(cx[r], wir, air[r]);
        aiz[r] = fmaf(cx[r], wiz, aiz[r]);
        ain[r] = fmaf(cx[r], win, ain[r]);
        ahr[r] = fmaf(hx[r], whr, ahr[r]);
        ahz[r] = fmaf(hx[r], whz, ahz[r]);
        ahn[r] = fmaf(hx[r], whn, ahn[r]);
      }
    }
    #pragma unroll
    for (int r = 0; r < 8; ++r) {
      float rg = sigm(air[r] + ahr[r]);
      float zg = sigm(aiz[r] + ahz[r]);
      float ng = tanhf(fmaf(rg, ahn[r], ain[r]));
      float hv = xh[f * LDP + r];
      float hp = (1.f - zg) * ng + zg * hv;
      size_t idx = (size_t)(row0 + r) * FPc + f;
      H[idx] = hp;
      float a = fmaxf(hp, 0.f);
      if (actOut) actOut[idx] = a;
      if (unbOut) unbOut[idx] = hp;
      if (vizOut) vizOut[idx] = a;
    }
  }
}

// -------------------- mol-level sum over atoms ---------------------------------------
__global__ __launch_bounds__(256) void mol_sum_k(
    const __bf16* __restrict__ Hb, const float* __restrict__ ACT, const float* __restrict__ mask,
    float* __restrict__ unb0, float* __restrict__ viz0,
    float* __restrict__ molfeat, float* __restrict__ actmol) {
  const int b = blockIdx.x;
  __shared__ float mk[Lc];
  for (int l = threadIdx.x; l < Lc; l += 256) mk[l] = mask[b * Lc + l];
  __syncthreads();
  const int f = threadIdx.x;
  if (f < FPc) {
    float s1 = 0.f, s2 = 0.f;
    for (int l = 0; l < Lc; ++l) {
      float m = mk[l];
      s1 = fmaf((float)Hb[((size_t)b * Lc + l) * KP + f], m, s1);
      s2 = fmaf(ACT[((size_t)b * Lc + l) * FPc + f], m, s2);
    }
    unb0[b * FPc + f] = s1;
    viz0[b * FPc + f] = s2;
    molfeat[b * FPc + f] = s2;
    actmol[b * FPc + f] = fmaxf(s2, 0.f);
  }
}

// -------------------- mol-level attention over L atoms -------------------------------
__global__ __launch_bounds__(256) void mol_attn_k(
    const float* __restrict__ act, const float* __restrict__ actmol,
    const float* __restrict__ malW, const float* __restrict__ malb,
    const float* __restrict__ mask,
    float* __restrict__ attnOut, float* __restrict__ wact, float* __restrict__ msumw) {
  const int b = blockIdx.x;
  __shared__ float sa_s;
  __shared__ float sn[Lc];
  __shared__ float wl[Lc];
  __shared__ float redmx[2], redsum[2], redsw[2];
  const int wv = threadIdx.x >> 6, lane = threadIdx.x & 63;
  if (wv == 0) {
    float p = 0.f;
    for (int f = lane; f < FPc; f += 64) p = fmaf(actmol[b * FPc + f], malW[f], p);
    float s = wave_sum(p);
    if (lane == 0) sa_s = s;
  }
  for (int l = wv; l < Lc; l += 4) {
    float p = 0.f;
    for (int f = lane; f < FPc; f += 64)
      p = fmaf(act[((size_t)b * Lc + l) * FPc + f], malW[FPc + f], p);
    float s = wave_sum(p);
    if (lane == 0) sn[l] = s;
  }
  __syncthreads();
  const int l = threadIdx.x;
  float sc = -3.0e38f, mval = 0.f;
  if (l < Lc) {
    mval = mask[b * Lc + l];
    sc = leaky(sa_s + sn[l] + malb[0]) + (mval == 0.f ? NEGC : 0.f);
  }
  float m = sc;
  #pragma unroll
  for (int o = 32; o >= 1; o >>= 1) m = fmaxf(m, __shfl_xor(m, o));
  if (lane == 0 && wv < 2) redmx[wv] = m;
  __syncthreads();
  float mx = fmaxf(redmx[0], redmx[1]);
  float e = (l < Lc) ? __expf(sc - mx) : 0.f;
  float s = e;
  #pragma unroll
  for (int o = 32; o >= 1; o >>= 1) s += __shfl_xor(s, o);
  if (lane == 0 && wv < 2) redsum[wv] = s;
  __syncthreads();
  float tot = redsum[0] + redsum[1];
  float w = 0.f;
  if (l < Lc) {
    w = e / tot * mval;
    wl[l] = w;
    attnOut[(size_t)b * Lc + l] = w;
  }
  float swp = w;
  #pragma unroll
  for (int o = 32; o >= 1; o >>= 1) swp += __shfl_xor(swp, o);
  if (lane == 0 && wv < 2) redsw[wv] = swp;
  __syncthreads();
  if (threadIdx.x == 0) msumw[b] = redsw[0] + redsw[1];
  const int f = threadIdx.x;
  if (f < FPc) {
    float a = 0.f;
    for (int l2 = 0; l2 < Lc; ++l2)
      a = fmaf(wl[l2], act[((size_t)b * Lc + l2) * FPc + f], a);
    wact[b * FPc + f] = a;
  }
}

// -------------------- final prediction -----------------------------------------------
__global__ __launch_bounds__(256) void pred_k(
    const float* __restrict__ molfeat, const float* __restrict__ outW,
    const float* __restrict__ outb, float* __restrict__ pred) {
  const int wv = threadIdx.x >> 6, lane = threadIdx.x & 63;
  const int b = blockIdx.x * 4 + wv;
  if (b < Bc) {
    float p = 0.f;
    for (int f = lane; f < FPc; f += 64) p = fmaf(molfeat[b * FPc + f], outW[f], p);
    float s = wave_sum(p);
    if (lane == 0) pred[b] = s + outb[0];
  }
}

extern "C" void kernel_launch(void* const* d_in, const int* in_sizes, int n_in,
                              void* d_out, int out_size, void* d_ws, size_t ws_size,
                              hipStream_t stream) {
  const float* atom_list = (const float*)d_in[0];
  const float* bond_list = (const float*)d_in[1];
  const int*   adl       = (const int*)d_in[2];
  const int*   bdl       = (const int*)d_in[3];
  const float* mask      = (const float*)d_in[4];
  const float* atom_fc_W = (const float*)d_in[5];
  const float* atom_fc_b = (const float*)d_in[6];
  const float* nb_W      = (const float*)d_in[7];
  const float* nb_b      = (const float*)d_in[8];
  const float* align_W   = (const float*)d_in[9];
  const float* align_b   = (const float*)d_in[10];
  const float* attend_W  = (const float*)d_in[11];
  const float* attend_b  = (const float*)d_in[12];
  const float* gru_Wih   = (const float*)d_in[13];
  const float* gru_Whh   = (const float*)d_in[14];
  const float* gru_bih   = (const float*)d_in[15];
  const float* gru_bhh   = (const float*)d_in[16];
  const float* mal_W     = (const float*)d_in[17];
  const float* mal_b     = (const float*)d_in[18];
  const float* matt_W    = (const float*)d_in[19];
  const float* matt_b    = (const float*)d_in[20];
  const float* mWih      = (const float*)d_in[21];
  const float* mWhh      = (const float*)d_in[22];
  const float* mbih      = (const float*)d_in[23];
  const float* mbhh      = (const float*)d_in[24];
  const float* out_W     = (const float*)d_in[25];
  const float* out_b     = (const float*)d_in[26];

  float* out  = (float*)d_out;
  float* AV   = out;                                  // (4,B,L,FP)
  float* ATTN = AV + (size_t)4 * BL * FPc;            // (3,B,L,K)
  float* MV   = ATTN + (size_t)Rc * BL * Kc;          // (3,B,FP)
  float* MU   = MV + (size_t)3 * Bc * FPc;            // (3,B,FP)
  float* MA   = MU + (size_t)3 * Bc * FPc;            // (2,B,L)
  float* PRED = MA + (size_t)Tc * Bc * Lc;            // (B,1)

  char* w = (char*)d_ws;
  __bf16* Hb0  = (__bf16*)w; w += (size_t)BL * KP * 2;
  __bf16* Hb1  = (__bf16*)w; w += (size_t)BL * KP * 2;
  __bf16* XCb  = (__bf16*)w; w += (size_t)BL * KP * 2;
  __bf16* WNb  = (__bf16*)w; w += (size_t)BL * KP * 2;
  __bf16* Pb   = (__bf16*)w; w += (size_t)BL * FPc * 2;
  __bf16* Qb   = (__bf16*)w; w += (size_t)BL * FPc * 2;
  __bf16* Wpk  = (__bf16*)w; w += (size_t)Rc * 6 * KP * KP * 2;
  __bf16* Apk  = (__bf16*)w; w += (size_t)Rc * KP * KP * 2;
  float* SW    = (float*)w;  w += (size_t)BL * 4;
  float* MOLF  = (float*)w;  w += (size_t)Bc * FPc * 4;
  float* ACTM  = (float*)w;  w += (size_t)Bc * FPc * 4;
  float* WACT  = (float*)w;  w += (size_t)Bc * FPc * 4;
  float* MCTX  = (float*)w;  w += (size_t)Bc * FPc * 4;
  float* MSW   = (float*)w;  w += (size_t)Bc * 4;
  float* atomfcT = (float*)w; w += (size_t)AFc * FPc * 4;
  float* naT     = (float*)w; w += (size_t)(AFc + BFc) * FPc * 4;
  float* mattT   = (float*)w; w += (size_t)FPc * FPc * 4;
  float* mWihT   = (float*)w; w += (size_t)FPc * 600 * 4;
  float* mWhhT   = (float*)w; w += (size_t)FPc * 600 * 4;

  transpose_k<<<64, 256, 0, stream>>>(atom_fc_W, atomfcT, FPc, AFc);
  transpose_k<<<64, 256, 0, stream>>>(nb_W, naT, FPc, AFc + BFc);
  transpose_k<<<64, 256, 0, stream>>>(matt_W, mattT, FPc, FPc);
  transpose_k<<<64, 256, 0, stream>>>(mWih, mWihT, 600, FPc);
  transpose_k<<<64, 256, 0, stream>>>(mWhh, mWhhT, 600, FPc);
  pack_gru_k<<<(Rc * 6 * KP * KP + 255) / 256, 256, 0, stream>>>(gru_Wih, gru_Whh, Wpk);
  pack_att_k<<<(Rc * KP * KP + 255) / 256, 256, 0, stream>>>(attend_W, Apk);

  // atom_lin raw -> AV[0], h0 = leaky -> Hb0 (bf16, padded)
  gemm8x1<AFc, 1><<<BL / 8, 256, 0, stream>>>(atom_list, atomfcT, atom_fc_b, nullptr, AV, Hb0);
  // P, Q (neighbor_fc split, bias folded in attn_round)
  gemm8x1<AFc, 0><<<BL / 8, 256, 0, stream>>>(atom_list, naT, nullptr, nullptr, nullptr, Pb);
  gemm8x1<BFc, 0><<<BL / 8, 256, 0, stream>>>(bond_list, naT + AFc * FPc, nullptr, nullptr, nullptr, Qb);

  __bf16* Hbuf[2] = {Hb0, Hb1};
  for (int r = 0; r < Rc; ++r) {
    const float* curp = (r == 0) ? AV : AV + (size_t)r * BL * FPc;
    attn_round<<<BL / 4, 256, 0, stream>>>(r, curp, AV + (size_t)r * BL * FPc,
        Pb, Qb, nb_b, adl, bdl, align_W + (size_t)r * 2 * FPc, align_b,
        ATTN + (size_t)r * BL * Kc, WNb, SW);
    attend_mfma<<<BL / 128, 256, 0, stream>>>(WNb, Apk + (size_t)r * KP * KP,
        attend_b + (size_t)r * FPc, SW, XCb);
    gru_mfma<<<BL / 128, 256, 0, stream>>>(XCb, Hbuf[r & 1], Hbuf[(r + 1) & 1],
        Wpk + (size_t)r * 6 * KP * KP, gru_bih + (size_t)r * 3 * FPc, gru_bhh + (size_t)r * 3 * FPc,
        AV + (size_t)(r + 1) * BL * FPc);
  }

  mol_sum_k<<<Bc, 256, 0, stream>>>(Hbuf[Rc & 1], AV + (size_t)3 * BL * FPc, mask, MU, MV, MOLF, ACTM);
  for (int t = 0; t < Tc; ++t) {
    mol_attn_k<<<Bc, 256, 0, stream>>>(AV + (size_t)3 * BL * FPc, ACTM, mal_W, mal_b, mask,
        MA + (size_t)t * Bc * Lc, WACT, MSW);
    gemm8x1<FPc, 2><<<Bc / 8, 256, 0, stream>>>(WACT, mattT, matt_b, MSW, MCTX, nullptr);
    gru8<<<Bc / 8, 256, 0, stream>>>(MCTX, MOLF, mWihT, mWhhT, mbih, mbhh,
        ACTM, MU + (size_t)(t + 1) * Bc * FPc, MV + (size_t)(t + 1) * Bc * FPc);
  }
  pred_k<<<Bc / 4, 256, 0, stream>>>(MOLF, out_W, out_b, PRED);
}

// Round 3
// 1593.789 us; speedup vs baseline: 1.9210x; 1.2165x over previous
//
#include <hip/hip_runtime.h>
#include <stdint.h>

#define Bc 512
#define Lc 128
#define Kc 6
#define AFc 39
#define BFc 10
#define FPc 200
#define Rc 3
#define Tc 2
constexpr int BL = Bc * Lc;          // 65536
constexpr int KP = 224;              // padded K / F for MFMA
constexpr float SLOPE = 0.01f;
constexpr float NEGC = -9e8f;

typedef __attribute__((ext_vector_type(8))) __bf16 bf16x8;
typedef __attribute__((ext_vector_type(16))) float f32x16;

__device__ __forceinline__ float leaky(float x) { return x >= 0.f ? x : SLOPE * x; }
__device__ __forceinline__ float sigm(float x) { return 1.f / (1.f + __expf(-x)); }
__device__ __forceinline__ float eluf(float x) { return x > 0.f ? x : expm1f(x); }
__device__ __forceinline__ float wave_sum(float v) {
  #pragma unroll
  for (int m = 32; m >= 1; m >>= 1) v += __shfl_xor(v, m);
  return v;
}
__device__ __forceinline__ void glds16(const void* g, void* l) {
  __builtin_amdgcn_global_load_lds((const __attribute__((address_space(1))) uint32_t*)g,
      (__attribute__((address_space(3))) uint32_t*)l, 16, 0, 0);
}
__device__ __forceinline__ f32x16 zero16() {
  f32x16 z;
  #pragma unroll
  for (int i = 0; i < 16; ++i) z[i] = 0.f;
  return z;
}

// -------------------- weight transpose: out[c*R + r] = in[r*C + c] --------------------
__global__ void transpose_k(const float* __restrict__ in, float* __restrict__ out, int R, int C) {
  int n = R * C;
  for (int i = blockIdx.x * blockDim.x + threadIdx.x; i < n; i += gridDim.x * blockDim.x) {
    int r = i / C, c = i - r * C;
    out[c * R + r] = in[i];
  }
}

// -------------------- pack GRU weights into staging-linear tiles ---------------------
// Wpk layout: [r][g6][ft7][kt7]{ tile 1024 elems: [c4][f32][j8] }
// tile element (c,fl,j) = W[g][ft*32+fl][kt*32+c*8+j], zero-padded past 200.
__global__ void pack_gru_k(const float* __restrict__ Wih, const float* __restrict__ Whh,
                           __bf16* __restrict__ Wpk) {
  int i = blockIdx.x * 256 + threadIdx.x;
  if (i >= Rc * 6 * 7 * 7 * 1024) return;
  int j = i & 7, fl = (i >> 3) & 31, c = (i >> 8) & 3;
  int T = i >> 10;
  int kt = T % 7; T /= 7;
  int ft = T % 7; T /= 7;
  int g = T % 6;  int r = T / 6;
  int f = ft * 32 + fl, k = kt * 32 + c * 8 + j;
  float v = 0.f;
  if (f < FPc && k < FPc) {
    if (g < 3) v = Wih[((size_t)r * 3 * FPc + g * FPc + f) * FPc + k];
    else       v = Whh[((size_t)r * 3 * FPc + (g - 3) * FPc + f) * FPc + k];
  }
  Wpk[i] = (__bf16)v;
}

// Apk layout: [r][ft7][kt7]{1024: [c4][f32][j8]}
__global__ void pack_att_k(const float* __restrict__ W, __bf16* __restrict__ Apk) {
  int i = blockIdx.x * 256 + threadIdx.x;
  if (i >= Rc * 7 * 7 * 1024) return;
  int j = i & 7, fl = (i >> 3) & 31, c = (i >> 8) & 3;
  int T = i >> 10;
  int kt = T % 7; T /= 7;
  int ft = T % 7; int r = T / 7;
  int f = ft * 32 + fl, k = kt * 32 + c * 8 + j;
  float v = (f < FPc && k < FPc) ? W[((size_t)r * FPc + f) * FPc + k] : 0.f;
  Apk[i] = (__bf16)v;
}

// -------------------- generic small GEMM (f32): Y[rows][200] ------------------------
template<int KD, int EPI>
__global__ __launch_bounds__(256) void gemm8x1(
    const float* __restrict__ X, const float* __restrict__ WT,
    const float* __restrict__ bias, const float* __restrict__ sumw,
    float* __restrict__ Y, __bf16* __restrict__ Yb) {
  constexpr int TR = 8, LDP = 12;
  __shared__ float xT[KD * LDP];
  const int row0 = blockIdx.x * TR;
  const int tid = threadIdx.x;
  for (int e = tid; e < TR * KD; e += 256) {
    int r = e / KD, g = e - r * KD;
    xT[g * LDP + r] = X[(size_t)row0 * KD + e];
  }
  __syncthreads();
  const int f = tid;
  if (f < FPc) {
    float acc[TR];
    #pragma unroll
    for (int r = 0; r < TR; ++r) acc[r] = 0.f;
    #pragma unroll 4
    for (int g = 0; g < KD; ++g) {
      float w = WT[(size_t)g * FPc + f];
      float4 x0 = *reinterpret_cast<const float4*>(&xT[g * LDP]);
      float4 x1 = *reinterpret_cast<const float4*>(&xT[g * LDP + 4]);
      acc[0] = fmaf(x0.x, w, acc[0]); acc[1] = fmaf(x0.y, w, acc[1]);
      acc[2] = fmaf(x0.z, w, acc[2]); acc[3] = fmaf(x0.w, w, acc[3]);
      acc[4] = fmaf(x1.x, w, acc[4]); acc[5] = fmaf(x1.y, w, acc[5]);
      acc[6] = fmaf(x1.z, w, acc[6]); acc[7] = fmaf(x1.w, w, acc[7]);
    }
    #pragma unroll
    for (int r = 0; r < TR; ++r) {
      if (EPI == 0) {
        Yb[(size_t)(row0 + r) * FPc + f] = (__bf16)acc[r];
      } else if (EPI == 1) {
        float v = acc[r] + bias[f];
        Y[(size_t)(row0 + r) * FPc + f] = v;                 // raw atom_lin (viz)
        Yb[(size_t)(row0 + r) * KP + f] = (__bf16)leaky(v);  // h0
      } else {
        float v = fmaf(sumw[row0 + r], bias[f], acc[r]);
        Y[(size_t)(row0 + r) * FPc + f] = eluf(v);
      }
    }
  } else if (EPI == 1 && f < KP) {
    #pragma unroll
    for (int r = 0; r < TR; ++r) Yb[(size_t)(row0 + r) * KP + f] = (__bf16)0.f;
  }
}

// -------------------- MFMA GRU v3: A-resident, conflict-free, counted vmcnt ----------
// block = 256 thr (4 waves x 32 rows = 128 rows). A (xc,h) staged once chunk-transposed:
// per array: [rg4][kt7][c4][row32][j8] (28672 elems, 56KB). B: [buf2][g6][c4][f32][j8].
__global__ __launch_bounds__(256, 1) void gru_mfma(
    const __bf16* __restrict__ XCb, const __bf16* __restrict__ Hin,
    __bf16* __restrict__ Hout, const __bf16* __restrict__ Wpk,
    const float* __restrict__ bih, const float* __restrict__ bhh,
    float* __restrict__ actOut) {
  __shared__ __align__(16) __bf16 smem[69632];   // 139264 B
  __bf16* Axc = smem;
  __bf16* Ah  = smem + 28672;
  __bf16* Bs  = smem + 57344;                    // 2 x 6144 elems
  const int tid = threadIdx.x, wv = tid >> 6, lane = tid & 63;
  const size_t row0 = (size_t)blockIdx.x * 128;

  // ---- A staging (each wave stages its own 32-row group; 28 calls/wave) ----
  {
    int rlo = lane & 31, chi = lane >> 5;
    const __bf16* sx = XCb + (row0 + wv * 32 + rlo) * KP + chi * 8;
    const __bf16* sh = Hin + (row0 + wv * 32 + rlo) * KP + chi * 8;
    #pragma unroll
    for (int kt = 0; kt < 7; ++kt) {
      #pragma unroll
      for (int hc = 0; hc < 2; ++hc) {
        glds16(sx + kt * 32 + hc * 16, Axc + wv * 7168 + kt * 1024 + hc * 512);
        glds16(sh + kt * 32 + hc * 16, Ah  + wv * 7168 + kt * 1024 + hc * 512);
      }
    }
  }
  auto stageB = [&](int t, int buf) {
    int ft = t / 7, kt = t % 7;
    #pragma unroll
    for (int m3 = 0; m3 < 3; ++m3) {
      int m = wv * 3 + m3;               // 0..11
      int g = m >> 1, half = m & 1;
      const __bf16* s = Wpk + ((size_t)(g * 7 + ft) * 7 + kt) * 1024 + half * 512 + lane * 8;
      glds16(s, Bs + buf * 6144 + g * 1024 + half * 512);
    }
  };
  stageB(0, 0);

  f32x16 acc[6];
  #pragma unroll
  for (int g = 0; g < 6; ++g) acc[g] = zero16();

  for (int it = 0; it < 49; ++it) {
    const int buf = it & 1;
    const int ft = it / 7, kt = it % 7;
    __builtin_amdgcn_sched_barrier(0);
    stageB(it + 1 < 49 ? it + 1 : 48, buf ^ 1);
    __builtin_amdgcn_sched_barrier(0);
    asm volatile("s_waitcnt vmcnt(3)" ::: "memory");
    __builtin_amdgcn_sched_barrier(0);
    __builtin_amdgcn_s_barrier();
    __builtin_amdgcn_sched_barrier(0);
    #pragma unroll
    for (int h = 0; h < 2; ++h) {
      bf16x8 axc = *(const bf16x8*)(Axc + wv * 7168 + kt * 1024 + h * 512 + lane * 8);
      bf16x8 ah  = *(const bf16x8*)(Ah  + wv * 7168 + kt * 1024 + h * 512 + lane * 8);
      const __bf16* bb = Bs + buf * 6144 + h * 512 + lane * 8;
      bf16x8 b0 = *(const bf16x8*)(bb);
      bf16x8 b1 = *(const bf16x8*)(bb + 1024);
      bf16x8 b2 = *(const bf16x8*)(bb + 2048);
      bf16x8 b3 = *(const bf16x8*)(bb + 3072);
      bf16x8 b4 = *(const bf16x8*)(bb + 4096);
      bf16x8 b5 = *(const bf16x8*)(bb + 5120);
      __builtin_amdgcn_s_setprio(1);
      acc[0] = __builtin_amdgcn_mfma_f32_32x32x16_bf16(axc, b0, acc[0], 0, 0, 0);
      acc[1] = __builtin_amdgcn_mfma_f32_32x32x16_bf16(axc, b1, acc[1], 0, 0, 0);
      acc[2] = __builtin_amdgcn_mfma_f32_32x32x16_bf16(axc, b2, acc[2], 0, 0, 0);
      acc[3] = __builtin_amdgcn_mfma_f32_32x32x16_bf16(ah,  b3, acc[3], 0, 0, 0);
      acc[4] = __builtin_amdgcn_mfma_f32_32x32x16_bf16(ah,  b4, acc[4], 0, 0, 0);
      acc[5] = __builtin_amdgcn_mfma_f32_32x32x16_bf16(ah,  b5, acc[5], 0, 0, 0);
      __builtin_amdgcn_s_setprio(0);
    }
    if (kt == 6) {
      const int f = ft * 32 + (lane & 31);
      const bool fok = f < FPc;
      float bir = 0, biz = 0, bin_ = 0, bhr = 0, bhz = 0, bhn = 0;
      if (fok) {
        bir = bih[f]; biz = bih[FPc + f]; bin_ = bih[2 * FPc + f];
        bhr = bhh[f]; bhz = bhh[FPc + f]; bhn = bhh[2 * FPc + f];
      }
      const int hoff = wv * 7168 + (f >> 5) * 1024 + ((f >> 3) & 3) * 256 + (f & 7);
      #pragma unroll
      for (int reg = 0; reg < 16; ++reg) {
        int rl = (reg & 3) + 8 * (reg >> 2) + 4 * (lane >> 5);
        size_t row = row0 + wv * 32 + rl;
        if (fok) {
          float ho = (float)Ah[hoff + rl * 8];
          float rg_ = sigm(acc[0][reg] + bir + acc[3][reg] + bhr);
          float zg  = sigm(acc[1][reg] + biz + acc[4][reg] + bhz);
          float ng  = tanhf(acc[2][reg] + bin_ + rg_ * (acc[5][reg] + bhn));
          float hp = (1.f - zg) * ng + zg * ho;
          Hout[row * KP + f] = (__bf16)hp;
          actOut[row * FPc + f] = fmaxf(hp, 0.f);
        } else {
          Hout[row * KP + f] = (__bf16)0.f;
        }
      }
      #pragma unroll
      for (int g = 0; g < 6; ++g) acc[g] = zero16();
    }
    __builtin_amdgcn_sched_barrier(0);
    __builtin_amdgcn_s_barrier();
    __builtin_amdgcn_sched_barrier(0);
  }
}

// -------------------- MFMA attend v3: same structure, 1 gate -------------------------
__global__ __launch_bounds__(256, 2) void attend_mfma(
    const __bf16* __restrict__ WNb, const __bf16* __restrict__ Apk,
    const float* __restrict__ bias, const float* __restrict__ SW,
    __bf16* __restrict__ XCb) {
  __shared__ __align__(16) __bf16 smem[30720];   // 61440 B: A 28672 + B 2x1024
  __bf16* Aw = smem;
  __bf16* Bs = smem + 28672;
  const int tid = threadIdx.x, wv = tid >> 6, lane = tid & 63;
  const size_t row0 = (size_t)blockIdx.x * 128;

  {
    int rlo = lane & 31, chi = lane >> 5;
    const __bf16* sw_ = WNb + (row0 + wv * 32 + rlo) * KP + chi * 8;
    #pragma unroll
    for (int kt = 0; kt < 7; ++kt)
      #pragma unroll
      for (int hc = 0; hc < 2; ++hc)
        glds16(sw_ + kt * 32 + hc * 16, Aw + wv * 7168 + kt * 1024 + hc * 512);
  }
  auto stageB = [&](int t, int buf) {
    int ft = t / 7, kt = t % 7;
    int half = wv & 1;
    const __bf16* s = Apk + ((size_t)ft * 7 + kt) * 1024 + half * 512 + lane * 8;
    glds16(s, Bs + buf * 1024 + half * 512);
  };
  stageB(0, 0);

  f32x16 acc = zero16();
  for (int it = 0; it < 49; ++it) {
    const int buf = it & 1;
    const int ft = it / 7, kt = it % 7;
    __builtin_amdgcn_sched_barrier(0);
    stageB(it + 1 < 49 ? it + 1 : 48, buf ^ 1);
    __builtin_amdgcn_sched_barrier(0);
    asm volatile("s_waitcnt vmcnt(1)" ::: "memory");
    __builtin_amdgcn_sched_barrier(0);
    __builtin_amdgcn_s_barrier();
    __builtin_amdgcn_sched_barrier(0);
    #pragma unroll
    for (int h = 0; h < 2; ++h) {
      bf16x8 a = *(const bf16x8*)(Aw + wv * 7168 + kt * 1024 + h * 512 + lane * 8);
      bf16x8 b = *(const bf16x8*)(Bs + buf * 1024 + h * 512 + lane * 8);
      acc = __builtin_amdgcn_mfma_f32_32x32x16_bf16(a, b, acc, 0, 0, 0);
    }
    if (kt == 6) {
      const int f = ft * 32 + (lane & 31);
      const bool fok = f < FPc;
      float bf = fok ? bias[f] : 0.f;
      #pragma unroll
      for (int reg = 0; reg < 16; ++reg) {
        int rl = (reg & 3) + 8 * (reg >> 2) + 4 * (lane >> 5);
        size_t row = row0 + wv * 32 + rl;
        if (fok) {
          float v = acc[reg] + SW[row] * bf;
          XCb[row * KP + f] = (__bf16)eluf(v);
        } else {
          XCb[row * KP + f] = (__bf16)0.f;
        }
      }
      acc = zero16();
    }
    __builtin_amdgcn_sched_barrier(0);
    __builtin_amdgcn_s_barrier();
    __builtin_amdgcn_sched_barrier(0);
  }
}

// -------------------- per-(b,l) neighbor attention round -----------------------------
__global__ __launch_bounds__(256) void attn_round(
    int r,
    const float* __restrict__ cur,   // r==0: raw atom_lin (leaky applied on the fly)
    const float* __restrict__ act,   // neigh source for r>=1 (f32)
    const __bf16* __restrict__ P, const __bf16* __restrict__ Q, const float* __restrict__ nbb,
    const int* __restrict__ adl, const int* __restrict__ bdl,
    const float* __restrict__ alW, const float* __restrict__ alb,
    float* __restrict__ attnOut,
    __bf16* __restrict__ WNb, float* __restrict__ sumwOut) {
  __shared__ float nb[4][Kc][FPc];
  const int wv = threadIdx.x >> 6, lane = threadIdx.x & 63;
  const int row = blockIdx.x * 4 + wv;
  const int b = row >> 7;
  int ai[Kc];
  #pragma unroll
  for (int k = 0; k < Kc; ++k) ai[k] = adl[(size_t)row * Kc + k];
  if (r == 0) {
    int bi[Kc];
    #pragma unroll
    for (int k = 0; k < Kc; ++k) bi[k] = bdl[(size_t)row * Kc + k];
    #pragma unroll
    for (int k = 0; k < Kc; ++k)
      for (int f = lane; f < FPc; f += 64) {
        float v = (float)P[((size_t)(b * Lc + ai[k])) * FPc + f]
                + (float)Q[((size_t)(b * Lc + bi[k])) * FPc + f] + nbb[f];
        nb[wv][k][f] = leaky(v);
      }
  } else {
    #pragma unroll
    for (int k = 0; k < Kc; ++k)
      for (int f = lane; f < FPc; f += 64)
        nb[wv][k][f] = act[((size_t)(b * Lc + ai[k])) * FPc + f];
  }
  __syncthreads();
  float part = 0.f;
  for (int f = lane; f < FPc; f += 64) {
    float cv = cur[(size_t)row * FPc + f];
    if (r == 0) cv = leaky(cv);
    part = fmaf(cv, alW[f], part);
  }
  float sa = wave_sum(part);
  float s[Kc];
  #pragma unroll
  for (int k = 0; k < Kc; ++k) {
    float p = 0.f;
    for (int f = lane; f < FPc; f += 64) p = fmaf(nb[wv][k][f], alW[FPc + f], p);
    s[k] = wave_sum(p);
  }
  const float ab = alb[r];
  bool pad[Kc];
  float mx = -3.0e38f;
  #pragma unroll
  for (int k = 0; k < Kc; ++k) {
    pad[k] = (ai[k] == Lc - 1);
    s[k] = leaky(sa + s[k] + ab) + (pad[k] ? NEGC : 0.f);
    mx = fmaxf(mx, s[k]);
  }
  float e[Kc], sum = 0.f;
  #pragma unroll
  for (int k = 0; k < Kc; ++k) { e[k] = __expf(s[k] - mx); sum += e[k]; }
  float inv = 1.f / sum;
  float w[Kc], sw = 0.f;
  #pragma unroll
  for (int k = 0; k < Kc; ++k) { w[k] = pad[k] ? 0.f : e[k] * inv; sw += w[k]; }
  if (lane < Kc) attnOut[(size_t)row * Kc + lane] = w[lane];
  if (lane == 0) sumwOut[row] = sw;
  for (int f = lane; f < KP; f += 64) {
    float a = 0.f;
    if (f < FPc) {
      #pragma unroll
      for (int k = 0; k < Kc; ++k) a = fmaf(w[k], nb[wv][k][f], a);
    }
    WNb[(size_t)row * KP + f] = (__bf16)a;
  }
}

// -------------------- fused GRU f32 (mol path, 512 rows) -----------------------------
__global__ __launch_bounds__(256) void gru8(
    const float* __restrict__ XC, float* __restrict__ H,
    const float* __restrict__ WihT, const float* __restrict__ WhhT,
    const float* __restrict__ bih, const float* __restrict__ bhh,
    float* __restrict__ actOut, float* __restrict__ unbOut, float* __restrict__ vizOut) {
  constexpr int TR = 8, LDP = 12;
  __shared__ float xc[FPc * LDP];
  __shared__ float xh[FPc * LDP];
  const int row0 = blockIdx.x * TR;
  const int tid = threadIdx.x;
  for (int e = tid; e < TR * FPc; e += 256) {
    int r = e / FPc, g = e - r * FPc;
    xc[g * LDP + r] = XC[(size_t)row0 * FPc + e];
    xh[g * LDP + r] = H[(size_t)row0 * FPc + e];
  }
  __syncthreads();
  const int f = tid;
  if (f < FPc) {
    float air[8], aiz[8], ain[8], ahr[8], ahz[8], ahn[8];
    const float bir = bih[f], biz = bih[f + 200], bin_ = bih[f + 400];
    const float bhr = bhh[f], bhz = bhh[f + 200], bhn = bhh[f + 400];
    #pragma unroll
    for (int r = 0; r < 8; ++r) {
      air[r] = bir; aiz[r] = biz; ain[r] = bin_;
      ahr[r] = bhr; ahz[r] = bhz; ahn[r] = bhn;
    }
    #pragma unroll 2
    for (int g = 0; g < FPc; ++g) {
      const float* wi = &WihT[(size_t)g * 600 + f];
      const float* wh = &WhhT[(size_t)g * 600 + f];
      float wir = wi[0], wiz = wi[200], win = wi[400];
      float whr = wh[0], whz = wh[200], whn = wh[400];
      float4 c0 = *reinterpret_cast<const float4*>(&xc[g * LDP]);
      float4 c1 = *reinterpret_cast<const float4*>(&xc[g * LDP + 4]);
      float4 h0 = *reinterpret_cast<const float4*>(&xh[g * LDP]);
      float4 h1 = *reinterpret_cast<const float4*>(&xh[g * LDP + 4]);
      float cx[8] = {c0.x, c0.y, c0.z, c0.w, c1.x, c1.y, c1.z, c1.w};
      float hx[8] = {h0.x, h0.y, h0.z, h0.w, h1.x, h1.y, h1.z, h1.w};
      #pragma unroll
      for (int r = 0; r < 8; ++r) {
        air[r] = fmaf(cx[r], wir, air[r]);
        aiz[r] = fmaf(cx[r], wiz, aiz[r]);
        ain[r] = fmaf(cx[r], win, ain[r]);
        ahr[r] = fmaf(hx[r], whr, ahr[r]);
        ahz[r] = fmaf(hx[r], whz, ahz[r]);
        ahn[r] = fmaf(hx[r], whn, ahn[r]);
      }
    }
    #pragma unroll
    for (int r = 0; r < 8; ++r) {
      float rg = sigm(air[r] + ahr[r]);
      float zg = sigm(aiz[r] + ahz[r]);
      float ng = tanhf(fmaf(rg, ahn[r], ain[r]));
      float hv = xh[f * LDP + r];
      float hp = (1.f - zg) * ng + zg * hv;
      size_t idx = (size_t)(row0 + r) * FPc + f;
      H[idx] = hp;
      float a = fmaxf(hp, 0.f);
      if (actOut) actOut[idx] = a;
      if (unbOut) unbOut[idx] = hp;
      if (vizOut) vizOut[idx] = a;
    }
  }
}

// -------------------- mol-level sum over atoms ---------------------------------------
__global__ __launch_bounds__(256) void mol_sum_k(
    const __bf16* __restrict__ Hb, const float* __restrict__ ACT, const float* __restrict__ mask,
    float* __restrict__ unb0, float* __restrict__ viz0,
    float* __restrict__ molfeat, float* __restrict__ actmol) {
  const int b = blockIdx.x;
  __shared__ float mk[Lc];
  for (int l = threadIdx.x; l < Lc; l += 256) mk[l] = mask[b * Lc + l];
  __syncthreads();
  const int f = threadIdx.x;
  if (f < FPc) {
    float s1 = 0.f, s2 = 0.f;
    for (int l = 0; l < Lc; ++l) {
      float m = mk[l];
      s1 = fmaf((float)Hb[((size_t)b * Lc + l) * KP + f], m, s1);
      s2 = fmaf(ACT[((size_t)b * Lc + l) * FPc + f], m, s2);
    }
    unb0[b * FPc + f] = s1;
    viz0[b * FPc + f] = s2;
    molfeat[b * FPc + f] = s2;
    actmol[b * FPc + f] = fmaxf(s2, 0.f);
  }
}

// -------------------- mol-level attention over L atoms -------------------------------
__global__ __launch_bounds__(256) void mol_attn_k(
    const float* __restrict__ act, const float* __restrict__ actmol,
    const float* __restrict__ malW, const float* __restrict__ malb,
    const float* __restrict__ mask,
    float* __restrict__ attnOut, float* __restrict__ wact, float* __restrict__ msumw) {
  const int b = blockIdx.x;
  __shared__ float sa_s;
  __shared__ float sn[Lc];
  __shared__ float wl[Lc];
  __shared__ float redmx[2], redsum[2], redsw[2];
  const int wv = threadIdx.x >> 6, lane = threadIdx.x & 63;
  if (wv == 0) {
    float p = 0.f;
    for (int f = lane; f < FPc; f += 64) p = fmaf(actmol[b * FPc + f], malW[f], p);
    float s = wave_sum(p);
    if (lane == 0) sa_s = s;
  }
  for (int l = wv; l < Lc; l += 4) {
    float p = 0.f;
    for (int f = lane; f < FPc; f += 64)
      p = fmaf(act[((size_t)b * Lc + l) * FPc + f], malW[FPc + f], p);
    float s = wave_sum(p);
    if (lane == 0) sn[l] = s;
  }
  __syncthreads();
  const int l = threadIdx.x;
  float sc = -3.0e38f, mval = 0.f;
  if (l < Lc) {
    mval = mask[b * Lc + l];
    sc = leaky(sa_s + sn[l] + malb[0]) + (mval == 0.f ? NEGC : 0.f);
  }
  float m = sc;
  #pragma unroll
  for (int o = 32; o >= 1; o >>= 1) m = fmaxf(m, __shfl_xor(m, o));
  if (lane == 0 && wv < 2) redmx[wv] = m;
  __syncthreads();
  float mx = fmaxf(redmx[0], redmx[1]);
  float e = (l < Lc) ? __expf(sc - mx) : 0.f;
  float s = e;
  #pragma unroll
  for (int o = 32; o >= 1; o >>= 1) s += __shfl_xor(s, o);
  if (lane == 0 && wv < 2) redsum[wv] = s;
  __syncthreads();
  float tot = redsum[0] + redsum[1];
  float w = 0.f;
  if (l < Lc) {
    w = e / tot * mval;
    wl[l] = w;
    attnOut[(size_t)b * Lc + l] = w;
  }
  float swp = w;
  #pragma unroll
  for (int o = 32; o >= 1; o >>= 1) swp += __shfl_xor(swp, o);
  if (lane == 0 && wv < 2) redsw[wv] = swp;
  __syncthreads();
  if (threadIdx.x == 0) msumw[b] = redsw[0] + redsw[1];
  const int f = threadIdx.x;
  if (f < FPc) {
    float a = 0.f;
    for (int l2 = 0; l2 < Lc; ++l2)
      a = fmaf(wl[l2], act[((size_t)b * Lc + l2) * FPc + f], a);
    wact[b * FPc + f] = a;
  }
}

// -------------------- final prediction -----------------------------------------------
__global__ __launch_bounds__(256) void pred_k(
    const float* __restrict__ molfeat, const float* __restrict__ outW,
    const float* __restrict__ outb, float* __restrict__ pred) {
  const int wv = threadIdx.x >> 6, lane = threadIdx.x & 63;
  const int b = blockIdx.x * 4 + wv;
  if (b < Bc) {
    float p = 0.f;
    for (int f = lane; f < FPc; f += 64) p = fmaf(molfeat[b * FPc + f], outW[f], p);
    float s = wave_sum(p);
    if (lane == 0) pred[b] = s + outb[0];
  }
}

extern "C" void kernel_launch(void* const* d_in, const int* in_sizes, int n_in,
                              void* d_out, int out_size, void* d_ws, size_t ws_size,
                              hipStream_t stream) {
  const float* atom_list = (const float*)d_in[0];
  const float* bond_list = (const float*)d_in[1];
  const int*   adl       = (const int*)d_in[2];
  const int*   bdl       = (const int*)d_in[3];
  const float* mask      = (const float*)d_in[4];
  const float* atom_fc_W = (const float*)d_in[5];
  const float* atom_fc_b = (const float*)d_in[6];
  const float* nb_W      = (const float*)d_in[7];
  const float* nb_b      = (const float*)d_in[8];
  const float* align_W   = (const float*)d_in[9];
  const float* align_b   = (const float*)d_in[10];
  const float* attend_W  = (const float*)d_in[11];
  const float* attend_b  = (const float*)d_in[12];
  const float* gru_Wih   = (const float*)d_in[13];
  const float* gru_Whh   = (const float*)d_in[14];
  const float* gru_bih   = (const float*)d_in[15];
  const float* gru_bhh   = (const float*)d_in[16];
  const float* mal_W     = (const float*)d_in[17];
  const float* mal_b     = (const float*)d_in[18];
  const float* matt_W    = (const float*)d_in[19];
  const float* matt_b    = (const float*)d_in[20];
  const float* mWih      = (const float*)d_in[21];
  const float* mWhh      = (const float*)d_in[22];
  const float* mbih      = (const float*)d_in[23];
  const float* mbhh      = (const float*)d_in[24];
  const float* out_W     = (const float*)d_in[25];
  const float* out_b     = (const float*)d_in[26];

  float* out  = (float*)d_out;
  float* AV   = out;                                  // (4,B,L,FP)
  float* ATTN = AV + (size_t)4 * BL * FPc;            // (3,B,L,K)
  float* MV   = ATTN + (size_t)Rc * BL * Kc;          // (3,B,FP)
  float* MU   = MV + (size_t)3 * Bc * FPc;            // (3,B,FP)
  float* MA   = MU + (size_t)3 * Bc * FPc;            // (2,B,L)
  float* PRED = MA + (size_t)Tc * Bc * Lc;            // (B,1)

  char* w = (char*)d_ws;
  __bf16* Hb0  = (__bf16*)w; w += (size_t)BL * KP * 2;
  __bf16* Hb1  = (__bf16*)w; w += (size_t)BL * KP * 2;
  __bf16* XCb  = (__bf16*)w; w += (size_t)BL * KP * 2;
  __bf16* WNb  = (__bf16*)w; w += (size_t)BL * KP * 2;
  __bf16* Pb   = (__bf16*)w; w += (size_t)BL * FPc * 2;
  __bf16* Qb   = (__bf16*)w; w += (size_t)BL * FPc * 2;
  __bf16* Wpk  = (__bf16*)w; w += (size_t)Rc * 6 * 49 * 1024 * 2;
  __bf16* Apk  = (__bf16*)w; w += (size_t)Rc * 49 * 1024 * 2;
  float* SW    = (float*)w;  w += (size_t)BL * 4;
  float* MOLF  = (float*)w;  w += (size_t)Bc * FPc * 4;
  float* ACTM  = (float*)w;  w += (size_t)Bc * FPc * 4;
  float* WACT  = (float*)w;  w += (size_t)Bc * FPc * 4;
  float* MCTX  = (float*)w;  w += (size_t)Bc * FPc * 4;
  float* MSW   = (float*)w;  w += (size_t)Bc * 4;
  float* atomfcT = (float*)w; w += (size_t)AFc * FPc * 4;
  float* naT     = (float*)w; w += (size_t)(AFc + BFc) * FPc * 4;
  float* mattT   = (float*)w; w += (size_t)FPc * FPc * 4;
  float* mWihT   = (float*)w; w += (size_t)FPc * 600 * 4;
  float* mWhhT   = (float*)w; w += (size_t)FPc * 600 * 4;

  transpose_k<<<64, 256, 0, stream>>>(atom_fc_W, atomfcT, FPc, AFc);
  transpose_k<<<64, 256, 0, stream>>>(nb_W, naT, FPc, AFc + BFc);
  transpose_k<<<64, 256, 0, stream>>>(matt_W, mattT, FPc, FPc);
  transpose_k<<<64, 256, 0, stream>>>(mWih, mWihT, 600, FPc);
  transpose_k<<<64, 256, 0, stream>>>(mWhh, mWhhT, 600, FPc);
  pack_gru_k<<<(Rc * 6 * 49 * 1024 + 255) / 256, 256, 0, stream>>>(gru_Wih, gru_Whh, Wpk);
  pack_att_k<<<(Rc * 49 * 1024 + 255) / 256, 256, 0, stream>>>(attend_W, Apk);

  gemm8x1<AFc, 1><<<BL / 8, 256, 0, stream>>>(atom_list, atomfcT, atom_fc_b, nullptr, AV, Hb0);
  gemm8x1<AFc, 0><<<BL / 8, 256, 0, stream>>>(atom_list, naT, nullptr, nullptr, nullptr, Pb);
  gemm8x1<BFc, 0><<<BL / 8, 256, 0, stream>>>(bond_list, naT + AFc * FPc, nullptr, nullptr, nullptr, Qb);

  __bf16* Hbuf[2] = {Hb0, Hb1};
  for (int r = 0; r < Rc; ++r) {
    const float* curp = (r == 0) ? AV : AV + (size_t)r * BL * FPc;
    attn_round<<<BL / 4, 256, 0, stream>>>(r, curp, AV + (size_t)r * BL * FPc,
        Pb, Qb, nb_b, adl, bdl, align_W + (size_t)r * 2 * FPc, align_b,
        ATTN + (size_t)r * BL * Kc, WNb, SW);
    attend_mfma<<<BL / 128, 256, 0, stream>>>(WNb, Apk + (size_t)r * 49 * 1024,
        attend_b + (size_t)r * FPc, SW, XCb);
    gru_mfma<<<BL / 128, 256, 0, stream>>>(XCb, Hbuf[r & 1], Hbuf[(r + 1) & 1],
        Wpk + (size_t)r * 6 * 49 * 1024, gru_bih + (size_t)r * 3 * FPc, gru_bhh + (size_t)r * 3 * FPc,
        AV + (size_t)(r + 1) * BL * FPc);
  }

  mol_sum_k<<<Bc, 256, 0, stream>>>(Hbuf[Rc & 1], AV + (size_t)3 * BL * FPc, mask, MU, MV, MOLF, ACTM);
  for (int t = 0; t < Tc; ++t) {
    mol_attn_k<<<Bc, 256, 0, stream>>>(AV + (size_t)3 * BL * FPc, ACTM, mal_W, mal_b, mask,
        MA + (size_t)t * Bc * Lc, WACT, MSW);
    gemm8x1<FPc, 2><<<Bc / 8, 256, 0, stream>>>(WACT, mattT, matt_b, MSW, MCTX, nullptr);
    gru8<<<Bc / 8, 256, 0, stream>>>(MCTX, MOLF, mWihT, mWhhT, mbih, mbhh,
        ACTM, MU + (size_t)(t + 1) * Bc * FPc, MV + (size_t)(t + 1) * Bc * FPc);
  }
  pred_k<<<Bc / 4, 256, 0, stream>>>(MOLF, out_W, out_b, PRED);
}

// Round 4
// 1298.231 us; speedup vs baseline: 2.3584x; 1.2277x over previous
//
#include <hip/hip_runtime.h>
#include <stdint.h>

#define Bc 512
#define Lc 128
#define Kc 6
#define AFc 39
#define BFc 10
#define FPc 200
#define Rc 3
#define Tc 2
constexpr int BL = Bc * Lc;          // 65536
constexpr int KP = 224;              // padded K / F for MFMA
constexpr float SLOPE = 0.01f;
constexpr float NEGC = -9e8f;

typedef __attribute__((ext_vector_type(8))) __bf16 bf16x8;
typedef __attribute__((ext_vector_type(16))) float f32x16;

__device__ __forceinline__ float leaky(float x) { return x >= 0.f ? x : SLOPE * x; }
__device__ __forceinline__ float sigm(float x) { return 1.f / (1.f + __expf(-x)); }
__device__ __forceinline__ float eluf(float x) { return x > 0.f ? x : expm1f(x); }
__device__ __forceinline__ float wave_sum(float v) {
  #pragma unroll
  for (int m = 32; m >= 1; m >>= 1) v += __shfl_xor(v, m);
  return v;
}
__device__ __forceinline__ void glds16(const void* g, void* l) {
  __builtin_amdgcn_global_load_lds((const __attribute__((address_space(1))) uint32_t*)g,
      (__attribute__((address_space(3))) uint32_t*)l, 16, 0, 0);
}
__device__ __forceinline__ f32x16 zero16() {
  f32x16 z;
  #pragma unroll
  for (int i = 0; i < 16; ++i) z[i] = 0.f;
  return z;
}

// -------------------- weight transpose: out[c*R + r] = in[r*C + c] --------------------
__global__ void transpose_k(const float* __restrict__ in, float* __restrict__ out, int R, int C) {
  int n = R * C;
  for (int i = blockIdx.x * blockDim.x + threadIdx.x; i < n; i += gridDim.x * blockDim.x) {
    int r = i / C, c = i - r * C;
    out[c * R + r] = in[i];
  }
}

// -------------------- pack GRU weights into staging-linear tiles ---------------------
// Wpk layout: [r][g6][ft7][kt7]{ tile 1024 elems: [c4][f32][j8] }
__global__ void pack_gru_k(const float* __restrict__ Wih, const float* __restrict__ Whh,
                           __bf16* __restrict__ Wpk) {
  int i = blockIdx.x * 256 + threadIdx.x;
  if (i >= Rc * 6 * 7 * 7 * 1024) return;
  int j = i & 7, fl = (i >> 3) & 31, c = (i >> 8) & 3;
  int T = i >> 10;
  int kt = T % 7; T /= 7;
  int ft = T % 7; T /= 7;
  int g = T % 6;  int r = T / 6;
  int f = ft * 32 + fl, k = kt * 32 + c * 8 + j;
  float v = 0.f;
  if (f < FPc && k < FPc) {
    if (g < 3) v = Wih[((size_t)r * 3 * FPc + g * FPc + f) * FPc + k];
    else       v = Whh[((size_t)r * 3 * FPc + (g - 3) * FPc + f) * FPc + k];
  }
  Wpk[i] = (__bf16)v;
}

// Apk layout: [r][ft7][kt7]{1024: [c4][f32][j8]}
__global__ void pack_att_k(const float* __restrict__ W, __bf16* __restrict__ Apk) {
  int i = blockIdx.x * 256 + threadIdx.x;
  if (i >= Rc * 7 * 7 * 1024) return;
  int j = i & 7, fl = (i >> 3) & 31, c = (i >> 8) & 3;
  int T = i >> 10;
  int kt = T % 7; T /= 7;
  int ft = T % 7; int r = T / 7;
  int f = ft * 32 + fl, k = kt * 32 + c * 8 + j;
  float v = (f < FPc && k < FPc) ? W[((size_t)r * FPc + f) * FPc + k] : 0.f;
  Apk[i] = (__bf16)v;
}

// -------------------- generic small GEMM (f32): Y[rows][200] ------------------------
template<int KD, int EPI>
__global__ __launch_bounds__(256) void gemm8x1(
    const float* __restrict__ X, const float* __restrict__ WT,
    const float* __restrict__ bias, const float* __restrict__ sumw,
    float* __restrict__ Y, __bf16* __restrict__ Yb) {
  constexpr int TR = 8, LDP = 12;
  __shared__ float xT[KD * LDP];
  const int row0 = blockIdx.x * TR;
  const int tid = threadIdx.x;
  for (int e = tid; e < TR * KD; e += 256) {
    int r = e / KD, g = e - r * KD;
    xT[g * LDP + r] = X[(size_t)row0 * KD + e];
  }
  __syncthreads();
  const int f = tid;
  if (f < FPc) {
    float acc[TR];
    #pragma unroll
    for (int r = 0; r < TR; ++r) acc[r] = 0.f;
    #pragma unroll 4
    for (int g = 0; g < KD; ++g) {
      float w = WT[(size_t)g * FPc + f];
      float4 x0 = *reinterpret_cast<const float4*>(&xT[g * LDP]);
      float4 x1 = *reinterpret_cast<const float4*>(&xT[g * LDP + 4]);
      acc[0] = fmaf(x0.x, w, acc[0]); acc[1] = fmaf(x0.y, w, acc[1]);
      acc[2] = fmaf(x0.z, w, acc[2]); acc[3] = fmaf(x0.w, w, acc[3]);
      acc[4] = fmaf(x1.x, w, acc[4]); acc[5] = fmaf(x1.y, w, acc[5]);
      acc[6] = fmaf(x1.z, w, acc[6]); acc[7] = fmaf(x1.w, w, acc[7]);
    }
    #pragma unroll
    for (int r = 0; r < TR; ++r) {
      if (EPI == 0) {
        Yb[(size_t)(row0 + r) * FPc + f] = (__bf16)acc[r];
      } else if (EPI == 1) {
        float v = acc[r] + bias[f];
        Y[(size_t)(row0 + r) * FPc + f] = v;                 // raw atom_lin (viz)
        Yb[(size_t)(row0 + r) * KP + f] = (__bf16)leaky(v);  // h0
      } else {
        float v = fmaf(sumw[row0 + r], bias[f], acc[r]);
        Y[(size_t)(row0 + r) * FPc + f] = eluf(v);
      }
    }
  } else if (EPI == 1 && f < KP) {
    #pragma unroll
    for (int r = 0; r < TR; ++r) Yb[(size_t)(row0 + r) * KP + f] = (__bf16)0.f;
  }
}

// -------------------- MFMA GRU v4: xc in reg-frags, h in LDS, 2 blocks/CU ------------
// block = 256 thr (4 waves x 32 rows = 128 rows). LDS = h 57344 B + B dbuf 24576 B = 81920.
__global__ __launch_bounds__(256, 2) void gru_mfma(
    const __bf16* __restrict__ XCb, const __bf16* __restrict__ Hin,
    __bf16* __restrict__ Hout, const __bf16* __restrict__ Wpk,
    const float* __restrict__ bih, const float* __restrict__ bhh,
    float* __restrict__ actOut) {
  __shared__ __align__(16) __bf16 smem[40960];   // 81920 B
  __bf16* Ah = smem;                              // [wv4][kt7][1024]
  __bf16* Bs = smem + 28672;                      // [buf2][g6][1024]
  const int tid = threadIdx.x, wv = tid >> 6, lane = tid & 63;
  const size_t row0 = (size_t)blockIdx.x * 128;

  // ---- h staging into LDS (chunk-transposed, conflict-free) ----
  {
    int rlo = lane & 31, chi = lane >> 5;
    const __bf16* sh = Hin + (row0 + wv * 32 + rlo) * KP + chi * 8;
    #pragma unroll
    for (int kt = 0; kt < 7; ++kt)
      #pragma unroll
      for (int hc = 0; hc < 2; ++hc)
        glds16(sh + kt * 32 + hc * 16, Ah + wv * 7168 + kt * 1024 + hc * 512);
  }
  // ---- xc fragments into registers (14 x 16B) ----
  bf16x8 xcf[7][2];
  {
    const __bf16* sx = XCb + (row0 + wv * 32 + (lane & 31)) * KP + (lane >> 5) * 8;
    #pragma unroll
    for (int kt = 0; kt < 7; ++kt)
      #pragma unroll
      for (int h = 0; h < 2; ++h)
        xcf[kt][h] = *(const bf16x8*)(sx + kt * 32 + h * 16);
  }
  auto stageB = [&](int ft, int kt, int buf) {
    #pragma unroll
    for (int m3 = 0; m3 < 3; ++m3) {
      int m = wv * 3 + m3;               // 0..11
      int g = m >> 1, half = m & 1;
      const __bf16* s = Wpk + ((size_t)(g * 7 + ft) * 7 + kt) * 1024 + half * 512 + lane * 8;
      glds16(s, Bs + buf * 6144 + g * 1024 + half * 512);
    }
  };
  stageB(0, 0, 0);

  f32x16 acc[6];
  #pragma unroll
  for (int g = 0; g < 6; ++g) acc[g] = zero16();

  for (int ft = 0; ft < 7; ++ft) {
    #pragma unroll
    for (int kt = 0; kt < 7; ++kt) {
      const int it = ft * 7 + kt;
      const int buf = it & 1;
      const int nft = (kt == 6) ? ft + 1 : ft;
      const int nkt = (kt == 6) ? 0 : kt + 1;
      __builtin_amdgcn_sched_barrier(0);
      if (it < 48) stageB(nft, nkt, buf ^ 1);
      else         stageB(6, 6, buf ^ 1);          // dummy: keep 3 outstanding
      __builtin_amdgcn_sched_barrier(0);
      asm volatile("s_waitcnt vmcnt(3)" ::: "memory");
      __builtin_amdgcn_sched_barrier(0);
      __builtin_amdgcn_s_barrier();
      __builtin_amdgcn_sched_barrier(0);
      #pragma unroll
      for (int h = 0; h < 2; ++h) {
        bf16x8 ah = *(const bf16x8*)(Ah + wv * 7168 + kt * 1024 + h * 512 + lane * 8);
        const __bf16* bb = Bs + buf * 6144 + h * 512 + lane * 8;
        bf16x8 b0 = *(const bf16x8*)(bb);
        bf16x8 b1 = *(const bf16x8*)(bb + 1024);
        bf16x8 b2 = *(const bf16x8*)(bb + 2048);
        bf16x8 b3 = *(const bf16x8*)(bb + 3072);
        bf16x8 b4 = *(const bf16x8*)(bb + 4096);
        bf16x8 b5 = *(const bf16x8*)(bb + 5120);
        __builtin_amdgcn_s_setprio(1);
        acc[0] = __builtin_amdgcn_mfma_f32_32x32x16_bf16(xcf[kt][h], b0, acc[0], 0, 0, 0);
        acc[1] = __builtin_amdgcn_mfma_f32_32x32x16_bf16(xcf[kt][h], b1, acc[1], 0, 0, 0);
        acc[2] = __builtin_amdgcn_mfma_f32_32x32x16_bf16(xcf[kt][h], b2, acc[2], 0, 0, 0);
        acc[3] = __builtin_amdgcn_mfma_f32_32x32x16_bf16(ah, b3, acc[3], 0, 0, 0);
        acc[4] = __builtin_amdgcn_mfma_f32_32x32x16_bf16(ah, b4, acc[4], 0, 0, 0);
        acc[5] = __builtin_amdgcn_mfma_f32_32x32x16_bf16(ah, b5, acc[5], 0, 0, 0);
        __builtin_amdgcn_s_setprio(0);
      }
      if (kt == 6) {
        const int f = ft * 32 + (lane & 31);
        const bool fok = f < FPc;
        float bir = 0, biz = 0, bin_ = 0, bhr = 0, bhz = 0, bhn = 0;
        if (fok) {
          bir = bih[f]; biz = bih[FPc + f]; bin_ = bih[2 * FPc + f];
          bhr = bhh[f]; bhz = bhh[FPc + f]; bhn = bhh[2 * FPc + f];
        }
        const int hoff = wv * 7168 + (f >> 5) * 1024 + ((f >> 3) & 3) * 256 + (f & 7);
        #pragma unroll
        for (int reg = 0; reg < 16; ++reg) {
          int rl = (reg & 3) + 8 * (reg >> 2) + 4 * (lane >> 5);
          size_t row = row0 + wv * 32 + rl;
          if (fok) {
            float ho = (float)Ah[hoff + rl * 8];
            float rg_ = sigm(acc[0][reg] + bir + acc[3][reg] + bhr);
            float zg  = sigm(acc[1][reg] + biz + acc[4][reg] + bhz);
            float ng  = tanhf(acc[2][reg] + bin_ + rg_ * (acc[5][reg] + bhn));
            float hp = (1.f - zg) * ng + zg * ho;
            Hout[row * KP + f] = (__bf16)hp;
            actOut[row * FPc + f] = fmaxf(hp, 0.f);
          } else {
            Hout[row * KP + f] = (__bf16)0.f;
          }
        }
        #pragma unroll
        for (int g = 0; g < 6; ++g) acc[g] = zero16();
      }
      __builtin_amdgcn_sched_barrier(0);
      __builtin_amdgcn_s_barrier();
      __builtin_amdgcn_sched_barrier(0);
    }
  }
}

// -------------------- MFMA attend v4: LDS-free, barrier-free -------------------------
__global__ __launch_bounds__(256, 2) void attend_mfma(
    const __bf16* __restrict__ WNb, const __bf16* __restrict__ Apk,
    const float* __restrict__ bias, const float* __restrict__ SW,
    __bf16* __restrict__ XCb) {
  const int tid = threadIdx.x, wv = tid >> 6, lane = tid & 63;
  const size_t row0 = (size_t)blockIdx.x * 128;

  bf16x8 af[7][2];
  {
    const __bf16* sw_ = WNb + (row0 + wv * 32 + (lane & 31)) * KP + (lane >> 5) * 8;
    #pragma unroll
    for (int kt = 0; kt < 7; ++kt)
      #pragma unroll
      for (int h = 0; h < 2; ++h)
        af[kt][h] = *(const bf16x8*)(sw_ + kt * 32 + h * 16);
  }

  for (int ft = 0; ft < 7; ++ft) {
    f32x16 acc = zero16();
    #pragma unroll
    for (int kt = 0; kt < 7; ++kt) {
      const __bf16* bt = Apk + ((size_t)ft * 7 + kt) * 1024 + lane * 8;
      bf16x8 b0 = *(const bf16x8*)(bt);
      bf16x8 b1 = *(const bf16x8*)(bt + 512);
      acc = __builtin_amdgcn_mfma_f32_32x32x16_bf16(af[kt][0], b0, acc, 0, 0, 0);
      acc = __builtin_amdgcn_mfma_f32_32x32x16_bf16(af[kt][1], b1, acc, 0, 0, 0);
    }
    const int f = ft * 32 + (lane & 31);
    const bool fok = f < FPc;
    float bf = fok ? bias[f] : 0.f;
    #pragma unroll
    for (int reg = 0; reg < 16; ++reg) {
      int rl = (reg & 3) + 8 * (reg >> 2) + 4 * (lane >> 5);
      size_t row = row0 + wv * 32 + rl;
      if (fok) {
        float v = acc[reg] + SW[row] * bf;
        XCb[row * KP + f] = (__bf16)eluf(v);
      } else {
        XCb[row * KP + f] = (__bf16)0.f;
      }
    }
  }
}

// -------------------- per-(b,l) neighbor attention round -----------------------------
__global__ __launch_bounds__(256) void attn_round(
    int r,
    const float* __restrict__ cur,   // r==0: raw atom_lin (leaky applied on the fly)
    const float* __restrict__ act,   // neigh source for r>=1 (f32)
    const __bf16* __restrict__ P, const __bf16* __restrict__ Q, const float* __restrict__ nbb,
    const int* __restrict__ adl, const int* __restrict__ bdl,
    const float* __restrict__ alW, const float* __restrict__ alb,
    float* __restrict__ attnOut,
    __bf16* __restrict__ WNb, float* __restrict__ sumwOut) {
  __shared__ float nb[4][Kc][FPc];
  const int wv = threadIdx.x >> 6, lane = threadIdx.x & 63;
  const int row = blockIdx.x * 4 + wv;
  const int b = row >> 7;
  int ai[Kc];
  #pragma unroll
  for (int k = 0; k < Kc; ++k) ai[k] = adl[(size_t)row * Kc + k];
  if (r == 0) {
    int bi[Kc];
    #pragma unroll
    for (int k = 0; k < Kc; ++k) bi[k] = bdl[(size_t)row * Kc + k];
    #pragma unroll
    for (int k = 0; k < Kc; ++k)
      for (int f = lane; f < FPc; f += 64) {
        float v = (float)P[((size_t)(b * Lc + ai[k])) * FPc + f]
                + (float)Q[((size_t)(b * Lc + bi[k])) * FPc + f] + nbb[f];
        nb[wv][k][f] = leaky(v);
      }
  } else {
    #pragma unroll
    for (int k = 0; k < Kc; ++k)
      for (int f = lane; f < FPc; f += 64)
        nb[wv][k][f] = act[((size_t)(b * Lc + ai[k])) * FPc + f];
  }
  __syncthreads();
  float part = 0.f;
  for (int f = lane; f < FPc; f += 64) {
    float cv = cur[(size_t)row * FPc + f];
    if (r == 0) cv = leaky(cv);
    part = fmaf(cv, alW[f], part);
  }
  float sa = wave_sum(part);
  float s[Kc];
  #pragma unroll
  for (int k = 0; k < Kc; ++k) {
    float p = 0.f;
    for (int f = lane; f < FPc; f += 64) p = fmaf(nb[wv][k][f], alW[FPc + f], p);
    s[k] = wave_sum(p);
  }
  const float ab = alb[r];
  bool pad[Kc];
  float mx = -3.0e38f;
  #pragma unroll
  for (int k = 0; k < Kc; ++k) {
    pad[k] = (ai[k] == Lc - 1);
    s[k] = leaky(sa + s[k] + ab) + (pad[k] ? NEGC : 0.f);
    mx = fmaxf(mx, s[k]);
  }
  float e[Kc], sum = 0.f;
  #pragma unroll
  for (int k = 0; k < Kc; ++k) { e[k] = __expf(s[k] - mx); sum += e[k]; }
  float inv = 1.f / sum;
  float w[Kc], sw = 0.f;
  #pragma unroll
  for (int k = 0; k < Kc; ++k) { w[k] = pad[k] ? 0.f : e[k] * inv; sw += w[k]; }
  if (lane < Kc) attnOut[(size_t)row * Kc + lane] = w[lane];
  if (lane == 0) sumwOut[row] = sw;
  for (int f = lane; f < KP; f += 64) {
    float a = 0.f;
    if (f < FPc) {
      #pragma unroll
      for (int k = 0; k < Kc; ++k) a = fmaf(w[k], nb[wv][k][f], a);
    }
    WNb[(size_t)row * KP + f] = (__bf16)a;
  }
}

// -------------------- fused GRU f32 (mol path, 512 rows) -----------------------------
__global__ __launch_bounds__(256) void gru8(
    const float* __restrict__ XC, float* __restrict__ H,
    const float* __restrict__ WihT, const float* __restrict__ WhhT,
    const float* __restrict__ bih, const float* __restrict__ bhh,
    float* __restrict__ actOut, float* __restrict__ unbOut, float* __restrict__ vizOut) {
  constexpr int TR = 8, LDP = 12;
  __shared__ float xc[FPc * LDP];
  __shared__ float xh[FPc * LDP];
  const int row0 = blockIdx.x * TR;
  const int tid = threadIdx.x;
  for (int e = tid; e < TR * FPc; e += 256) {
    int r = e / FPc, g = e - r * FPc;
    xc[g * LDP + r] = XC[(size_t)row0 * FPc + e];
    xh[g * LDP + r] = H[(size_t)row0 * FPc + e];
  }
  __syncthreads();
  const int f = tid;
  if (f < FPc) {
    float air[8], aiz[8], ain[8], ahr[8], ahz[8], ahn[8];
    const float bir = bih[f], biz = bih[f + 200], bin_ = bih[f + 400];
    const float bhr = bhh[f], bhz = bhh[f + 200], bhn = bhh[f + 400];
    #pragma unroll
    for (int r = 0; r < 8; ++r) {
      air[r] = bir; aiz[r] = biz; ain[r] = bin_;
      ahr[r] = bhr; ahz[r] = bhz; ahn[r] = bhn;
    }
    #pragma unroll 2
    for (int g = 0; g < FPc; ++g) {
      const float* wi = &WihT[(size_t)g * 600 + f];
      const float* wh = &WhhT[(size_t)g * 600 + f];
      float wir = wi[0], wiz = wi[200], win = wi[400];
      float whr = wh[0], whz = wh[200], whn = wh[400];
      float4 c0 = *reinterpret_cast<const float4*>(&xc[g * LDP]);
      float4 c1 = *reinterpret_cast<const float4*>(&xc[g * LDP + 4]);
      float4 h0 = *reinterpret_cast<const float4*>(&xh[g * LDP]);
      float4 h1 = *reinterpret_cast<const float4*>(&xh[g * LDP + 4]);
      float cx[8] = {c0.x, c0.y, c0.z, c0.w, c1.x, c1.y, c1.z, c1.w};
      float hx[8] = {h0.x, h0.y, h0.z, h0.w, h1.x, h1.y, h1.z, h1.w};
      #pragma unroll
      for (int r = 0; r < 8; ++r) {
        air[r] = fmaf(cx[r], wir, air[r]);
        aiz[r] = fmaf(cx[r], wiz, aiz[r]);
        ain[r] = fmaf(cx[r], win, ain[r]);
        ahr[r] = fmaf(hx[r], whr, ahr[r]);
        ahz[r] = fmaf(hx[r], whz, ahz[r]);
        ahn[r] = fmaf(hx[r], whn, ahn[r]);
      }
    }
    #pragma unroll
    for (int r = 0; r < 8; ++r) {
      float rg = sigm(air[r] + ahr[r]);
      float zg = sigm(aiz[r] + ahz[r]);
      float ng = tanhf(fmaf(rg, ahn[r], ain[r]));
      float hv = xh[f * LDP + r];
      float hp = (1.f - zg) * ng + zg * hv;
      size_t idx = (size_t)(row0 + r) * FPc + f;
      H[idx] = hp;
      float a = fmaxf(hp, 0.f);
      if (actOut) actOut[idx] = a;
      if (unbOut) unbOut[idx] = hp;
      if (vizOut) vizOut[idx] = a;
    }
  }
}

// -------------------- mol-level sum over atoms ---------------------------------------
__global__ __launch_bounds__(256) void mol_sum_k(
    const __bf16* __restrict__ Hb, const float* __restrict__ ACT, const float* __restrict__ mask,
    float* __restrict__ unb0, float* __restrict__ viz0,
    float* __restrict__ molfeat, float* __restrict__ actmol) {
  const int b = blockIdx.x;
  __shared__ float mk[Lc];
  for (int l = threadIdx.x; l < Lc; l += 256) mk[l] = mask[b * Lc + l];
  __syncthreads();
  const int f = threadIdx.x;
  if (f < FPc) {
    float s1 = 0.f, s2 = 0.f;
    for (int l = 0; l < Lc; ++l) {
      float m = mk[l];
      s1 = fmaf((float)Hb[((size_t)b * Lc + l) * KP + f], m, s1);
      s2 = fmaf(ACT[((size_t)b * Lc + l) * FPc + f], m, s2);
    }
    unb0[b * FPc + f] = s1;
    viz0[b * FPc + f] = s2;
    molfeat[b * FPc + f] = s2;
    actmol[b * FPc + f] = fmaxf(s2, 0.f);
  }
}

// -------------------- mol-level attention over L atoms -------------------------------
__global__ __launch_bounds__(256) void mol_attn_k(
    const float* __restrict__ act, const float* __restrict__ actmol,
    const float* __restrict__ malW, const float* __restrict__ malb,
    const float* __restrict__ mask,
    float* __restrict__ attnOut, float* __restrict__ wact, float* __restrict__ msumw) {
  const int b = blockIdx.x;
  __shared__ float sa_s;
  __shared__ float sn[Lc];
  __shared__ float wl[Lc];
  __shared__ float redmx[2], redsum[2], redsw[2];
  const int wv = threadIdx.x >> 6, lane = threadIdx.x & 63;
  if (wv == 0) {
    float p = 0.f;
    for (int f = lane; f < FPc; f += 64) p = fmaf(actmol[b * FPc + f], malW[f], p);
    float s = wave_sum(p);
    if (lane == 0) sa_s = s;
  }
  for (int l = wv; l < Lc; l += 4) {
    float p = 0.f;
    for (int f = lane; f < FPc; f += 64)
      p = fmaf(act[((size_t)b * Lc + l) * FPc + f], malW[FPc + f], p);
    float s = wave_sum(p);
    if (lane == 0) sn[l] = s;
  }
  __syncthreads();
  const int l = threadIdx.x;
  float sc = -3.0e38f, mval = 0.f;
  if (l < Lc) {
    mval = mask[b * Lc + l];
    sc = leaky(sa_s + sn[l] + malb[0]) + (mval == 0.f ? NEGC : 0.f);
  }
  float m = sc;
  #pragma unroll
  for (int o = 32; o >= 1; o >>= 1) m = fmaxf(m, __shfl_xor(m, o));
  if (lane == 0 && wv < 2) redmx[wv] = m;
  __syncthreads();
  float mx = fmaxf(redmx[0], redmx[1]);
  float e = (l < Lc) ? __expf(sc - mx) : 0.f;
  float s = e;
  #pragma unroll
  for (int o = 32; o >= 1; o >>= 1) s += __shfl_xor(s, o);
  if (lane == 0 && wv < 2) redsum[wv] = s;
  __syncthreads();
  float tot = redsum[0] + redsum[1];
  float w = 0.f;
  if (l < Lc) {
    w = e / tot * mval;
    wl[l] = w;
    attnOut[(size_t)b * Lc + l] = w;
  }
  float swp = w;
  #pragma unroll
  for (int o = 32; o >= 1; o >>= 1) swp += __shfl_xor(swp, o);
  if (lane == 0 && wv < 2) redsw[wv] = swp;
  __syncthreads();
  if (threadIdx.x == 0) msumw[b] = redsw[0] + redsw[1];
  const int f = threadIdx.x;
  if (f < FPc) {
    float a = 0.f;
    for (int l2 = 0; l2 < Lc; ++l2)
      a = fmaf(wl[l2], act[((size_t)b * Lc + l2) * FPc + f], a);
    wact[b * FPc + f] = a;
  }
}

// -------------------- final prediction -----------------------------------------------
__global__ __launch_bounds__(256) void pred_k(
    const float* __restrict__ molfeat, const float* __restrict__ outW,
    const float* __restrict__ outb, float* __restrict__ pred) {
  const int wv = threadIdx.x >> 6, lane = threadIdx.x & 63;
  const int b = blockIdx.x * 4 + wv;
  if (b < Bc) {
    float p = 0.f;
    for (int f = lane; f < FPc; f += 64) p = fmaf(molfeat[b * FPc + f], outW[f], p);
    float s = wave_sum(p);
    if (lane == 0) pred[b] = s + outb[0];
  }
}

extern "C" void kernel_launch(void* const* d_in, const int* in_sizes, int n_in,
                              void* d_out, int out_size, void* d_ws, size_t ws_size,
                              hipStream_t stream) {
  const float* atom_list = (const float*)d_in[0];
  const float* bond_list = (const float*)d_in[1];
  const int*   adl       = (const int*)d_in[2];
  const int*   bdl       = (const int*)d_in[3];
  const float* mask      = (const float*)d_in[4];
  const float* atom_fc_W = (const float*)d_in[5];
  const float* atom_fc_b = (const float*)d_in[6];
  const float* nb_W      = (const float*)d_in[7];
  const float* nb_b      = (const float*)d_in[8];
  const float* align_W   = (const float*)d_in[9];
  const float* align_b   = (const float*)d_in[10];
  const float* attend_W  = (const float*)d_in[11];
  const float* attend_b  = (const float*)d_in[12];
  const float* gru_Wih   = (const float*)d_in[13];
  const float* gru_Whh   = (const float*)d_in[14];
  const float* gru_bih   = (const float*)d_in[15];
  const float* gru_bhh   = (const float*)d_in[16];
  const float* mal_W     = (const float*)d_in[17];
  const float* mal_b     = (const float*)d_in[18];
  const float* matt_W    = (const float*)d_in[19];
  const float* matt_b    = (const float*)d_in[20];
  const float* mWih      = (const float*)d_in[21];
  const float* mWhh      = (const float*)d_in[22];
  const float* mbih      = (const float*)d_in[23];
  const float* mbhh      = (const float*)d_in[24];
  const float* out_W     = (const float*)d_in[25];
  const float* out_b     = (const float*)d_in[26];

  float* out  = (float*)d_out;
  float* AV   = out;                                  // (4,B,L,FP)
  float* ATTN = AV + (size_t)4 * BL * FPc;            // (3,B,L,K)
  float* MV   = ATTN + (size_t)Rc * BL * Kc;          // (3,B,FP)
  float* MU   = MV + (size_t)3 * Bc * FPc;            // (3,B,FP)
  float* MA   = MU + (size_t)3 * Bc * FPc;            // (2,B,L)
  float* PRED = MA + (size_t)Tc * Bc * Lc;            // (B,1)

  char* w = (char*)d_ws;
  __bf16* Hb0  = (__bf16*)w; w += (size_t)BL * KP * 2;
  __bf16* Hb1  = (__bf16*)w; w += (size_t)BL * KP * 2;
  __bf16* XCb  = (__bf16*)w; w += (size_t)BL * KP * 2;
  __bf16* WNb  = (__bf16*)w; w += (size_t)BL * KP * 2;
  __bf16* Pb   = (__bf16*)w; w += (size_t)BL * FPc * 2;
  __bf16* Qb   = (__bf16*)w; w += (size_t)BL * FPc * 2;
  __bf16* Wpk  = (__bf16*)w; w += (size_t)Rc * 6 * 49 * 1024 * 2;
  __bf16* Apk  = (__bf16*)w; w += (size_t)Rc * 49 * 1024 * 2;
  float* SW    = (float*)w;  w += (size_t)BL * 4;
  float* MOLF  = (float*)w;  w += (size_t)Bc * FPc * 4;
  float* ACTM  = (float*)w;  w += (size_t)Bc * FPc * 4;
  float* WACT  = (float*)w;  w += (size_t)Bc * FPc * 4;
  float* MCTX  = (float*)w;  w += (size_t)Bc * FPc * 4;
  float* MSW   = (float*)w;  w += (size_t)Bc * 4;
  float* atomfcT = (float*)w; w += (size_t)AFc * FPc * 4;
  float* naT     = (float*)w; w += (size_t)(AFc + BFc) * FPc * 4;
  float* mattT   = (float*)w; w += (size_t)FPc * FPc * 4;
  float* mWihT   = (float*)w; w += (size_t)FPc * 600 * 4;
  float* mWhhT   = (float*)w; w += (size_t)FPc * 600 * 4;

  transpose_k<<<64, 256, 0, stream>>>(atom_fc_W, atomfcT, FPc, AFc);
  transpose_k<<<64, 256, 0, stream>>>(nb_W, naT, FPc, AFc + BFc);
  transpose_k<<<64, 256, 0, stream>>>(matt_W, mattT, FPc, FPc);
  transpose_k<<<64, 256, 0, stream>>>(mWih, mWihT, 600, FPc);
  transpose_k<<<64, 256, 0, stream>>>(mWhh, mWhhT, 600, FPc);
  pack_gru_k<<<(Rc * 6 * 49 * 1024 + 255) / 256, 256, 0, stream>>>(gru_Wih, gru_Whh, Wpk);
  pack_att_k<<<(Rc * 49 * 1024 + 255) / 256, 256, 0, stream>>>(attend_W, Apk);

  gemm8x1<AFc, 1><<<BL / 8, 256, 0, stream>>>(atom_list, atomfcT, atom_fc_b, nullptr, AV, Hb0);
  gemm8x1<AFc, 0><<<BL / 8, 256, 0, stream>>>(atom_list, naT, nullptr, nullptr, nullptr, Pb);
  gemm8x1<BFc, 0><<<BL / 8, 256, 0, stream>>>(bond_list, naT + AFc * FPc, nullptr, nullptr, nullptr, Qb);

  __bf16* Hbuf[2] = {Hb0, Hb1};
  for (int r = 0; r < Rc; ++r) {
    const float* curp = (r == 0) ? AV : AV + (size_t)r * BL * FPc;
    attn_round<<<BL / 4, 256, 0, stream>>>(r, curp, AV + (size_t)r * BL * FPc,
        Pb, Qb, nb_b, adl, bdl, align_W + (size_t)r * 2 * FPc, align_b,
        ATTN + (size_t)r * BL * Kc, WNb, SW);
    attend_mfma<<<BL / 128, 256, 0, stream>>>(WNb, Apk + (size_t)r * 49 * 1024,
        attend_b + (size_t)r * FPc, SW, XCb);
    gru_mfma<<<BL / 128, 256, 0, stream>>>(XCb, Hbuf[r & 1], Hbuf[(r + 1) & 1],
        Wpk + (size_t)r * 6 * 49 * 1024, gru_bih + (size_t)r * 3 * FPc, gru_bhh + (size_t)r * 3 * FPc,
        AV + (size_t)(r + 1) * BL * FPc);
  }

  mol_sum_k<<<Bc, 256, 0, stream>>>(Hbuf[Rc & 1], AV + (size_t)3 * BL * FPc, mask, MU, MV, MOLF, ACTM);
  for (int t = 0; t < Tc; ++t) {
    mol_attn_k<<<Bc, 256, 0, stream>>>(AV + (size_t)3 * BL * FPc, ACTM, mal_W, mal_b, mask,
        MA + (size_t)t * Bc * Lc, WACT, MSW);
    gemm8x1<FPc, 2><<<Bc / 8, 256, 0, stream>>>(WACT, mattT, matt_b, MSW, MCTX, nullptr);
    gru8<<<Bc / 8, 256, 0, stream>>>(MCTX, MOLF, mWihT, mWhhT, mbih, mbhh,
        ACTM, MU + (size_t)(t + 1) * Bc * FPc, MV + (size_t)(t + 1) * Bc * FPc);
  }
  pred_k<<<Bc / 4, 256, 0, stream>>>(MOLF, out_W, out_b, PRED);
}

// Round 6
// 1221.489 us; speedup vs baseline: 2.5066x; 1.0628x over previous
//
#include <hip/hip_runtime.h>
#include <stdint.h>

#define Bc 512
#define Lc 128
#define Kc 6
#define AFc 39
#define BFc 10
#define FPc 200
#define Rc 3
#define Tc 2
constexpr int BL = Bc * Lc;          // 65536
constexpr int KP = 224;              // padded K / F for MFMA
constexpr float SLOPE = 0.01f;
constexpr float NEGC = -9e8f;

typedef __attribute__((ext_vector_type(8))) __bf16 bf16x8;
typedef __attribute__((ext_vector_type(16))) float f32x16;

__device__ __forceinline__ float leaky(float x) { return x >= 0.f ? x : SLOPE * x; }
__device__ __forceinline__ float sigm(float x) { return 1.f / (1.f + __expf(-x)); }
__device__ __forceinline__ float eluf(float x) { return x > 0.f ? x : expm1f(x); }
__device__ __forceinline__ float wave_sum(float v) {
  #pragma unroll
  for (int m = 32; m >= 1; m >>= 1) v += __shfl_xor(v, m);
  return v;
}
__device__ __forceinline__ float bflo(uint32_t u) { return __uint_as_float(u << 16); }
__device__ __forceinline__ float bfhi(uint32_t u) { return __uint_as_float(u & 0xffff0000u); }
__device__ __forceinline__ unsigned short f2bu(float x) {
  __bf16 b = (__bf16)x;
  return __builtin_bit_cast(unsigned short, b);
}
__device__ __forceinline__ void glds16(const void* g, void* l) {
  __builtin_amdgcn_global_load_lds((const __attribute__((address_space(1))) uint32_t*)g,
      (__attribute__((address_space(3))) uint32_t*)l, 16, 0, 0);
}
__device__ __forceinline__ f32x16 zero16() {
  f32x16 z;
  #pragma unroll
  for (int i = 0; i < 16; ++i) z[i] = 0.f;
  return z;
}

// -------------------- weight transpose: out[c*R + r] = in[r*C + c] --------------------
__global__ void transpose_k(const float* __restrict__ in, float* __restrict__ out, int R, int C) {
  int n = R * C;
  for (int i = blockIdx.x * blockDim.x + threadIdx.x; i < n; i += gridDim.x * blockDim.x) {
    int r = i / C, c = i - r * C;
    out[c * R + r] = in[i];
  }
}

// -------------------- pack GRU weights into staging-linear tiles ---------------------
__global__ void pack_gru_k(const float* __restrict__ Wih, const float* __restrict__ Whh,
                           __bf16* __restrict__ Wpk) {
  int i = blockIdx.x * 256 + threadIdx.x;
  if (i >= Rc * 6 * 7 * 7 * 1024) return;
  int j = i & 7, fl = (i >> 3) & 31, c = (i >> 8) & 3;
  int T = i >> 10;
  int kt = T % 7; T /= 7;
  int ft = T % 7; T /= 7;
  int g = T % 6;  int r = T / 6;
  int f = ft * 32 + fl, k = kt * 32 + c * 8 + j;
  float v = 0.f;
  if (f < FPc && k < FPc) {
    if (g < 3) v = Wih[((size_t)r * 3 * FPc + g * FPc + f) * FPc + k];
    else       v = Whh[((size_t)r * 3 * FPc + (g - 3) * FPc + f) * FPc + k];
  }
  Wpk[i] = (__bf16)v;
}

// Apk layout: [r][ft7][kt7]{1024: [c4][f32][j8]}
__global__ void pack_att_k(const float* __restrict__ W, __bf16* __restrict__ Apk) {
  int i = blockIdx.x * 256 + threadIdx.x;
  if (i >= Rc * 7 * 7 * 1024) return;
  int j = i & 7, fl = (i >> 3) & 31, c = (i >> 8) & 3;
  int T = i >> 10;
  int kt = T % 7; T /= 7;
  int ft = T % 7; int r = T / 7;
  int f = ft * 32 + fl, k = kt * 32 + c * 8 + j;
  float v = (f < FPc && k < FPc) ? W[((size_t)r * FPc + f) * FPc + k] : 0.f;
  Apk[i] = (__bf16)v;
}

// -------------------- generic small GEMM (f32): Y[rows][200] ------------------------
template<int KD, int EPI>
__global__ __launch_bounds__(256) void gemm8x1(
    const float* __restrict__ X, const float* __restrict__ WT,
    const float* __restrict__ bias, const float* __restrict__ sumw,
    float* __restrict__ Y, __bf16* __restrict__ Yb) {
  constexpr int TR = 8, LDP = 12;
  __shared__ float xT[KD * LDP];
  const int row0 = blockIdx.x * TR;
  const int tid = threadIdx.x;
  for (int e = tid; e < TR * KD; e += 256) {
    int r = e / KD, g = e - r * KD;
    xT[g * LDP + r] = X[(size_t)row0 * KD + e];
  }
  __syncthreads();
  const int f = tid;
  if (f < FPc) {
    float acc[TR];
    #pragma unroll
    for (int r = 0; r < TR; ++r) acc[r] = 0.f;
    #pragma unroll 4
    for (int g = 0; g < KD; ++g) {
      float w = WT[(size_t)g * FPc + f];
      float4 x0 = *reinterpret_cast<const float4*>(&xT[g * LDP]);
      float4 x1 = *reinterpret_cast<const float4*>(&xT[g * LDP + 4]);
      acc[0] = fmaf(x0.x, w, acc[0]); acc[1] = fmaf(x0.y, w, acc[1]);
      acc[2] = fmaf(x0.z, w, acc[2]); acc[3] = fmaf(x0.w, w, acc[3]);
      acc[4] = fmaf(x1.x, w, acc[4]); acc[5] = fmaf(x1.y, w, acc[5]);
      acc[6] = fmaf(x1.z, w, acc[6]); acc[7] = fmaf(x1.w, w, acc[7]);
    }
    #pragma unroll
    for (int r = 0; r < TR; ++r) {
      if (EPI == 0) {
        Yb[(size_t)(row0 + r) * FPc + f] = (__bf16)acc[r];
      } else if (EPI == 1) {
        float v = acc[r] + bias[f];
        Y[(size_t)(row0 + r) * FPc + f] = v;                 // raw atom_lin (viz)
        Yb[(size_t)(row0 + r) * KP + f] = (__bf16)leaky(v);  // h0
      } else {
        float v = fmaf(sumw[row0 + r], bias[f], acc[r]);
        Y[(size_t)(row0 + r) * FPc + f] = eluf(v);
      }
    }
  } else if (EPI == 1 && f < KP) {
    #pragma unroll
    for (int r = 0; r < TR; ++r) Yb[(size_t)(row0 + r) * KP + f] = (__bf16)0.f;
  }
}

// -------------------- MFMA GRU v4: xc in reg-frags, h in LDS, 2 blocks/CU ------------
__global__ __launch_bounds__(256, 2) void gru_mfma(
    const __bf16* __restrict__ XCb, const __bf16* __restrict__ Hin,
    __bf16* __restrict__ Hout, const __bf16* __restrict__ Wpk,
    const float* __restrict__ bih, const float* __restrict__ bhh,
    float* __restrict__ actOut) {
  __shared__ __align__(16) __bf16 smem[40960];   // 81920 B
  __bf16* Ah = smem;                              // [wv4][kt7][1024]
  __bf16* Bs = smem + 28672;                      // [buf2][g6][1024]
  const int tid = threadIdx.x, wv = tid >> 6, lane = tid & 63;
  const size_t row0 = (size_t)blockIdx.x * 128;

  {
    int rlo = lane & 31, chi = lane >> 5;
    const __bf16* sh = Hin + (row0 + wv * 32 + rlo) * KP + chi * 8;
    #pragma unroll
    for (int kt = 0; kt < 7; ++kt)
      #pragma unroll
      for (int hc = 0; hc < 2; ++hc)
        glds16(sh + kt * 32 + hc * 16, Ah + wv * 7168 + kt * 1024 + hc * 512);
  }
  bf16x8 xcf[7][2];
  {
    const __bf16* sx = XCb + (row0 + wv * 32 + (lane & 31)) * KP + (lane >> 5) * 8;
    #pragma unroll
    for (int kt = 0; kt < 7; ++kt)
      #pragma unroll
      for (int h = 0; h < 2; ++h)
        xcf[kt][h] = *(const bf16x8*)(sx + kt * 32 + h * 16);
  }
  auto stageB = [&](int ft, int kt, int buf) {
    #pragma unroll
    for (int m3 = 0; m3 < 3; ++m3) {
      int m = wv * 3 + m3;               // 0..11
      int g = m >> 1, half = m & 1;
      const __bf16* s = Wpk + ((size_t)(g * 7 + ft) * 7 + kt) * 1024 + half * 512 + lane * 8;
      glds16(s, Bs + buf * 6144 + g * 1024 + half * 512);
    }
  };
  stageB(0, 0, 0);

  f32x16 acc[6];
  #pragma unroll
  for (int g = 0; g < 6; ++g) acc[g] = zero16();

  for (int ft = 0; ft < 7; ++ft) {
    #pragma unroll
    for (int kt = 0; kt < 7; ++kt) {
      const int it = ft * 7 + kt;
      const int buf = it & 1;
      const int nft = (kt == 6) ? ft + 1 : ft;
      const int nkt = (kt == 6) ? 0 : kt + 1;
      __builtin_amdgcn_sched_barrier(0);
      if (it < 48) stageB(nft, nkt, buf ^ 1);
      else         stageB(6, 6, buf ^ 1);          // dummy: keep 3 outstanding
      __builtin_amdgcn_sched_barrier(0);
      asm volatile("s_waitcnt vmcnt(3)" ::: "memory");
      __builtin_amdgcn_sched_barrier(0);
      __builtin_amdgcn_s_barrier();
      __builtin_amdgcn_sched_barrier(0);
      #pragma unroll
      for (int h = 0; h < 2; ++h) {
        bf16x8 ah = *(const bf16x8*)(Ah + wv * 7168 + kt * 1024 + h * 512 + lane * 8);
        const __bf16* bb = Bs + buf * 6144 + h * 512 + lane * 8;
        bf16x8 b0 = *(const bf16x8*)(bb);
        bf16x8 b1 = *(const bf16x8*)(bb + 1024);
        bf16x8 b2 = *(const bf16x8*)(bb + 2048);
        bf16x8 b3 = *(const bf16x8*)(bb + 3072);
        bf16x8 b4 = *(const bf16x8*)(bb + 4096);
        bf16x8 b5 = *(const bf16x8*)(bb + 5120);
        __builtin_amdgcn_s_setprio(1);
        acc[0] = __builtin_amdgcn_mfma_f32_32x32x16_bf16(xcf[kt][h], b0, acc[0], 0, 0, 0);
        acc[1] = __builtin_amdgcn_mfma_f32_32x32x16_bf16(xcf[kt][h], b1, acc[1], 0, 0, 0);
        acc[2] = __builtin_amdgcn_mfma_f32_32x32x16_bf16(xcf[kt][h], b2, acc[2], 0, 0, 0);
        acc[3] = __builtin_amdgcn_mfma_f32_32x32x16_bf16(ah, b3, acc[3], 0, 0, 0);
        acc[4] = __builtin_amdgcn_mfma_f32_32x32x16_bf16(ah, b4, acc[4], 0, 0, 0);
        acc[5] = __builtin_amdgcn_mfma_f32_32x32x16_bf16(ah, b5, acc[5], 0, 0, 0);
        __builtin_amdgcn_s_setprio(0);
      }
      if (kt == 6) {
        const int f = ft * 32 + (lane & 31);
        const bool fok = f < FPc;
        float bir = 0, biz = 0, bin_ = 0, bhr = 0, bhz = 0, bhn = 0;
        if (fok) {
          bir = bih[f]; biz = bih[FPc + f]; bin_ = bih[2 * FPc + f];
          bhr = bhh[f]; bhz = bhh[FPc + f]; bhn = bhh[2 * FPc + f];
        }
        const int hoff = wv * 7168 + (f >> 5) * 1024 + ((f >> 3) & 3) * 256 + (f & 7);
        #pragma unroll
        for (int reg = 0; reg < 16; ++reg) {
          int rl = (reg & 3) + 8 * (reg >> 2) + 4 * (lane >> 5);
          size_t row = row0 + wv * 32 + rl;
          if (fok) {
            float ho = (float)Ah[hoff + rl * 8];
            float rg_ = sigm(acc[0][reg] + bir + acc[3][reg] + bhr);
            float zg  = sigm(acc[1][reg] + biz + acc[4][reg] + bhz);
            float ng  = tanhf(acc[2][reg] + bin_ + rg_ * (acc[5][reg] + bhn));
            float hp = (1.f - zg) * ng + zg * ho;
            Hout[row * KP + f] = (__bf16)hp;
            actOut[row * FPc + f] = fmaxf(hp, 0.f);
          } else {
            Hout[row * KP + f] = (__bf16)0.f;
          }
        }
        #pragma unroll
        for (int g = 0; g < 6; ++g) acc[g] = zero16();
      }
      __builtin_amdgcn_sched_barrier(0);
      __builtin_amdgcn_s_barrier();
      __builtin_amdgcn_sched_barrier(0);
    }
  }
}

// -------------------- MFMA attend v4: LDS-free, barrier-free -------------------------
__global__ __launch_bounds__(256, 2) void attend_mfma(
    const __bf16* __restrict__ WNb, const __bf16* __restrict__ Apk,
    const float* __restrict__ bias, const float* __restrict__ SW,
    __bf16* __restrict__ XCb) {
  const int tid = threadIdx.x, wv = tid >> 6, lane = tid & 63;
  const size_t row0 = (size_t)blockIdx.x * 128;

  bf16x8 af[7][2];
  {
    const __bf16* sw_ = WNb + (row0 + wv * 32 + (lane & 31)) * KP + (lane >> 5) * 8;
    #pragma unroll
    for (int kt = 0; kt < 7; ++kt)
      #pragma unroll
      for (int h = 0; h < 2; ++h)
        af[kt][h] = *(const bf16x8*)(sw_ + kt * 32 + h * 16);
  }

  for (int ft = 0; ft < 7; ++ft) {
    f32x16 acc = zero16();
    #pragma unroll
    for (int kt = 0; kt < 7; ++kt) {
      const __bf16* bt = Apk + ((size_t)ft * 7 + kt) * 1024 + lane * 8;
      bf16x8 b0 = *(const bf16x8*)(bt);
      bf16x8 b1 = *(const bf16x8*)(bt + 512);
      acc = __builtin_amdgcn_mfma_f32_32x32x16_bf16(af[kt][0], b0, acc, 0, 0, 0);
      acc = __builtin_amdgcn_mfma_f32_32x32x16_bf16(af[kt][1], b1, acc, 0, 0, 0);
    }
    const int f = ft * 32 + (lane & 31);
    const bool fok = f < FPc;
    float bf = fok ? bias[f] : 0.f;
    #pragma unroll
    for (int reg = 0; reg < 16; ++reg) {
      int rl = (reg & 3) + 8 * (reg >> 2) + 4 * (lane >> 5);
      size_t row = row0 + wv * 32 + rl;
      if (fok) {
        float v = acc[reg] + SW[row] * bf;
        XCb[row * KP + f] = (__bf16)eluf(v);
      } else {
        XCb[row * KP + f] = (__bf16)0.f;
      }
    }
  }
}

// -------------------- attn round r>=1: per-molecule block ---------------------------
// act = relu(Hb). sn[l] factored per-atom; weighted sum from LDS.
__global__ __launch_bounds__(256) void attn_molN(
    const __bf16* __restrict__ Hb,       // [BL][KP]
    const int* __restrict__ adl,
    const float* __restrict__ alW,       // +r*2*FP
    const float* __restrict__ albp,      // +r
    float* __restrict__ attnOut, __bf16* __restrict__ WNb, float* __restrict__ SW) {
  __shared__ __align__(16) __bf16 actL[128 * 224];
  __shared__ float saL[128], snL[128];
  const int b = blockIdx.x;
  const int tid = threadIdx.x, wv = tid >> 6, lane = tid & 63;
  const bool l36 = lane < 36;

  // ---- stage act = relu(Hb) ----
  {
    const uint4* src = (const uint4*)(Hb + (size_t)b * 128 * KP);
    uint4* dst = (uint4*)actL;
    for (int i = tid; i < 128 * 224 / 8; i += 256) {
      uint4 v = src[i];
      uint32_t c[4] = {v.x, v.y, v.z, v.w};
      #pragma unroll
      for (int j = 0; j < 4; ++j) {
        uint32_t lo = c[j] & 0xffffu, hi = c[j] >> 16;
        if (lo & 0x8000u) lo = 0;
        if (hi & 0x8000u) hi = 0;
        c[j] = lo | (hi << 16);
      }
      dst[i] = make_uint4(c[0], c[1], c[2], c[3]);
    }
  }
  // weight pairs in regs
  float wa0x = alW[2 * lane], wa0y = alW[2 * lane + 1];
  float wa1x = l36 ? alW[128 + 2 * lane] : 0.f, wa1y = l36 ? alW[129 + 2 * lane] : 0.f;
  float wn0x = alW[FPc + 2 * lane], wn0y = alW[FPc + 2 * lane + 1];
  float wn1x = l36 ? alW[FPc + 128 + 2 * lane] : 0.f, wn1y = l36 ? alW[FPc + 129 + 2 * lane] : 0.f;
  const float ab = albp[0];
  __syncthreads();

  // ---- per-atom dots: sa[l], sn[l] ----
  for (int i = 0; i < 32; ++i) {
    int l = wv * 32 + i;
    const uint32_t* rowp = (const uint32_t*)(actL + l * 224);
    uint32_t u0 = rowp[lane];
    uint32_t u1 = l36 ? rowp[64 + lane] : 0u;
    float x0 = bflo(u0), y0 = bfhi(u0), x1 = bflo(u1), y1 = bfhi(u1);
    float psa = x0 * wa0x + y0 * wa0y + x1 * wa1x + y1 * wa1y;
    float psn = x0 * wn0x + y0 * wn0y + x1 * wn1x + y1 * wn1y;
    psa = wave_sum(psa);
    psn = wave_sum(psn);
    if (lane == 0) { saL[l] = psa; snL[l] = psn; }
  }
  __syncthreads();

  // ---- per-row: softmax over 6 neighbors + weighted sum ----
  for (int i = 0; i < 32; ++i) {
    const int row = wv * 32 + i;
    const size_t grow = (size_t)b * 128 + row;
    int gk = (lane < Kc) ? adl[grow * Kc + lane] : 0;
    int ai[Kc];
    #pragma unroll
    for (int k = 0; k < Kc; ++k) ai[k] = __shfl(gk, k);
    const float sarow = saL[row];
    float s[Kc]; bool pad[Kc]; float mx = -3.0e38f;
    #pragma unroll
    for (int k = 0; k < Kc; ++k) {
      pad[k] = (ai[k] == Lc - 1);
      s[k] = leaky(sarow + snL[ai[k]] + ab) + (pad[k] ? NEGC : 0.f);
      mx = fmaxf(mx, s[k]);
    }
    float e[Kc], sum = 0.f;
    #pragma unroll
    for (int k = 0; k < Kc; ++k) { e[k] = __expf(s[k] - mx); sum += e[k]; }
    float inv = 1.f / sum;
    float w[Kc], sw = 0.f;
    #pragma unroll
    for (int k = 0; k < Kc; ++k) { w[k] = pad[k] ? 0.f : e[k] * inv; sw += w[k]; }
    if (lane < Kc) attnOut[grow * Kc + lane] = w[lane];
    if (lane == 0) SW[grow] = sw;
    float a0 = 0.f, b0 = 0.f, a1 = 0.f, b1 = 0.f;
    #pragma unroll
    for (int k = 0; k < Kc; ++k) {
      const uint32_t* nr = (const uint32_t*)(actL + ai[k] * 224);
      uint32_t u0 = nr[lane];
      uint32_t u1 = l36 ? nr[64 + lane] : 0u;
      a0 = fmaf(w[k], bflo(u0), a0); b0 = fmaf(w[k], bfhi(u0), b0);
      a1 = fmaf(w[k], bflo(u1), a1); b1 = fmaf(w[k], bfhi(u1), b1);
    }
    __bf16* wr = WNb + grow * KP;
    ushort2 o0; o0.x = f2bu(a0); o0.y = f2bu(b0);
    *(ushort2*)(wr + 2 * lane) = o0;
    if (lane < 48) {
      float va = l36 ? a1 : 0.f, vb = l36 ? b1 : 0.f;
      ushort2 o1; o1.x = f2bu(va); o1.y = f2bu(vb);
      *(ushort2*)(wr + 128 + 2 * lane) = o1;
    }
  }
}

// -------------------- attn round r==0: per-molecule block ---------------------------
// neigh = leaky(P[ai]+Q[bi]+nbb) recomputed on the fly from LDS P,Q.
__global__ __launch_bounds__(256) void attn_mol0(
    const __bf16* __restrict__ Pb, const __bf16* __restrict__ Qb,
    const float* __restrict__ nbb, const __bf16* __restrict__ Hb0,
    const int* __restrict__ adl, const int* __restrict__ bdl,
    const float* __restrict__ alW, const float* __restrict__ albp,
    float* __restrict__ attnOut, __bf16* __restrict__ WNb, float* __restrict__ SW) {
  __shared__ __align__(16) __bf16 Pl[128 * 200];
  __shared__ __align__(16) __bf16 Ql[128 * 200];
  __shared__ float nbbL[200];
  __shared__ float saL[128];
  const int b = blockIdx.x;
  const int tid = threadIdx.x, wv = tid >> 6, lane = tid & 63;
  const bool l36 = lane < 36;

  {
    const uint4* sp = (const uint4*)(Pb + (size_t)b * 128 * FPc);
    const uint4* sq = (const uint4*)(Qb + (size_t)b * 128 * FPc);
    uint4* dp = (uint4*)Pl;
    uint4* dq = (uint4*)Ql;
    for (int i = tid; i < 128 * 200 / 8; i += 256) { dp[i] = sp[i]; dq[i] = sq[i]; }
    for (int i = tid; i < FPc; i += 256) nbbL[i] = nbb[i];
  }
  float wa0x = alW[2 * lane], wa0y = alW[2 * lane + 1];
  float wa1x = l36 ? alW[128 + 2 * lane] : 0.f, wa1y = l36 ? alW[129 + 2 * lane] : 0.f;
  float wn0x = alW[FPc + 2 * lane], wn0y = alW[FPc + 2 * lane + 1];
  float wn1x = l36 ? alW[FPc + 128 + 2 * lane] : 0.f, wn1y = l36 ? alW[FPc + 129 + 2 * lane] : 0.f;
  const float ab = albp[0];

  // per-atom sa from global Hb0 (leaky(atom_lin) already applied, bf16, stride KP)
  for (int i = 0; i < 32; ++i) {
    int l = wv * 32 + i;
    const uint32_t* hr = (const uint32_t*)(Hb0 + ((size_t)b * 128 + l) * KP);
    uint32_t u0 = hr[lane];
    uint32_t u1 = l36 ? hr[64 + lane] : 0u;
    float psa = bflo(u0) * wa0x + bfhi(u0) * wa0y + bflo(u1) * wa1x + bfhi(u1) * wa1y;
    psa = wave_sum(psa);
    if (lane == 0) saL[l] = psa;
  }
  __syncthreads();

  const float n0x = nbbL[2 * lane], n0y = nbbL[2 * lane + 1];
  const float n1x = l36 ? nbbL[128 + 2 * lane] : 0.f, n1y = l36 ? nbbL[129 + 2 * lane] : 0.f;

  for (int i = 0; i < 32; ++i) {
    const int row = wv * 32 + i;
    const size_t grow = (size_t)b * 128 + row;
    int gk = (lane < Kc) ? adl[grow * Kc + lane] : 0;
    int hk = (lane < Kc) ? bdl[grow * Kc + lane] : 0;
    int ai[Kc], bi[Kc];
    #pragma unroll
    for (int k = 0; k < Kc; ++k) { ai[k] = __shfl(gk, k); bi[k] = __shfl(hk, k); }
    const float sarow = saL[row];
    float s[Kc]; bool pad[Kc]; float mx = -3.0e38f;
    #pragma unroll
    for (int k = 0; k < Kc; ++k) {
      const uint32_t* pr = (const uint32_t*)(Pl + ai[k] * 200);
      const uint32_t* qr = (const uint32_t*)(Ql + bi[k] * 200);
      uint32_t up0 = pr[lane], uq0 = qr[lane];
      uint32_t up1 = l36 ? pr[64 + lane] : 0u, uq1 = l36 ? qr[64 + lane] : 0u;
      float v0x = leaky(bflo(up0) + bflo(uq0) + n0x);
      float v0y = leaky(bfhi(up0) + bfhi(uq0) + n0y);
      float v1x = l36 ? leaky(bflo(up1) + bflo(uq1) + n1x) : 0.f;
      float v1y = l36 ? leaky(bfhi(up1) + bfhi(uq1) + n1y) : 0.f;
      float p = v0x * wn0x + v0y * wn0y + v1x * wn1x + v1y * wn1y;
      s[k] = wave_sum(p);
    }
    #pragma unroll
    for (int k = 0; k < Kc; ++k) {
      pad[k] = (ai[k] == Lc - 1);
      s[k] = leaky(sarow + s[k] + ab) + (pad[k] ? NEGC : 0.f);
      mx = fmaxf(mx, s[k]);
    }
    float e[Kc], sum = 0.f;
    #pragma unroll
    for (int k = 0; k < Kc; ++k) { e[k] = __expf(s[k] - mx); sum += e[k]; }
    float inv = 1.f / sum;
    float w[Kc], sw = 0.f;
    #pragma unroll
    for (int k = 0; k < Kc; ++k) { w[k] = pad[k] ? 0.f : e[k] * inv; sw += w[k]; }
    if (lane < Kc) attnOut[grow * Kc + lane] = w[lane];
    if (lane == 0) SW[grow] = sw;
    float a0 = 0.f, b0v = 0.f, a1 = 0.f, b1v = 0.f;
    #pragma unroll
    for (int k = 0; k < Kc; ++k) {
      const uint32_t* pr = (const uint32_t*)(Pl + ai[k] * 200);
      const uint32_t* qr = (const uint32_t*)(Ql + bi[k] * 200);
      uint32_t up0 = pr[lane], uq0 = qr[lane];
      uint32_t up1 = l36 ? pr[64 + lane] : 0u, uq1 = l36 ? qr[64 + lane] : 0u;
      a0  = fmaf(w[k], leaky(bflo(up0) + bflo(uq0) + n0x), a0);
      b0v = fmaf(w[k], leaky(bfhi(up0) + bfhi(uq0) + n0y), b0v);
      if (l36) {
        a1  = fmaf(w[k], leaky(bflo(up1) + bflo(uq1) + n1x), a1);
        b1v = fmaf(w[k], leaky(bfhi(up1) + bfhi(uq1) + n1y), b1v);
      }
    }
    __bf16* wr = WNb + grow * KP;
    ushort2 o0; o0.x = f2bu(a0); o0.y = f2bu(b0v);
    *(ushort2*)(wr + 2 * lane) = o0;
    if (lane < 48) {
      float va = l36 ? a1 : 0.f, vb = l36 ? b1v : 0.f;
      ushort2 o1; o1.x = f2bu(va); o1.y = f2bu(vb);
      *(ushort2*)(wr + 128 + 2 * lane) = o1;
    }
  }
}

// -------------------- fused GRU f32 (mol path, 512 rows) -----------------------------
__global__ __launch_bounds__(256) void gru8(
    const float* __restrict__ XC, float* __restrict__ H,
    const float* __restrict__ WihT, const float* __restrict__ WhhT,
    const float* __restrict__ bih, const float* __restrict__ bhh,
    float* __restrict__ actOut, float* __restrict__ unbOut, float* __restrict__ vizOut) {
  constexpr int TR = 8, LDP = 12;
  __shared__ float xc[FPc * LDP];
  __shared__ float xh[FPc * LDP];
  const int row0 = blockIdx.x * TR;
  const int tid = threadIdx.x;
  for (int e = tid; e < TR * FPc; e += 256) {
    int r = e / FPc, g = e - r * FPc;
    xc[g * LDP + r] = XC[(size_t)row0 * FPc + e];
    xh[g * LDP + r] = H[(size_t)row0 * FPc + e];
  }
  __syncthreads();
  const int f = tid;
  if (f < FPc) {
    float air[8], aiz[8], ain[8], ahr[8], ahz[8], ahn[8];
    const float bir = bih[f], biz = bih[f + 200], bin_ = bih[f + 400];
    const float bhr = bhh[f], bhz = bhh[f + 200], bhn = bhh[f + 400];
    #pragma unroll
    for (int r = 0; r < 8; ++r) {
      air[r] = bir; aiz[r] = biz; ain[r] = bin_;
      ahr[r] = bhr; ahz[r] = bhz; ahn[r] = bhn;
    }
    #pragma unroll 2
    for (int g = 0; g < FPc; ++g) {
      const float* wi = &WihT[(size_t)g * 600 + f];
      const float* wh = &WhhT[(size_t)g * 600 + f];
      float wir = wi[0], wiz = wi[200], win = wi[400];
      float whr = wh[0], whz = wh[200], whn = wh[400];
      float4 c0 = *reinterpret_cast<const float4*>(&xc[g * LDP]);
      float4 c1 = *reinterpret_cast<const float4*>(&xc[g * LDP + 4]);
      float4 h0 = *reinterpret_cast<const float4*>(&xh[g * LDP]);
      float4 h1 = *reinterpret_cast<const float4*>(&xh[g * LDP + 4]);
      float cx[8] = {c0.x, c0.y, c0.z, c0.w, c1.x, c1.y, c1.z, c1.w};
      float hx[8] = {h0.x, h0.y, h0.z, h0.w, h1.x, h1.y, h1.z, h1.w};
      #pragma unroll
      for (int r = 0; r < 8; ++r) {
        air[r] = fmaf(cx[r], wir, air[r]);
        aiz[r] = fmaf(cx[r], wiz, aiz[r]);
        ain[r] = fmaf(cx[r], win, ain[r]);
        ahr[r] = fmaf(hx[r], whr, ahr[r]);
        ahz[r] = fmaf(hx[r], whz, ahz[r]);
        ahn[r] = fmaf(hx[r], whn, ahn[r]);
      }
    }
    #pragma unroll
    for (int r = 0; r < 8; ++r) {
      float rg = sigm(air[r] + ahr[r]);
      float zg = sigm(aiz[r] + ahz[r]);
      float ng = tanhf(fmaf(rg, ahn[r], ain[r]));
      float hv = xh[f * LDP + r];
      float hp = (1.f - zg) * ng + zg * hv;
      size_t idx = (size_t)(row0 + r) * FPc + f;
      H[idx] = hp;
      float a = fmaxf(hp, 0.f);
      if (actOut) actOut[idx] = a;
      if (unbOut) unbOut[idx] = hp;
      if (vizOut) vizOut[idx] = a;
    }
  }
}

// -------------------- mol-level sum over atoms ---------------------------------------
__global__ __launch_bounds__(256) void mol_sum_k(
    const __bf16* __restrict__ Hb, const float* __restrict__ ACT, const float* __restrict__ mask,
    float* __restrict__ unb0, float* __restrict__ viz0,
    float* __restrict__ molfeat, float* __restrict__ actmol) {
  const int b = blockIdx.x;
  __shared__ float mk[Lc];
  for (int l = threadIdx.x; l < Lc; l += 256) mk[l] = mask[b * Lc + l];
  __syncthreads();
  const int f = threadIdx.x;
  if (f < FPc) {
    float s1 = 0.f, s2 = 0.f;
    for (int l = 0; l < Lc; ++l) {
      float m = mk[l];
      s1 = fmaf((float)Hb[((size_t)b * Lc + l) * KP + f], m, s1);
      s2 = fmaf(ACT[((size_t)b * Lc + l) * FPc + f], m, s2);
    }
    unb0[b * FPc + f] = s1;
    viz0[b * FPc + f] = s2;
    molfeat[b * FPc + f] = s2;
    actmol[b * FPc + f] = fmaxf(s2, 0.f);
  }
}

// -------------------- mol-level attention over L atoms -------------------------------
__global__ __launch_bounds__(256) void mol_attn_k(
    const float* __restrict__ act, const float* __restrict__ actmol,
    const float* __restrict__ malW, const float* __restrict__ malb,
    const float* __restrict__ mask,
    float* __restrict__ attnOut, float* __restrict__ wact, float* __restrict__ msumw) {
  const int b = blockIdx.x;
  __shared__ float sa_s;
  __shared__ float sn[Lc];
  __shared__ float wl[Lc];
  __shared__ float redmx[2], redsum[2], redsw[2];
  const int wv = threadIdx.x >> 6, lane = threadIdx.x & 63;
  if (wv == 0) {
    float p = 0.f;
    for (int f = lane; f < FPc; f += 64) p = fmaf(actmol[b * FPc + f], malW[f], p);
    float s = wave_sum(p);
    if (lane == 0) sa_s = s;
  }
  for (int l = wv; l < Lc; l += 4) {
    float p = 0.f;
    for (int f = lane; f < FPc; f += 64)
      p = fmaf(act[((size_t)b * Lc + l) * FPc + f], malW[FPc + f], p);
    float s = wave_sum(p);
    if (lane == 0) sn[l] = s;
  }
  __syncthreads();
  const int l = threadIdx.x;
  float sc = -3.0e38f, mval = 0.f;
  if (l < Lc) {
    mval = mask[b * Lc + l];
    sc = leaky(sa_s + sn[l] + malb[0]) + (mval == 0.f ? NEGC : 0.f);
  }
  float m = sc;
  #pragma unroll
  for (int o = 32; o >= 1; o >>= 1) m = fmaxf(m, __shfl_xor(m, o));
  if (lane == 0 && wv < 2) redmx[wv] = m;
  __syncthreads();
  float mx = fmaxf(redmx[0], redmx[1]);
  float e = (l < Lc) ? __expf(sc - mx) : 0.f;
  float s = e;
  #pragma unroll
  for (int o = 32; o >= 1; o >>= 1) s += __shfl_xor(s, o);
  if (lane == 0 && wv < 2) redsum[wv] = s;
  __syncthreads();
  float tot = redsum[0] + redsum[1];
  float w = 0.f;
  if (l < Lc) {
    w = e / tot * mval;
    wl[l] = w;
    attnOut[(size_t)b * Lc + l] = w;
  }
  float swp = w;
  #pragma unroll
  for (int o = 32; o >= 1; o >>= 1) swp += __shfl_xor(swp, o);
  if (lane == 0 && wv < 2) redsw[wv] = swp;
  __syncthreads();
  if (threadIdx.x == 0) msumw[b] = redsw[0] + redsw[1];
  const int f = threadIdx.x;
  if (f < FPc) {
    float a = 0.f;
    for (int l2 = 0; l2 < Lc; ++l2)
      a = fmaf(wl[l2], act[((size_t)b * Lc + l2) * FPc + f], a);
    wact[b * FPc + f] = a;
  }
}

// -------------------- final prediction -----------------------------------------------
__global__ __launch_bounds__(256) void pred_k(
    const float* __restrict__ molfeat, const float* __restrict__ outW,
    const float* __restrict__ outb, float* __restrict__ pred) {
  const int wv = threadIdx.x >> 6, lane = threadIdx.x & 63;
  const int b = blockIdx.x * 4 + wv;
  if (b < Bc) {
    float p = 0.f;
    for (int f = lane; f < FPc; f += 64) p = fmaf(molfeat[b * FPc + f], outW[f], p);
    float s = wave_sum(p);
    if (lane == 0) pred[b] = s + outb[0];
  }
}

extern "C" void kernel_launch(void* const* d_in, const int* in_sizes, int n_in,
                              void* d_out, int out_size, void* d_ws, size_t ws_size,
                              hipStream_t stream) {
  const float* atom_list = (const float*)d_in[0];
  const float* bond_list = (const float*)d_in[1];
  const int*   adl       = (const int*)d_in[2];
  const int*   bdl       = (const int*)d_in[3];
  const float* mask      = (const float*)d_in[4];
  const float* atom_fc_W = (const float*)d_in[5];
  const float* atom_fc_b = (const float*)d_in[6];
  const float* nb_W      = (const float*)d_in[7];
  const float* nb_b      = (const float*)d_in[8];
  const float* align_W   = (const float*)d_in[9];
  const float* align_b   = (const float*)d_in[10];
  const float* attend_W  = (const float*)d_in[11];
  const float* attend_b  = (const float*)d_in[12];
  const float* gru_Wih   = (const float*)d_in[13];
  const float* gru_Whh   = (const float*)d_in[14];
  const float* gru_bih   = (const float*)d_in[15];
  const float* gru_bhh   = (const float*)d_in[16];
  const float* mal_W     = (const float*)d_in[17];
  const float* mal_b     = (const float*)d_in[18];
  const float* matt_W    = (const float*)d_in[19];
  const float* matt_b    = (const float*)d_in[20];
  const float* mWih      = (const float*)d_in[21];
  const float* mWhh      = (const float*)d_in[22];
  const float* mbih      = (const float*)d_in[23];
  const float* mbhh      = (const float*)d_in[24];
  const float* out_W     = (const float*)d_in[25];
  const float* out_b     = (const float*)d_in[26];

  float* out  = (float*)d_out;
  float* AV   = out;                                  // (4,B,L,FP)
  float* ATTN = AV + (size_t)4 * BL * FPc;            // (3,B,L,K)
  float* MV   = ATTN + (size_t)Rc * BL * Kc;          // (3,B,FP)
  float* MU   = MV + (size_t)3 * Bc * FPc;            // (3,B,FP)
  float* MA   = MU + (size_t)3 * Bc * FPc;            // (2,B,L)
  float* PRED = MA + (size_t)Tc * Bc * Lc;            // (B,1)

  char* w = (char*)d_ws;
  __bf16* Hb0  = (__bf16*)w; w += (size_t)BL * KP * 2;
  __bf16* Hb1  = (__bf16*)w; w += (size_t)BL * KP * 2;
  __bf16* XCb  = (__bf16*)w; w += (size_t)BL * KP * 2;
  __bf16* WNb  = (__bf16*)w; w += (size_t)BL * KP * 2;
  __bf16* Pb   = (__bf16*)w; w += (size_t)BL * FPc * 2;
  __bf16* Qb   = (__bf16*)w; w += (size_t)BL * FPc * 2;
  __bf16* Wpk  = (__bf16*)w; w += (size_t)Rc * 6 * 49 * 1024 * 2;
  __bf16* Apk  = (__bf16*)w; w += (size_t)Rc * 49 * 1024 * 2;
  float* SW    = (float*)w;  w += (size_t)BL * 4;
  float* MOLF  = (float*)w;  w += (size_t)Bc * FPc * 4;
  float* ACTM  = (float*)w;  w += (size_t)Bc * FPc * 4;
  float* WACT  = (float*)w;  w += (size_t)Bc * FPc * 4;
  float* MCTX  = (float*)w;  w += (size_t)Bc * FPc * 4;
  float* MSW   = (float*)w;  w += (size_t)Bc * 4;
  float* atomfcT = (float*)w; w += (size_t)AFc * FPc * 4;
  float* naT     = (float*)w; w += (size_t)(AFc + BFc) * FPc * 4;
  float* mattT   = (float*)w; w += (size_t)FPc * FPc * 4;
  float* mWihT   = (float*)w; w += (size_t)FPc * 600 * 4;
  float* mWhhT   = (float*)w; w += (size_t)FPc * 600 * 4;

  transpose_k<<<64, 256, 0, stream>>>(atom_fc_W, atomfcT, FPc, AFc);
  transpose_k<<<64, 256, 0, stream>>>(nb_W, naT, FPc, AFc + BFc);
  transpose_k<<<64, 256, 0, stream>>>(matt_W, mattT, FPc, FPc);
  transpose_k<<<64, 256, 0, stream>>>(mWih, mWihT, 600, FPc);
  transpose_k<<<64, 256, 0, stream>>>(mWhh, mWhhT, 600, FPc);
  pack_gru_k<<<(Rc * 6 * 49 * 1024 + 255) / 256, 256, 0, stream>>>(gru_Wih, gru_Whh, Wpk);
  pack_att_k<<<(Rc * 49 * 1024 + 255) / 256, 256, 0, stream>>>(attend_W, Apk);

  gemm8x1<AFc, 1><<<BL / 8, 256, 0, stream>>>(atom_list, atomfcT, atom_fc_b, nullptr, AV, Hb0);
  gemm8x1<AFc, 0><<<BL / 8, 256, 0, stream>>>(atom_list, naT, nullptr, nullptr, nullptr, Pb);
  gemm8x1<BFc, 0><<<BL / 8, 256, 0, stream>>>(bond_list, naT + AFc * FPc, nullptr, nullptr, nullptr, Qb);

  __bf16* Hbuf[2] = {Hb0, Hb1};
  for (int r = 0; r < Rc; ++r) {
    if (r == 0) {
      attn_mol0<<<Bc, 256, 0, stream>>>(Pb, Qb, nb_b, Hb0, adl, bdl,
          align_W, align_b, ATTN, WNb, SW);
    } else {
      attn_molN<<<Bc, 256, 0, stream>>>(Hbuf[r & 1], adl,
          align_W + (size_t)r * 2 * FPc, align_b + r,
          ATTN + (size_t)r * BL * Kc, WNb, SW);
    }
    attend_mfma<<<BL / 128, 256, 0, stream>>>(WNb, Apk + (size_t)r * 49 * 1024,
        attend_b + (size_t)r * FPc, SW, XCb);
    gru_mfma<<<BL / 128, 256, 0, stream>>>(XCb, Hbuf[r & 1], Hbuf[(r + 1) & 1],
        Wpk + (size_t)r * 6 * 49 * 1024, gru_bih + (size_t)r * 3 * FPc, gru_bhh + (size_t)r * 3 * FPc,
        AV + (size_t)(r + 1) * BL * FPc);
  }

  mol_sum_k<<<Bc, 256, 0, stream>>>(Hbuf[Rc & 1], AV + (size_t)3 * BL * FPc, mask, MU, MV, MOLF, ACTM);
  for (int t = 0; t < Tc; ++t) {
    mol_attn_k<<<Bc, 256, 0, stream>>>(AV + (size_t)3 * BL * FPc, ACTM, mal_W, mal_b, mask,
        MA + (size_t)t * Bc * Lc, WACT, MSW);
    gemm8x1<FPc, 2><<<Bc / 8, 256, 0, stream>>>(WACT, mattT, matt_b, MSW, MCTX, nullptr);
    gru8<<<Bc / 8, 256, 0, stream>>>(MCTX, MOLF, mWihT, mWhhT, mbih, mbhh,
        ACTM, MU + (size_t)(t + 1) * Bc * FPc, MV + (size_t)(t + 1) * Bc * FPc);
  }
  pred_k<<<Bc / 4, 256, 0, stream>>>(MOLF, out_W, out_b, PRED);
}

// Round 7
// 1079.639 us; speedup vs baseline: 2.8359x; 1.1314x over previous
//
#include <hip/hip_runtime.h>
#include <stdint.h>

#define Bc 512
#define Lc 128
#define Kc 6
#define AFc 39
#define BFc 10
#define FPc 200
#define Rc 3
#define Tc 2
constexpr int BL = Bc * Lc;          // 65536
constexpr int KP = 224;              // padded K / F for MFMA
constexpr float SLOPE = 0.01f;
constexpr float NEGC = -9e8f;

typedef __attribute__((ext_vector_type(8))) __bf16 bf16x8;
typedef __attribute__((ext_vector_type(16))) float f32x16;

__device__ __forceinline__ float leaky(float x) { return x >= 0.f ? x : SLOPE * x; }
__device__ __forceinline__ float sigm(float x) { return 1.f / (1.f + __expf(-x)); }
__device__ __forceinline__ float eluf(float x) { return x > 0.f ? x : expm1f(x); }
__device__ __forceinline__ float wave_sum(float v) {
  #pragma unroll
  for (int m = 32; m >= 1; m >>= 1) v += __shfl_xor(v, m);
  return v;
}
__device__ __forceinline__ float bflo(uint32_t u) { return __uint_as_float(u << 16); }
__device__ __forceinline__ float bfhi(uint32_t u) { return __uint_as_float(u & 0xffff0000u); }
__device__ __forceinline__ unsigned short f2bu(float x) {
  __bf16 b = (__bf16)x;
  return __builtin_bit_cast(unsigned short, b);
}
__device__ __forceinline__ void glds16(const void* g, void* l) {
  __builtin_amdgcn_global_load_lds((const __attribute__((address_space(1))) uint32_t*)g,
      (__attribute__((address_space(3))) uint32_t*)l, 16, 0, 0);
}
__device__ __forceinline__ f32x16 zero16() {
  f32x16 z;
  #pragma unroll
  for (int i = 0; i < 16; ++i) z[i] = 0.f;
  return z;
}

// -------------------- weight transpose: out[c*R + r] = in[r*C + c] --------------------
__global__ void transpose_k(const float* __restrict__ in, float* __restrict__ out, int R, int C) {
  int n = R * C;
  for (int i = blockIdx.x * blockDim.x + threadIdx.x; i < n; i += gridDim.x * blockDim.x) {
    int r = i / C, c = i - r * C;
    out[c * R + r] = in[i];
  }
}

// -------------------- pack GRU weights into staging-linear tiles ---------------------
__global__ void pack_gru_k(const float* __restrict__ Wih, const float* __restrict__ Whh,
                           __bf16* __restrict__ Wpk) {
  int i = blockIdx.x * 256 + threadIdx.x;
  if (i >= Rc * 6 * 7 * 7 * 1024) return;
  int j = i & 7, fl = (i >> 3) & 31, c = (i >> 8) & 3;
  int T = i >> 10;
  int kt = T % 7; T /= 7;
  int ft = T % 7; T /= 7;
  int g = T % 6;  int r = T / 6;
  int f = ft * 32 + fl, k = kt * 32 + c * 8 + j;
  float v = 0.f;
  if (f < FPc && k < FPc) {
    if (g < 3) v = Wih[((size_t)r * 3 * FPc + g * FPc + f) * FPc + k];
    else       v = Whh[((size_t)r * 3 * FPc + (g - 3) * FPc + f) * FPc + k];
  }
  Wpk[i] = (__bf16)v;
}

// Apk layout: [r][ft7][kt7]{1024: [c4][f32][j8]}
__global__ void pack_att_k(const float* __restrict__ W, __bf16* __restrict__ Apk) {
  int i = blockIdx.x * 256 + threadIdx.x;
  if (i >= Rc * 7 * 7 * 1024) return;
  int j = i & 7, fl = (i >> 3) & 31, c = (i >> 8) & 3;
  int T = i >> 10;
  int kt = T % 7; T /= 7;
  int ft = T % 7; int r = T / 7;
  int f = ft * 32 + fl, k = kt * 32 + c * 8 + j;
  float v = (f < FPc && k < FPc) ? W[((size_t)r * FPc + f) * FPc + k] : 0.f;
  Apk[i] = (__bf16)v;
}

// -------------------- generic small GEMM (f32): Y[rows][200] ------------------------
template<int KD, int EPI>
__global__ __launch_bounds__(256) void gemm8x1(
    const float* __restrict__ X, const float* __restrict__ WT,
    const float* __restrict__ bias, const float* __restrict__ sumw,
    float* __restrict__ Y, __bf16* __restrict__ Yb) {
  constexpr int TR = 8, LDP = 12;
  __shared__ float xT[KD * LDP];
  const int row0 = blockIdx.x * TR;
  const int tid = threadIdx.x;
  for (int e = tid; e < TR * KD; e += 256) {
    int r = e / KD, g = e - r * KD;
    xT[g * LDP + r] = X[(size_t)row0 * KD + e];
  }
  __syncthreads();
  const int f = tid;
  if (f < FPc) {
    float acc[TR];
    #pragma unroll
    for (int r = 0; r < TR; ++r) acc[r] = 0.f;
    #pragma unroll 4
    for (int g = 0; g < KD; ++g) {
      float w = WT[(size_t)g * FPc + f];
      float4 x0 = *reinterpret_cast<const float4*>(&xT[g * LDP]);
      float4 x1 = *reinterpret_cast<const float4*>(&xT[g * LDP + 4]);
      acc[0] = fmaf(x0.x, w, acc[0]); acc[1] = fmaf(x0.y, w, acc[1]);
      acc[2] = fmaf(x0.z, w, acc[2]); acc[3] = fmaf(x0.w, w, acc[3]);
      acc[4] = fmaf(x1.x, w, acc[4]); acc[5] = fmaf(x1.y, w, acc[5]);
      acc[6] = fmaf(x1.z, w, acc[6]); acc[7] = fmaf(x1.w, w, acc[7]);
    }
    #pragma unroll
    for (int r = 0; r < TR; ++r) {
      if (EPI == 0) {
        Yb[(size_t)(row0 + r) * FPc + f] = (__bf16)acc[r];
      } else if (EPI == 1) {
        float v = acc[r] + bias[f];
        Y[(size_t)(row0 + r) * FPc + f] = v;                 // raw atom_lin (viz)
        Yb[(size_t)(row0 + r) * KP + f] = (__bf16)leaky(v);  // h0
      } else {
        float v = fmaf(sumw[row0 + r], bias[f], acc[r]);
        Y[(size_t)(row0 + r) * FPc + f] = eluf(v);
      }
    }
  } else if (EPI == 1 && f < KP) {
    #pragma unroll
    for (int r = 0; r < TR; ++r) Yb[(size_t)(row0 + r) * KP + f] = (__bf16)0.f;
  }
}

// -------------------- MFMA GRU v4: xc in reg-frags, h in LDS, 2 blocks/CU ------------
__global__ __launch_bounds__(256, 2) void gru_mfma(
    const __bf16* __restrict__ XCb, const __bf16* __restrict__ Hin,
    __bf16* __restrict__ Hout, const __bf16* __restrict__ Wpk,
    const float* __restrict__ bih, const float* __restrict__ bhh,
    float* __restrict__ actOut) {
  __shared__ __align__(16) __bf16 smem[40960];   // 81920 B
  __bf16* Ah = smem;                              // [wv4][kt7][1024]
  __bf16* Bs = smem + 28672;                      // [buf2][g6][1024]
  const int tid = threadIdx.x, wv = tid >> 6, lane = tid & 63;
  const size_t row0 = (size_t)blockIdx.x * 128;

  {
    int rlo = lane & 31, chi = lane >> 5;
    const __bf16* sh = Hin + (row0 + wv * 32 + rlo) * KP + chi * 8;
    #pragma unroll
    for (int kt = 0; kt < 7; ++kt)
      #pragma unroll
      for (int hc = 0; hc < 2; ++hc)
        glds16(sh + kt * 32 + hc * 16, Ah + wv * 7168 + kt * 1024 + hc * 512);
  }
  bf16x8 xcf[7][2];
  {
    const __bf16* sx = XCb + (row0 + wv * 32 + (lane & 31)) * KP + (lane >> 5) * 8;
    #pragma unroll
    for (int kt = 0; kt < 7; ++kt)
      #pragma unroll
      for (int h = 0; h < 2; ++h)
        xcf[kt][h] = *(const bf16x8*)(sx + kt * 32 + h * 16);
  }
  auto stageB = [&](int ft, int kt, int buf) {
    #pragma unroll
    for (int m3 = 0; m3 < 3; ++m3) {
      int m = wv * 3 + m3;               // 0..11
      int g = m >> 1, half = m & 1;
      const __bf16* s = Wpk + ((size_t)(g * 7 + ft) * 7 + kt) * 1024 + half * 512 + lane * 8;
      glds16(s, Bs + buf * 6144 + g * 1024 + half * 512);
    }
  };
  stageB(0, 0, 0);

  f32x16 acc[6];
  #pragma unroll
  for (int g = 0; g < 6; ++g) acc[g] = zero16();

  for (int ft = 0; ft < 7; ++ft) {
    #pragma unroll
    for (int kt = 0; kt < 7; ++kt) {
      const int it = ft * 7 + kt;
      const int buf = it & 1;
      const int nft = (kt == 6) ? ft + 1 : ft;
      const int nkt = (kt == 6) ? 0 : kt + 1;
      __builtin_amdgcn_sched_barrier(0);
      if (it < 48) stageB(nft, nkt, buf ^ 1);
      else         stageB(6, 6, buf ^ 1);          // dummy: keep 3 outstanding
      __builtin_amdgcn_sched_barrier(0);
      asm volatile("s_waitcnt vmcnt(3)" ::: "memory");
      __builtin_amdgcn_sched_barrier(0);
      __builtin_amdgcn_s_barrier();
      __builtin_amdgcn_sched_barrier(0);
      #pragma unroll
      for (int h = 0; h < 2; ++h) {
        bf16x8 ah = *(const bf16x8*)(Ah + wv * 7168 + kt * 1024 + h * 512 + lane * 8);
        const __bf16* bb = Bs + buf * 6144 + h * 512 + lane * 8;
        bf16x8 b0 = *(const bf16x8*)(bb);
        bf16x8 b1 = *(const bf16x8*)(bb + 1024);
        bf16x8 b2 = *(const bf16x8*)(bb + 2048);
        bf16x8 b3 = *(const bf16x8*)(bb + 3072);
        bf16x8 b4 = *(const bf16x8*)(bb + 4096);
        bf16x8 b5 = *(const bf16x8*)(bb + 5120);
        __builtin_amdgcn_s_setprio(1);
        acc[0] = __builtin_amdgcn_mfma_f32_32x32x16_bf16(xcf[kt][h], b0, acc[0], 0, 0, 0);
        acc[1] = __builtin_amdgcn_mfma_f32_32x32x16_bf16(xcf[kt][h], b1, acc[1], 0, 0, 0);
        acc[2] = __builtin_amdgcn_mfma_f32_32x32x16_bf16(xcf[kt][h], b2, acc[2], 0, 0, 0);
        acc[3] = __builtin_amdgcn_mfma_f32_32x32x16_bf16(ah, b3, acc[3], 0, 0, 0);
        acc[4] = __builtin_amdgcn_mfma_f32_32x32x16_bf16(ah, b4, acc[4], 0, 0, 0);
        acc[5] = __builtin_amdgcn_mfma_f32_32x32x16_bf16(ah, b5, acc[5], 0, 0, 0);
        __builtin_amdgcn_s_setprio(0);
      }
      if (kt == 6) {
        const int f = ft * 32 + (lane & 31);
        const bool fok = f < FPc;
        float bir = 0, biz = 0, bin_ = 0, bhr = 0, bhz = 0, bhn = 0;
        if (fok) {
          bir = bih[f]; biz = bih[FPc + f]; bin_ = bih[2 * FPc + f];
          bhr = bhh[f]; bhz = bhh[FPc + f]; bhn = bhh[2 * FPc + f];
        }
        const int hoff = wv * 7168 + (f >> 5) * 1024 + ((f >> 3) & 3) * 256 + (f & 7);
        #pragma unroll
        for (int reg = 0; reg < 16; ++reg) {
          int rl = (reg & 3) + 8 * (reg >> 2) + 4 * (lane >> 5);
          size_t row = row0 + wv * 32 + rl;
          if (fok) {
            float ho = (float)Ah[hoff + rl * 8];
            float rg_ = sigm(acc[0][reg] + bir + acc[3][reg] + bhr);
            float zg  = sigm(acc[1][reg] + biz + acc[4][reg] + bhz);
            float ng  = tanhf(acc[2][reg] + bin_ + rg_ * (acc[5][reg] + bhn));
            float hp = (1.f - zg) * ng + zg * ho;
            Hout[row * KP + f] = (__bf16)hp;
            actOut[row * FPc + f] = fmaxf(hp, 0.f);
          } else {
            Hout[row * KP + f] = (__bf16)0.f;
          }
        }
        #pragma unroll
        for (int g = 0; g < 6; ++g) acc[g] = zero16();
      }
      __builtin_amdgcn_sched_barrier(0);
      __builtin_amdgcn_s_barrier();
      __builtin_amdgcn_sched_barrier(0);
    }
  }
}

// -------------------- MFMA attend v4: LDS-free, barrier-free -------------------------
__global__ __launch_bounds__(256, 2) void attend_mfma(
    const __bf16* __restrict__ WNb, const __bf16* __restrict__ Apk,
    const float* __restrict__ bias, const float* __restrict__ SW,
    __bf16* __restrict__ XCb) {
  const int tid = threadIdx.x, wv = tid >> 6, lane = tid & 63;
  const size_t row0 = (size_t)blockIdx.x * 128;

  bf16x8 af[7][2];
  {
    const __bf16* sw_ = WNb + (row0 + wv * 32 + (lane & 31)) * KP + (lane >> 5) * 8;
    #pragma unroll
    for (int kt = 0; kt < 7; ++kt)
      #pragma unroll
      for (int h = 0; h < 2; ++h)
        af[kt][h] = *(const bf16x8*)(sw_ + kt * 32 + h * 16);
  }

  for (int ft = 0; ft < 7; ++ft) {
    f32x16 acc = zero16();
    #pragma unroll
    for (int kt = 0; kt < 7; ++kt) {
      const __bf16* bt = Apk + ((size_t)ft * 7 + kt) * 1024 + lane * 8;
      bf16x8 b0 = *(const bf16x8*)(bt);
      bf16x8 b1 = *(const bf16x8*)(bt + 512);
      acc = __builtin_amdgcn_mfma_f32_32x32x16_bf16(af[kt][0], b0, acc, 0, 0, 0);
      acc = __builtin_amdgcn_mfma_f32_32x32x16_bf16(af[kt][1], b1, acc, 0, 0, 0);
    }
    const int f = ft * 32 + (lane & 31);
    const bool fok = f < FPc;
    float bf = fok ? bias[f] : 0.f;
    #pragma unroll
    for (int reg = 0; reg < 16; ++reg) {
      int rl = (reg & 3) + 8 * (reg >> 2) + 4 * (lane >> 5);
      size_t row = row0 + wv * 32 + rl;
      if (fok) {
        float v = acc[reg] + SW[row] * bf;
        XCb[row * KP + f] = (__bf16)eluf(v);
      } else {
        XCb[row * KP + f] = (__bf16)0.f;
      }
    }
  }
}

// -------------------- attn round r>=1: per-molecule block ---------------------------
// act = relu(Hb). sn[l] factored per-atom; weighted sum from LDS.
__global__ __launch_bounds__(256) void attn_molN(
    const __bf16* __restrict__ Hb,       // [BL][KP]
    const int* __restrict__ adl,
    const float* __restrict__ alW,       // +r*2*FP
    const float* __restrict__ albp,      // +r
    float* __restrict__ attnOut, __bf16* __restrict__ WNb, float* __restrict__ SW) {
  __shared__ __align__(16) __bf16 actL[128 * 224];
  __shared__ float saL[128], snL[128];
  const int b = blockIdx.x;
  const int tid = threadIdx.x, wv = tid >> 6, lane = tid & 63;
  const bool l36 = lane < 36;

  // ---- stage act = relu(Hb) ----
  {
    const uint4* src = (const uint4*)(Hb + (size_t)b * 128 * KP);
    uint4* dst = (uint4*)actL;
    for (int i = tid; i < 128 * 224 / 8; i += 256) {
      uint4 v = src[i];
      uint32_t c[4] = {v.x, v.y, v.z, v.w};
      #pragma unroll
      for (int j = 0; j < 4; ++j) {
        uint32_t lo = c[j] & 0xffffu, hi = c[j] >> 16;
        if (lo & 0x8000u) lo = 0;
        if (hi & 0x8000u) hi = 0;
        c[j] = lo | (hi << 16);
      }
      dst[i] = make_uint4(c[0], c[1], c[2], c[3]);
    }
  }
  // weight pairs in regs
  float wa0x = alW[2 * lane], wa0y = alW[2 * lane + 1];
  float wa1x = l36 ? alW[128 + 2 * lane] : 0.f, wa1y = l36 ? alW[129 + 2 * lane] : 0.f;
  float wn0x = alW[FPc + 2 * lane], wn0y = alW[FPc + 2 * lane + 1];
  float wn1x = l36 ? alW[FPc + 128 + 2 * lane] : 0.f, wn1y = l36 ? alW[FPc + 129 + 2 * lane] : 0.f;
  const float ab = albp[0];
  __syncthreads();

  // ---- per-atom dots: sa[l], sn[l] ----
  for (int i = 0; i < 32; ++i) {
    int l = wv * 32 + i;
    const uint32_t* rowp = (const uint32_t*)(actL + l * 224);
    uint32_t u0 = rowp[lane];
    uint32_t u1 = l36 ? rowp[64 + lane] : 0u;
    float x0 = bflo(u0), y0 = bfhi(u0), x1 = bflo(u1), y1 = bfhi(u1);
    float psa = x0 * wa0x + y0 * wa0y + x1 * wa1x + y1 * wa1y;
    float psn = x0 * wn0x + y0 * wn0y + x1 * wn1x + y1 * wn1y;
    psa = wave_sum(psa);
    psn = wave_sum(psn);
    if (lane == 0) { saL[l] = psa; snL[l] = psn; }
  }
  __syncthreads();

  // ---- per-row: softmax over 6 neighbors + weighted sum ----
  for (int i = 0; i < 32; ++i) {
    const int row = wv * 32 + i;
    const size_t grow = (size_t)b * 128 + row;
    int gk = (lane < Kc) ? adl[grow * Kc + lane] : 0;
    int ai[Kc];
    #pragma unroll
    for (int k = 0; k < Kc; ++k) ai[k] = __shfl(gk, k);
    const float sarow = saL[row];
    float s[Kc]; bool pad[Kc]; float mx = -3.0e38f;
    #pragma unroll
    for (int k = 0; k < Kc; ++k) {
      pad[k] = (ai[k] == Lc - 1);
      s[k] = leaky(sarow + snL[ai[k]] + ab) + (pad[k] ? NEGC : 0.f);
      mx = fmaxf(mx, s[k]);
    }
    float e[Kc], sum = 0.f;
    #pragma unroll
    for (int k = 0; k < Kc; ++k) { e[k] = __expf(s[k] - mx); sum += e[k]; }
    float inv = 1.f / sum;
    float w[Kc], sw = 0.f;
    #pragma unroll
    for (int k = 0; k < Kc; ++k) { w[k] = pad[k] ? 0.f : e[k] * inv; sw += w[k]; }
    if (lane < Kc) attnOut[grow * Kc + lane] = w[lane];
    if (lane == 0) SW[grow] = sw;
    float a0 = 0.f, b0 = 0.f, a1 = 0.f, b1 = 0.f;
    #pragma unroll
    for (int k = 0; k < Kc; ++k) {
      const uint32_t* nr = (const uint32_t*)(actL + ai[k] * 224);
      uint32_t u0 = nr[lane];
      uint32_t u1 = l36 ? nr[64 + lane] : 0u;
      a0 = fmaf(w[k], bflo(u0), a0); b0 = fmaf(w[k], bfhi(u0), b0);
      a1 = fmaf(w[k], bflo(u1), a1); b1 = fmaf(w[k], bfhi(u1), b1);
    }
    __bf16* wr = WNb + grow * KP;
    ushort2 o0; o0.x = f2bu(a0); o0.y = f2bu(b0);
    *(ushort2*)(wr + 2 * lane) = o0;
    if (lane < 48) {
      float va = l36 ? a1 : 0.f, vb = l36 ? b1 : 0.f;
      ushort2 o1; o1.x = f2bu(va); o1.y = f2bu(vb);
      *(ushort2*)(wr + 128 + 2 * lane) = o1;
    }
  }
}

// -------------------- attn round r==0: per-molecule block, 8 waves, v-reg cache -----
__global__ __launch_bounds__(512) void attn_mol0(
    const __bf16* __restrict__ Pb, const __bf16* __restrict__ Qb,
    const float* __restrict__ nbb, const __bf16* __restrict__ Hb0,
    const int* __restrict__ adl, const int* __restrict__ bdl,
    const float* __restrict__ alW, const float* __restrict__ albp,
    float* __restrict__ attnOut, __bf16* __restrict__ WNb, float* __restrict__ SW) {
  __shared__ __align__(16) __bf16 Pl[128 * 200];
  __shared__ __align__(16) __bf16 Ql[128 * 200];
  __shared__ float nbbL[200];
  __shared__ float saL[128];
  const int b = blockIdx.x;
  const int tid = threadIdx.x, wv = tid >> 6, lane = tid & 63;
  const bool l36 = lane < 36;

  {
    const uint4* sp = (const uint4*)(Pb + (size_t)b * 128 * FPc);
    const uint4* sq = (const uint4*)(Qb + (size_t)b * 128 * FPc);
    uint4* dp = (uint4*)Pl;
    uint4* dq = (uint4*)Ql;
    for (int i = tid; i < 128 * 200 / 8; i += 512) { dp[i] = sp[i]; dq[i] = sq[i]; }
    for (int i = tid; i < FPc; i += 512) nbbL[i] = nbb[i];
  }
  float wa0x = alW[2 * lane], wa0y = alW[2 * lane + 1];
  float wa1x = l36 ? alW[128 + 2 * lane] : 0.f, wa1y = l36 ? alW[129 + 2 * lane] : 0.f;
  float wn0x = alW[FPc + 2 * lane], wn0y = alW[FPc + 2 * lane + 1];
  float wn1x = l36 ? alW[FPc + 128 + 2 * lane] : 0.f, wn1y = l36 ? alW[FPc + 129 + 2 * lane] : 0.f;
  const float ab = albp[0];

  // per-atom sa from global Hb0 (leaky(atom_lin), bf16, stride KP): 16 atoms per wave
  for (int i = 0; i < 16; ++i) {
    int l = wv * 16 + i;
    const uint32_t* hr = (const uint32_t*)(Hb0 + ((size_t)b * 128 + l) * KP);
    uint32_t u0 = hr[lane];
    uint32_t u1 = l36 ? hr[64 + lane] : 0u;
    float psa = bflo(u0) * wa0x + bfhi(u0) * wa0y + bflo(u1) * wa1x + bfhi(u1) * wa1y;
    psa = wave_sum(psa);
    if (lane == 0) saL[l] = psa;
  }
  __syncthreads();

  const float n0x = nbbL[2 * lane], n0y = nbbL[2 * lane + 1];
  const float n1x = l36 ? nbbL[128 + 2 * lane] : 0.f, n1y = l36 ? nbbL[129 + 2 * lane] : 0.f;

  // 16 rows per wave; v[k] cached in registers across score + sum passes
  for (int i = 0; i < 16; ++i) {
    const int row = wv * 16 + i;
    const size_t grow = (size_t)b * 128 + row;
    int gk = (lane < Kc) ? adl[grow * Kc + lane] : 0;
    int hk = (lane < Kc) ? bdl[grow * Kc + lane] : 0;
    int ai[Kc], bi[Kc];
    #pragma unroll
    for (int k = 0; k < Kc; ++k) { ai[k] = __shfl(gk, k); bi[k] = __shfl(hk, k); }
    float v0x[Kc], v0y[Kc], v1x[Kc], v1y[Kc], p[Kc];
    #pragma unroll
    for (int k = 0; k < Kc; ++k) {
      const uint32_t* pr = (const uint32_t*)(Pl + ai[k] * 200);
      const uint32_t* qr = (const uint32_t*)(Ql + bi[k] * 200);
      uint32_t up0 = pr[lane], uq0 = qr[lane];
      uint32_t up1 = l36 ? pr[64 + lane] : 0u, uq1 = l36 ? qr[64 + lane] : 0u;
      v0x[k] = leaky(bflo(up0) + bflo(uq0) + n0x);
      v0y[k] = leaky(bfhi(up0) + bfhi(uq0) + n0y);
      v1x[k] = l36 ? leaky(bflo(up1) + bflo(uq1) + n1x) : 0.f;
      v1y[k] = l36 ? leaky(bfhi(up1) + bfhi(uq1) + n1y) : 0.f;
      p[k] = v0x[k] * wn0x + v0y[k] * wn0y + v1x[k] * wn1x + v1y[k] * wn1y;
    }
    #pragma unroll
    for (int k = 0; k < Kc; ++k) p[k] = wave_sum(p[k]);
    const float sarow = saL[row];
    float s[Kc]; bool pad[Kc]; float mx = -3.0e38f;
    #pragma unroll
    for (int k = 0; k < Kc; ++k) {
      pad[k] = (ai[k] == Lc - 1);
      s[k] = leaky(sarow + p[k] + ab) + (pad[k] ? NEGC : 0.f);
      mx = fmaxf(mx, s[k]);
    }
    float e[Kc], sum = 0.f;
    #pragma unroll
    for (int k = 0; k < Kc; ++k) { e[k] = __expf(s[k] - mx); sum += e[k]; }
    float inv = 1.f / sum;
    float w[Kc], sw = 0.f;
    #pragma unroll
    for (int k = 0; k < Kc; ++k) { w[k] = pad[k] ? 0.f : e[k] * inv; sw += w[k]; }
    if (lane < Kc) attnOut[grow * Kc + lane] = w[lane];
    if (lane == 0) SW[grow] = sw;
    float a0 = 0.f, b0v = 0.f, a1 = 0.f, b1v = 0.f;
    #pragma unroll
    for (int k = 0; k < Kc; ++k) {
      a0  = fmaf(w[k], v0x[k], a0);
      b0v = fmaf(w[k], v0y[k], b0v);
      a1  = fmaf(w[k], v1x[k], a1);
      b1v = fmaf(w[k], v1y[k], b1v);
    }
    __bf16* wr = WNb + grow * KP;
    ushort2 o0; o0.x = f2bu(a0); o0.y = f2bu(b0v);
    *(ushort2*)(wr + 2 * lane) = o0;
    if (lane < 48) {
      float va = l36 ? a1 : 0.f, vb = l36 ? b1v : 0.f;
      ushort2 o1; o1.x = f2bu(va); o1.y = f2bu(vb);
      *(ushort2*)(wr + 128 + 2 * lane) = o1;
    }
  }
}

// -------------------- fused GRU f32 (mol path, 512 rows) -----------------------------
__global__ __launch_bounds__(256) void gru8(
    const float* __restrict__ XC, float* __restrict__ H,
    const float* __restrict__ WihT, const float* __restrict__ WhhT,
    const float* __restrict__ bih, const float* __restrict__ bhh,
    float* __restrict__ actOut, float* __restrict__ unbOut, float* __restrict__ vizOut) {
  constexpr int TR = 8, LDP = 12;
  __shared__ float xc[FPc * LDP];
  __shared__ float xh[FPc * LDP];
  const int row0 = blockIdx.x * TR;
  const int tid = threadIdx.x;
  for (int e = tid; e < TR * FPc; e += 256) {
    int r = e / FPc, g = e - r * FPc;
    xc[g * LDP + r] = XC[(size_t)row0 * FPc + e];
    xh[g * LDP + r] = H[(size_t)row0 * FPc + e];
  }
  __syncthreads();
  const int f = tid;
  if (f < FPc) {
    float air[8], aiz[8], ain[8], ahr[8], ahz[8], ahn[8];
    const float bir = bih[f], biz = bih[f + 200], bin_ = bih[f + 400];
    const float bhr = bhh[f], bhz = bhh[f + 200], bhn = bhh[f + 400];
    #pragma unroll
    for (int r = 0; r < 8; ++r) {
      air[r] = bir; aiz[r] = biz; ain[r] = bin_;
      ahr[r] = bhr; ahz[r] = bhz; ahn[r] = bhn;
    }
    #pragma unroll 2
    for (int g = 0; g < FPc; ++g) {
      const float* wi = &WihT[(size_t)g * 600 + f];
      const float* wh = &WhhT[(size_t)g * 600 + f];
      float wir = wi[0], wiz = wi[200], win = wi[400];
      float whr = wh[0], whz = wh[200], whn = wh[400];
      float4 c0 = *reinterpret_cast<const float4*>(&xc[g * LDP]);
      float4 c1 = *reinterpret_cast<const float4*>(&xc[g * LDP + 4]);
      float4 h0 = *reinterpret_cast<const float4*>(&xh[g * LDP]);
      float4 h1 = *reinterpret_cast<const float4*>(&xh[g * LDP + 4]);
      float cx[8] = {c0.x, c0.y, c0.z, c0.w, c1.x, c1.y, c1.z, c1.w};
      float hx[8] = {h0.x, h0.y, h0.z, h0.w, h1.x, h1.y, h1.z, h1.w};
      #pragma unroll
      for (int r = 0; r < 8; ++r) {
        air[r] = fmaf(cx[r], wir, air[r]);
        aiz[r] = fmaf(cx[r], wiz, aiz[r]);
        ain[r] = fmaf(cx[r], win, ain[r]);
        ahr[r] = fmaf(hx[r], whr, ahr[r]);
        ahz[r] = fmaf(hx[r], whz, ahz[r]);
        ahn[r] = fmaf(hx[r], whn, ahn[r]);
      }
    }
    #pragma unroll
    for (int r = 0; r < 8; ++r) {
      float rg = sigm(air[r] + ahr[r]);
      float zg = sigm(aiz[r] + ahz[r]);
      float ng = tanhf(fmaf(rg, ahn[r], ain[r]));
      float hv = xh[f * LDP + r];
      float hp = (1.f - zg) * ng + zg * hv;
      size_t idx = (size_t)(row0 + r) * FPc + f;
      H[idx] = hp;
      float a = fmaxf(hp, 0.f);
      if (actOut) actOut[idx] = a;
      if (unbOut) unbOut[idx] = hp;
      if (vizOut) vizOut[idx] = a;
    }
  }
}

// -------------------- mol-level sum over atoms ---------------------------------------
__global__ __launch_bounds__(256) void mol_sum_k(
    const __bf16* __restrict__ Hb, const float* __restrict__ ACT, const float* __restrict__ mask,
    float* __restrict__ unb0, float* __restrict__ viz0,
    float* __restrict__ molfeat, float* __restrict__ actmol) {
  const int b = blockIdx.x;
  __shared__ float mk[Lc];
  for (int l = threadIdx.x; l < Lc; l += 256) mk[l] = mask[b * Lc + l];
  __syncthreads();
  const int f = threadIdx.x;
  if (f < FPc) {
    float s1 = 0.f, s2 = 0.f;
    for (int l = 0; l < Lc; ++l) {
      float m = mk[l];
      s1 = fmaf((float)Hb[((size_t)b * Lc + l) * KP + f], m, s1);
      s2 = fmaf(ACT[((size_t)b * Lc + l) * FPc + f], m, s2);
    }
    unb0[b * FPc + f] = s1;
    viz0[b * FPc + f] = s2;
    molfeat[b * FPc + f] = s2;
    actmol[b * FPc + f] = fmaxf(s2, 0.f);
  }
}

// -------------------- mol-level attention over L atoms -------------------------------
__global__ __launch_bounds__(256) void mol_attn_k(
    const float* __restrict__ act, const float* __restrict__ actmol,
    const float* __restrict__ malW, const float* __restrict__ malb,
    const float* __restrict__ mask,
    float* __restrict__ attnOut, float* __restrict__ wact, float* __restrict__ msumw) {
  const int b = blockIdx.x;
  __shared__ float sa_s;
  __shared__ float sn[Lc];
  __shared__ float wl[Lc];
  __shared__ float redmx[2], redsum[2], redsw[2];
  const int wv = threadIdx.x >> 6, lane = threadIdx.x & 63;
  if (wv == 0) {
    float p = 0.f;
    for (int f = lane; f < FPc; f += 64) p = fmaf(actmol[b * FPc + f], malW[f], p);
    float s = wave_sum(p);
    if (lane == 0) sa_s = s;
  }
  for (int l = wv; l < Lc; l += 4) {
    float p = 0.f;
    for (int f = lane; f < FPc; f += 64)
      p = fmaf(act[((size_t)b * Lc + l) * FPc + f], malW[FPc + f], p);
    float s = wave_sum(p);
    if (lane == 0) sn[l] = s;
  }
  __syncthreads();
  const int l = threadIdx.x;
  float sc = -3.0e38f, mval = 0.f;
  if (l < Lc) {
    mval = mask[b * Lc + l];
    sc = leaky(sa_s + sn[l] + malb[0]) + (mval == 0.f ? NEGC : 0.f);
  }
  float m = sc;
  #pragma unroll
  for (int o = 32; o >= 1; o >>= 1) m = fmaxf(m, __shfl_xor(m, o));
  if (lane == 0 && wv < 2) redmx[wv] = m;
  __syncthreads();
  float mx = fmaxf(redmx[0], redmx[1]);
  float e = (l < Lc) ? __expf(sc - mx) : 0.f;
  float s = e;
  #pragma unroll
  for (int o = 32; o >= 1; o >>= 1) s += __shfl_xor(s, o);
  if (lane == 0 && wv < 2) redsum[wv] = s;
  __syncthreads();
  float tot = redsum[0] + redsum[1];
  float w = 0.f;
  if (l < Lc) {
    w = e / tot * mval;
    wl[l] = w;
    attnOut[(size_t)b * Lc + l] = w;
  }
  float swp = w;
  #pragma unroll
  for (int o = 32; o >= 1; o >>= 1) swp += __shfl_xor(swp, o);
  if (lane == 0 && wv < 2) redsw[wv] = swp;
  __syncthreads();
  if (threadIdx.x == 0) msumw[b] = redsw[0] + redsw[1];
  const int f = threadIdx.x;
  if (f < FPc) {
    float a = 0.f;
    for (int l2 = 0; l2 < Lc; ++l2)
      a = fmaf(wl[l2], act[((size_t)b * Lc + l2) * FPc + f], a);
    wact[b * FPc + f] = a;
  }
}

// -------------------- final prediction -----------------------------------------------
__global__ __launch_bounds__(256) void pred_k(
    const float* __restrict__ molfeat, const float* __restrict__ outW,
    const float* __restrict__ outb, float* __restrict__ pred) {
  const int wv = threadIdx.x >> 6, lane = threadIdx.x & 63;
  const int b = blockIdx.x * 4 + wv;
  if (b < Bc) {
    float p = 0.f;
    for (int f = lane; f < FPc; f += 64) p = fmaf(molfeat[b * FPc + f], outW[f], p);
    float s = wave_sum(p);
    if (lane == 0) pred[b] = s + outb[0];
  }
}

extern "C" void kernel_launch(void* const* d_in, const int* in_sizes, int n_in,
                              void* d_out, int out_size, void* d_ws, size_t ws_size,
                              hipStream_t stream) {
  const float* atom_list = (const float*)d_in[0];
  const float* bond_list = (const float*)d_in[1];
  const int*   adl       = (const int*)d_in[2];
  const int*   bdl       = (const int*)d_in[3];
  const float* mask      = (const float*)d_in[4];
  const float* atom_fc_W = (const float*)d_in[5];
  const float* atom_fc_b = (const float*)d_in[6];
  const float* nb_W      = (const float*)d_in[7];
  const float* nb_b      = (const float*)d_in[8];
  const float* align_W   = (const float*)d_in[9];
  const float* align_b   = (const float*)d_in[10];
  const float* attend_W  = (const float*)d_in[11];
  const float* attend_b  = (const float*)d_in[12];
  const float* gru_Wih   = (const float*)d_in[13];
  const float* gru_Whh   = (const float*)d_in[14];
  const float* gru_bih   = (const float*)d_in[15];
  const float* gru_bhh   = (const float*)d_in[16];
  const float* mal_W     = (const float*)d_in[17];
  const float* mal_b     = (const float*)d_in[18];
  const float* matt_W    = (const float*)d_in[19];
  const float* matt_b    = (const float*)d_in[20];
  const float* mWih      = (const float*)d_in[21];
  const float* mWhh      = (const float*)d_in[22];
  const float* mbih      = (const float*)d_in[23];
  const float* mbhh      = (const float*)d_in[24];
  const float* out_W     = (const float*)d_in[25];
  const float* out_b     = (const float*)d_in[26];

  float* out  = (float*)d_out;
  float* AV   = out;                                  // (4,B,L,FP)
  float* ATTN = AV + (size_t)4 * BL * FPc;            // (3,B,L,K)
  float* MV   = ATTN + (size_t)Rc * BL * Kc;          // (3,B,FP)
  float* MU   = MV + (size_t)3 * Bc * FPc;            // (3,B,FP)
  float* MA   = MU + (size_t)3 * Bc * FPc;            // (2,B,L)
  float* PRED = MA + (size_t)Tc * Bc * Lc;            // (B,1)

  char* w = (char*)d_ws;
  __bf16* Hb0  = (__bf16*)w; w += (size_t)BL * KP * 2;
  __bf16* Hb1  = (__bf16*)w; w += (size_t)BL * KP * 2;
  __bf16* XCb  = (__bf16*)w; w += (size_t)BL * KP * 2;
  __bf16* WNb  = (__bf16*)w; w += (size_t)BL * KP * 2;
  __bf16* Pb   = (__bf16*)w; w += (size_t)BL * FPc * 2;
  __bf16* Qb   = (__bf16*)w; w += (size_t)BL * FPc * 2;
  __bf16* Wpk  = (__bf16*)w; w += (size_t)Rc * 6 * 49 * 1024 * 2;
  __bf16* Apk  = (__bf16*)w; w += (size_t)Rc * 49 * 1024 * 2;
  float* SW    = (float*)w;  w += (size_t)BL * 4;
  float* MOLF  = (float*)w;  w += (size_t)Bc * FPc * 4;
  float* ACTM  = (float*)w;  w += (size_t)Bc * FPc * 4;
  float* WACT  = (float*)w;  w += (size_t)Bc * FPc * 4;
  float* MCTX  = (float*)w;  w += (size_t)Bc * FPc * 4;
  float* MSW   = (float*)w;  w += (size_t)Bc * 4;
  float* atomfcT = (float*)w; w += (size_t)AFc * FPc * 4;
  float* naT     = (float*)w; w += (size_t)(AFc + BFc) * FPc * 4;
  float* mattT   = (float*)w; w += (size_t)FPc * FPc * 4;
  float* mWihT   = (float*)w; w += (size_t)FPc * 600 * 4;
  float* mWhhT   = (float*)w; w += (size_t)FPc * 600 * 4;

  transpose_k<<<64, 256, 0, stream>>>(atom_fc_W, atomfcT, FPc, AFc);
  transpose_k<<<64, 256, 0, stream>>>(nb_W, naT, FPc, AFc + BFc);
  transpose_k<<<64, 256, 0, stream>>>(matt_W, mattT, FPc, FPc);
  transpose_k<<<64, 256, 0, stream>>>(mWih, mWihT, 600, FPc);
  transpose_k<<<64, 256, 0, stream>>>(mWhh, mWhhT, 600, FPc);
  pack_gru_k<<<(Rc * 6 * 49 * 1024 + 255) / 256, 256, 0, stream>>>(gru_Wih, gru_Whh, Wpk);
  pack_att_k<<<(Rc * 49 * 1024 + 255) / 256, 256, 0, stream>>>(attend_W, Apk);

  gemm8x1<AFc, 1><<<BL / 8, 256, 0, stream>>>(atom_list, atomfcT, atom_fc_b, nullptr, AV, Hb0);
  gemm8x1<AFc, 0><<<BL / 8, 256, 0, stream>>>(atom_list, naT, nullptr, nullptr, nullptr, Pb);
  gemm8x1<BFc, 0><<<BL / 8, 256, 0, stream>>>(bond_list, naT + AFc * FPc, nullptr, nullptr, nullptr, Qb);

  __bf16* Hbuf[2] = {Hb0, Hb1};
  for (int r = 0; r < Rc; ++r) {
    if (r == 0) {
      attn_mol0<<<Bc, 512, 0, stream>>>(Pb, Qb, nb_b, Hb0, adl, bdl,
          align_W, align_b, ATTN, WNb, SW);
    } else {
      attn_molN<<<Bc, 256, 0, stream>>>(Hbuf[r & 1], adl,
          align_W + (size_t)r * 2 * FPc, align_b + r,
          ATTN + (size_t)r * BL * Kc, WNb, SW);
    }
    attend_mfma<<<BL / 128, 256, 0, stream>>>(WNb, Apk + (size_t)r * 49 * 1024,
        attend_b + (size_t)r * FPc, SW, XCb);
    gru_mfma<<<BL / 128, 256, 0, stream>>>(XCb, Hbuf[r & 1], Hbuf[(r + 1) & 1],
        Wpk + (size_t)r * 6 * 49 * 1024, gru_bih + (size_t)r * 3 * FPc, gru_bhh + (size_t)r * 3 * FPc,
        AV + (size_t)(r + 1) * BL * FPc);
  }

  mol_sum_k<<<Bc, 256, 0, stream>>>(Hbuf[Rc & 1], AV + (size_t)3 * BL * FPc, mask, MU, MV, MOLF, ACTM);
  for (int t = 0; t < Tc; ++t) {
    mol_attn_k<<<Bc, 256, 0, stream>>>(AV + (size_t)3 * BL * FPc, ACTM, mal_W, mal_b, mask,
        MA + (size_t)t * Bc * Lc, WACT, MSW);
    gemm8x1<FPc, 2><<<Bc / 8, 256, 0, stream>>>(WACT, mattT, matt_b, MSW, MCTX, nullptr);
    gru8<<<Bc / 8, 256, 0, stream>>>(MCTX, MOLF, mWihT, mWhhT, mbih, mbhh,
        ACTM, MU + (size_t)(t + 1) * Bc * FPc, MV + (size_t)(t + 1) * Bc * FPc);
  }
  pred_k<<<Bc / 4, 256, 0, stream>>>(MOLF, out_W, out_b, PRED);
}